// Round 9
// baseline (535.906 us; speedup 1.0000x reference)
//
#include <hip/hip_runtime.h>
#include <hip/hip_bf16.h>

typedef unsigned int u32;
typedef unsigned short u16;
typedef _Float16 f16;
typedef float f32x2 __attribute__((ext_vector_type(2)));
typedef _Float16 f16x2 __attribute__((ext_vector_type(2)));
typedef u32 u32x4 __attribute__((ext_vector_type(4)));
typedef u32 u32x2v __attribute__((ext_vector_type(2)));
typedef _Float16 f16x8 __attribute__((ext_vector_type(8)));
typedef float f32x4v __attribute__((ext_vector_type(4)));

#define LN_EPS 1e-5f
#define T_STEPS 30
#define NAG 4096

__device__ __forceinline__ float bf2f(u16 v){
    union { u32 u; float f; } c; c.u = ((u32)v) << 16; return c.f;
}
__device__ __forceinline__ u16 f2bf(float f){
    union { float f; u32 u; } c; c.f = f;
    return (u16)((c.u + 0x7FFFu + ((c.u >> 16) & 1u)) >> 16);
}
__device__ __forceinline__ u32 pk_h2(float a, float b){
    f16x2 h; h[0] = (f16)a; h[1] = (f16)b;
    return __builtin_bit_cast(u32, h);
}
__device__ __forceinline__ f32x2 unpk_h2(u32 p){
    f16x2 h = __builtin_bit_cast(f16x2, p);
    f32x2 r; r[0] = (float)h[0]; r[1] = (float)h[1]; return r;
}
__device__ __forceinline__ u32 bfp2h2(u32 p){
    union { u32 u; float f; } a, b;
    a.u = p << 16; b.u = p & 0xFFFF0000u;
    return pk_h2(a.f, b.f);
}
__device__ __forceinline__ float fdot2u(u32 a, u32 b, float c){
    return __builtin_amdgcn_fdot2(__builtin_bit_cast(f16x2, a),
                                  __builtin_bit_cast(f16x2, b), c, false);
}
// dtype probe: fp32 buffers read as u16 have random mantissa halves at even
// positions (~50% decode to |x|>=128); bf16 weight buffers (|w| < 1) never do.
__device__ __forceinline__ int detect_f32(const void* probe){
    const u16* p = (const u16*)probe;
    int bad = 0;
    #pragma unroll
    for (int i = 0; i < 32; i++){
        u32 e = (p[2*i] >> 7) & 0xFF;
        bad += (e >= 0x86) ? 1 : 0;
    }
    return bad > 4;
}
__device__ __forceinline__ float ldin(const void* p, int i, int F){
    float v;
    if (F) v = ((const float*)p)[i];
    else   v = bf2f(((const u16*)p)[i]);
    return v;
}
__device__ __forceinline__ u32 ld_pair(const void* p, int pairIdx, int F){
    if (F){ const float* f = (const float*)p; return pk_h2(f[2*pairIdx], f[2*pairIdx+1]); }
    return bfp2h2(((const u32*)p)[pairIdx]);
}
__device__ __forceinline__ void wred64(float& s, float& q){
    #pragma unroll
    for (int m = 1; m < 64; m <<= 1){ s += __shfl_xor(s, m); q += __shfl_xor(q, m); }
}
__device__ __forceinline__ void wred32(float& s, float& q){
    #pragma unroll
    for (int m = 1; m < 32; m <<= 1){ s += __shfl_xor(s, m); q += __shfl_xor(q, m); }
}
__device__ __forceinline__ float lrelu(float x){ return fmaxf(x, 0.1f * x); }
__device__ __forceinline__ float sigm(float x){ return 1.0f / (1.0f + __expf(-x)); }
__device__ __forceinline__ float ftanh(float x){ return 1.0f - 2.0f / (1.0f + __expf(2.0f * x)); }
__device__ __forceinline__ void ln128(float a0, float a1, float& o0, float& o1){
    float s = a0 + a1, q = a0*a0 + a1*a1;
    wred64(s, q);
    float m = s * (1.f/128.f), v = q * (1.f/128.f) - m*m;
    float rs = rsqrtf(fmaxf(v, 0.f) + LN_EPS);
    o0 = (a0 - m) * rs; o1 = (a1 - m) * rs;
}

// ---------------- K1: cond embeddings (both dirs): [N,2] -> 64 -> 128 ----------------
// 256 thr / 8 agents per block; w2 staged TRANSPOSED in LDS (coalesced global
// reads; +2-pad stride 130, reads conflict-free). One barrier total.
__global__ __launch_bounds__(256) void k_cond(
    const void* __restrict__ cond,
    const void* __restrict__ w1a, const void* __restrict__ b1a,
    const void* __restrict__ w2a, const void* __restrict__ b2a,
    const void* __restrict__ w1b, const void* __restrict__ b1b,
    const void* __restrict__ w2b, const void* __restrict__ b2b,
    const void* __restrict__ probe,
    f16* __restrict__ disp)
{
    __shared__ float w2T[64*130];     // [k][u], padded stride 130 (33.3 KB)
    __shared__ float w1s[128], b1s[64], b2s[128];
    __shared__ float x1s[4][64];      // layer-1 outs, per wave
    int F = detect_f32(probe);
    int tid = threadIdx.x, dir = blockIdx.y;
    const void* w1 = dir ? w1b : w1a; const void* b1 = dir ? b1b : b1a;
    const void* w2 = dir ? w2b : w2a; const void* b2 = dir ? b2b : b2a;
    // stage w2 transposed: global idx i = u*64 + k, k fastest -> coalesced reads
    for (int i = tid; i < 8192; i += 256){
        int u = i >> 6, k = i & 63;
        w2T[k*130 + u] = ldin(w2, i, F);
    }
    if (tid < 128) w1s[tid] = ldin(w1, tid, F);
    else           b2s[tid - 128] = ldin(b2, tid - 128, F);
    if (tid < 64)  b1s[tid] = ldin(b1, tid, F);
    __syncthreads();

    int w = tid >> 6, lane = tid & 63;
    int nb = blockIdx.x * 8 + w * 2;
    #pragma unroll
    for (int a = 0; a < 2; a++){
        int n = nb + a;
        float c0 = ldin(cond, n*2, F), c1 = ldin(cond, n*2+1, F);
        float y = w1s[lane*2] * c0 + w1s[lane*2+1] * c1 + b1s[lane];
        float s = y, q = y*y; wred64(s, q);
        float m = s * (1.f/64.f), v = q * (1.f/64.f) - m*m;
        float rs = rsqrtf(fmaxf(v, 0.f) + LN_EPS);
        x1s[w][lane] = lrelu((y - m) * rs);   // per-wave buffer, no barrier needed
        float y0 = b2s[lane], y1 = b2s[lane + 64];
        #pragma unroll 8
        for (int k = 0; k < 64; k++){
            float xv = x1s[w][k];
            y0 = fmaf(xv, w2T[k*130 + lane], y0);
            y1 = fmaf(xv, w2T[k*130 + 64 + lane], y1);
        }
        float o0, o1; ln128(y0, y1, o0, o1);
        f16* dp = disp + ((size_t)dir * NAG + n) * 128;
        dp[lane] = (f16)lrelu(o0);
        dp[lane+64] = (f16)lrelu(o1);
    }
}

// ---------------- K2: scene embedding: z[T,N,128] -> 32 -> 64 (packed fdot2) ----------
__global__ __launch_bounds__(256) void k_emb(
    const void* __restrict__ z,
    const void* __restrict__ iw1, const void* __restrict__ ib1,
    const void* __restrict__ iw2, const void* __restrict__ ib2,
    const void* __restrict__ probe,
    f16* __restrict__ semb)
{
    __shared__ u32 w1p[64*32];      // [kp<64][e<32]
    __shared__ u32 w2p[16*64];      // [kp<16][e<64]
    __shared__ u32 zp[4][2][64];    // z rows packed, 2 rows per wave pass
    __shared__ u32 x1p[4][2][16];   // layer-1 outs packed
    int F = detect_f32(probe);
    int tid = threadIdx.x;
    for (int i = tid; i < 2048; i += 256){
        int kp = i >> 5, e = i & 31;
        w1p[kp*32+e] = ld_pair(iw1, e*64 + kp, F);      // iw1 [32][128]
    }
    for (int i = tid; i < 1024; i += 256){
        int kp = i >> 6, e = i & 63;
        w2p[kp*64+e] = ld_pair(iw2, e*16 + kp, F);      // iw2 [64][32]
    }
    __syncthreads();
    int w = tid >> 6, lane = tid & 63;
    int rp = lane >> 5, ll = lane & 31;
    float b1v = ldin(ib1, ll, F);
    float b2v = ldin(ib2, lane, F);
    int rowbase = (blockIdx.x * 4 + w) * 8;
    #pragma unroll 1
    for (int pass = 0; pass < 4; pass++){
        int row = rowbase + pass*2 + rp;                // half-wave rp owns this row
        zp[w][rp][ll]    = ld_pair(z, row*64 + ll, F);
        zp[w][rp][ll+32] = ld_pair(z, row*64 + ll + 32, F);
        float y1 = b1v;
        #pragma unroll 8
        for (int kp = 0; kp < 64; kp++)
            y1 = fdot2u(zp[w][rp][kp], w1p[kp*32+ll], y1);
        float s = y1, q = y1*y1; wred32(s, q);
        float m = s*(1.f/32.f), v = q*(1.f/32.f)-m*m, rs = rsqrtf(fmaxf(v,0.f)+LN_EPS);
        float sv = lrelu((y1-m)*rs);
        float e0 = __shfl(sv, (lane & 32) + 2*(lane & 15));
        float e1 = __shfl(sv, (lane & 32) + 2*(lane & 15) + 1);
        if (ll < 16) x1p[w][rp][ll] = pk_h2(e0, e1);
        #pragma unroll
        for (int r2 = 0; r2 < 2; r2++){
            float y2 = b2v;
            #pragma unroll
            for (int kp = 0; kp < 16; kp++)
                y2 = fdot2u(x1p[w][r2][kp], w2p[kp*64+lane], y2);
            s = y2; q = y2*y2; wred64(s, q);
            m = s*(1.f/64.f); v = q*(1.f/64.f)-m*m; rs = rsqrtf(fmaxf(v,0.f)+LN_EPS);
            semb[(size_t)(rowbase + pass*2 + r2)*64 + lane] = (f16)lrelu((y2-m)*rs);
        }
    }
}

// ---------------- K3: MFMA bidirectional LN-GRU, both dirs fused in one block ----------
// grid 256, 768 thr = 12 waves. Waves 0-5 = dir 0, waves 6-11 = dir 1; each half
// is the proven 6-wave gate-split structure over 16 agents. Rationale: K3 is
// latency-bound (13.4 kcy/step vs ~2 kcy useful; 4 barriers/step; gate-masked
// phases run 2-of-6 waves). The two dir recurrences are independent -> fusing
// them doubles active waves per CU in EVERY phase (guaranteed co-residency,
// unlike the R6 2-block split which regressed). Joint __syncthreads couples the
// halves but work is symmetric, so lockstep is harmless.
// Wave wl owns M-tiles 4wl..4wl+3 -> gate = wl>>1 (r: 0,1; z: 2,3; n: 4,5).
// Verified gfx950 16x16x32 f16 fragment layouts (m89/m91/m120):
//   A[m=lane&15][k=quad*8+j], B[k=quad*8+j][n=lane&15], C col=lane&15 row=quad*4+reg.
__global__ __launch_bounds__(768) void k_gru_mfma(
    const f16* __restrict__ semb, const f16* __restrict__ disp,
    const void* __restrict__ wihA, const void* __restrict__ whhA,
    const void* __restrict__ bihA, const void* __restrict__ bhhA,
    const void* __restrict__ wihB, const void* __restrict__ whhB,
    const void* __restrict__ bihB, const void* __restrict__ bhhB,
    const void* __restrict__ probe,
    f16* __restrict__ hencF, f16* __restrict__ hencB)
{
    __shared__ __align__(16) f16 hbuf[2][16][136];      // [dir][agent][d]
    __shared__ __align__(16) f16 xbuf[2][2][16][72];    // [dir][dbuf][agent][d]
    __shared__ __align__(16) f16 rzbuf[2][2][16][136];  // [dir][gate][agent][d]
    __shared__ __align__(16) float bias1[2][384];
    __shared__ __align__(16) float bias2[2][128];
    __shared__ float redS[2][6][16], redQ[2][6][16];
    int F = detect_f32(probe);
    int tid = threadIdx.x;
    int w = tid >> 6, lane = tid & 63;
    int dirg = (w >= 6) ? 1 : 0;
    int wl = w - dirg*6;                 // wave index within dir half [0,6)
    int lt = tid - dirg*384;             // thread index within dir half [0,384)
    int quad = lane >> 4, l15 = lane & 15;
    int gate = wl >> 1;
    const void* wih = dirg ? wihB : wihA;  const void* whh = dirg ? whhB : whhA;
    const void* bih = dirg ? bihB : bihA;  const void* bhh = dirg ? bhhB : bhhA;
    f16* henc = dirg ? hencB : hencF;

    // ---- A fragments: Af[mt][kt]; lane supplies A[m=l15][k=quad*8+j] ----
    f16x8 Af[4][6];
    if (F){
        #pragma unroll
        for (int mt = 0; mt < 4; mt++){
            int u = (wl*4+mt)*16 + l15;
            #pragma unroll
            for (int kt = 0; kt < 6; kt++){
                const float* src = (kt < 4)
                    ? ((const float*)whh + (size_t)u*128 + kt*32 + quad*8)
                    : ((const float*)wih + (size_t)u*64 + (kt-4)*32 + quad*8);
                f16x8 v;
                #pragma unroll
                for (int j = 0; j < 8; j++) v[j] = (f16)src[j];
                Af[mt][kt] = v;
            }
        }
    } else {
        #pragma unroll
        for (int mt = 0; mt < 4; mt++){
            int u = (wl*4+mt)*16 + l15;
            #pragma unroll
            for (int kt = 0; kt < 6; kt++){
                const u16* src = (kt < 4)
                    ? ((const u16*)whh + (size_t)u*128 + kt*32 + quad*8)
                    : ((const u16*)wih + (size_t)u*64 + (kt-4)*32 + quad*8);
                f16x8 v;
                #pragma unroll
                for (int j = 0; j < 8; j++) v[j] = (f16)bf2f(src[j]);
                Af[mt][kt] = v;
            }
        }
    }
    // biases (each dir half stages its own; lt covers [0,384) exactly)
    {
        float bi = ldin(bih, lt, F), bh = ldin(bhh, lt, F);
        bias1[dirg][lt] = (lt < 256) ? (bi + bh) : bi;
        if (lt >= 256) bias2[dirg][lt - 256] = bh;
    }

    int nb = blockIdx.x * 16;
    // stage h0 (from disp) and x(t0), per dir half
    for (int i = lt; i < 256; i += 384){
        int a = i >> 4, c = i & 15;
        u32x4 v = *(const u32x4*)(disp + ((size_t)dirg*NAG + nb + a)*128 + c*8);
        *(u32x4*)&hbuf[dirg][a][c*8] = v;
    }
    int tx0 = dirg ? (T_STEPS-1) : 0;
    for (int i = lt; i < 128; i += 384){
        int a = i >> 3, c = i & 7;
        u32x4 v = *(const u32x4*)(semb + ((size_t)tx0*NAG + nb + a)*64 + c*8);
        *(u32x4*)&xbuf[dirg][0][a][c*8] = v;
    }
    __syncthreads();

    #pragma unroll 1
    for (int t = 0; t < T_STEPS; t++){
        int tx = dirg ? (T_STEPS-1-t) : t;
        int cur = t & 1;
        // ---- C init from biases ----
        f32x4v C0[4], C1[4];
        #pragma unroll
        for (int mt = 0; mt < 4; mt++){
            f32x4v b1f = *(const f32x4v*)&bias1[dirg][(wl*4+mt)*16 + quad*4];
            if (gate < 2){
                C0[mt] = b1f;                               // combined bias
                C1[mt] = b1f;                               // unused on this path
            } else {
                f32x4v b2f = *(const f32x4v*)&bias2[dirg][((wl&1)*4+mt)*16 + quad*4];
                C0[mt] = b2f;                               // hh + bhh
                C1[mt] = b1f;                               // ih + bih
            }
        }
        // ---- MFMA phase ----
        {
            int ag = l15;
            f16x8 B0 = *(const f16x8*)&hbuf[dirg][ag][0*32 + quad*8];
            f16x8 B1 = *(const f16x8*)&hbuf[dirg][ag][1*32 + quad*8];
            f16x8 B2 = *(const f16x8*)&hbuf[dirg][ag][2*32 + quad*8];
            f16x8 B3 = *(const f16x8*)&hbuf[dirg][ag][3*32 + quad*8];
            f16x8 B4 = *(const f16x8*)&xbuf[dirg][cur][ag][0*32 + quad*8];
            f16x8 B5 = *(const f16x8*)&xbuf[dirg][cur][ag][1*32 + quad*8];
            if (gate < 2){
                #pragma unroll
                for (int mt = 0; mt < 4; mt++){
                    f32x4v c = C0[mt];
                    c = __builtin_amdgcn_mfma_f32_16x16x32_f16(Af[mt][0], B0, c, 0, 0, 0);
                    c = __builtin_amdgcn_mfma_f32_16x16x32_f16(Af[mt][1], B1, c, 0, 0, 0);
                    c = __builtin_amdgcn_mfma_f32_16x16x32_f16(Af[mt][2], B2, c, 0, 0, 0);
                    c = __builtin_amdgcn_mfma_f32_16x16x32_f16(Af[mt][3], B3, c, 0, 0, 0);
                    c = __builtin_amdgcn_mfma_f32_16x16x32_f16(Af[mt][4], B4, c, 0, 0, 0);
                    c = __builtin_amdgcn_mfma_f32_16x16x32_f16(Af[mt][5], B5, c, 0, 0, 0);
                    C0[mt] = c;
                }
            } else {
                #pragma unroll
                for (int mt = 0; mt < 4; mt++){
                    f32x4v c = C0[mt];
                    c = __builtin_amdgcn_mfma_f32_16x16x32_f16(Af[mt][0], B0, c, 0, 0, 0);
                    c = __builtin_amdgcn_mfma_f32_16x16x32_f16(Af[mt][1], B1, c, 0, 0, 0);
                    c = __builtin_amdgcn_mfma_f32_16x16x32_f16(Af[mt][2], B2, c, 0, 0, 0);
                    c = __builtin_amdgcn_mfma_f32_16x16x32_f16(Af[mt][3], B3, c, 0, 0, 0);
                    C0[mt] = c;
                    f32x4v d = C1[mt];
                    d = __builtin_amdgcn_mfma_f32_16x16x32_f16(Af[mt][4], B4, d, 0, 0, 0);
                    d = __builtin_amdgcn_mfma_f32_16x16x32_f16(Af[mt][5], B5, d, 0, 0, 0);
                    C1[mt] = d;
                }
            }
        }
        // ---- phase1 tail: r/z LN partials; n-waves stage next x ----
        if (gate < 2){
            float s = 0.f, q = 0.f;
            #pragma unroll
            for (int mt = 0; mt < 4; mt++)
                #pragma unroll
                for (int r = 0; r < 4; r++){
                    float v = C0[mt][r];
                    s += v; q += v*v;
                }
            s += __shfl_xor(s, 16); q += __shfl_xor(q, 16);
            s += __shfl_xor(s, 32); q += __shfl_xor(q, 32);
            if (lane < 16){ redS[dirg][wl][l15] = s; redQ[dirg][wl][l15] = q; }
        } else {
            if (t + 1 < T_STEPS){
                int txn = dirg ? (T_STEPS-2-t) : (t+1);
                int i = (wl-4)*64 + lane;                  // [0,128)
                int a = i >> 3, c = i & 7;
                u32x4 v = *(const u32x4*)(semb + ((size_t)txn*NAG + nb + a)*64 + c*8);
                *(u32x4*)&xbuf[dirg][cur^1][a][c*8] = v;
            }
        }
        __syncthreads();                                   // bar1
        // ---- phase2: r/z finalize LN + sigmoid -> rzbuf ----
        if (gate < 2){
            int ag = l15;
            float s = redS[dirg][wl][ag] + redS[dirg][wl^1][ag];
            float q = redQ[dirg][wl][ag] + redQ[dirg][wl^1][ag];
            float m = s*(1.f/128.f), vv = q*(1.f/128.f) - m*m;
            float rs = rsqrtf(fmaxf(vv, 0.f) + LN_EPS);
            #pragma unroll
            for (int mt = 0; mt < 4; mt++){
                float g0 = sigm((C0[mt][0] - m)*rs);
                float g1 = sigm((C0[mt][1] - m)*rs);
                float g2 = sigm((C0[mt][2] - m)*rs);
                float g3 = sigm((C0[mt][3] - m)*rs);
                int dg = ((wl&1)*4 + mt)*16 + quad*4;
                u32x2v p; p.x = pk_h2(g0, g1); p.y = pk_h2(g2, g3);
                *(u32x2v*)&rzbuf[dirg][gate][ag][dg] = p;
            }
        }
        __syncthreads();                                   // bar2
        // ---- phase3: n-pre = ih + r * hh ; LN partials ----
        if (gate == 2){
            int ag = l15;
            float s = 0.f, q = 0.f;
            #pragma unroll
            for (int mt = 0; mt < 4; mt++){
                int dg = ((wl&1)*4 + mt)*16 + quad*4;
                u32x2v rp = *(const u32x2v*)&rzbuf[dirg][0][ag][dg];
                f32x2 ra = unpk_h2(rp.x), rb = unpk_h2(rp.y);
                float p0 = C1[mt][0] + ra[0]*C0[mt][0];
                float p1 = C1[mt][1] + ra[1]*C0[mt][1];
                float p2 = C1[mt][2] + rb[0]*C0[mt][2];
                float p3 = C1[mt][3] + rb[1]*C0[mt][3];
                C0[mt][0] = p0; C0[mt][1] = p1;
                C0[mt][2] = p2; C0[mt][3] = p3;
                s += p0 + p1 + p2 + p3;
                q += p0*p0 + p1*p1 + p2*p2 + p3*p3;
            }
            s += __shfl_xor(s, 16); q += __shfl_xor(q, 16);
            s += __shfl_xor(s, 32); q += __shfl_xor(q, 32);
            if (lane < 16){ redS[dirg][wl][ag] = s; redQ[dirg][wl][ag] = q; }
        }
        __syncthreads();                                   // bar3
        // ---- phase4: n finalize, h update, write back ----
        if (gate == 2){
            int ag = l15;
            float s = redS[dirg][4][ag] + redS[dirg][5][ag];
            float q = redQ[dirg][4][ag] + redQ[dirg][5][ag];
            float m = s*(1.f/128.f), vv = q*(1.f/128.f) - m*m;
            float rs = rsqrtf(fmaxf(vv, 0.f) + LN_EPS);
            #pragma unroll
            for (int mt = 0; mt < 4; mt++){
                int dg = ((wl&1)*4 + mt)*16 + quad*4;
                float n0 = ftanh((C0[mt][0] - m)*rs);
                float n1 = ftanh((C0[mt][1] - m)*rs);
                float n2 = ftanh((C0[mt][2] - m)*rs);
                float n3 = ftanh((C0[mt][3] - m)*rs);
                u32x2v zp = *(const u32x2v*)&rzbuf[dirg][1][ag][dg];
                f32x2 za = unpk_h2(zp.x), zb = unpk_h2(zp.y);
                u32x2v hp = *(const u32x2v*)&hbuf[dirg][ag][dg];
                f32x2 ha = unpk_h2(hp.x), hb2 = unpk_h2(hp.y);
                float h0 = (1.f - za[0])*n0 + za[0]*ha[0];
                float h1 = (1.f - za[1])*n1 + za[1]*ha[1];
                float h2 = (1.f - zb[0])*n2 + zb[0]*hb2[0];
                float h3 = (1.f - zb[1])*n3 + zb[1]*hb2[1];
                u32x2v o; o.x = pk_h2(h0, h1); o.y = pk_h2(h2, h3);
                *(u32x2v*)&hbuf[dirg][ag][dg] = o;
                *(u32x2v*)(henc + ((size_t)tx*NAG + nb + ag)*128 + dg) = o;
            }
        }
        __syncthreads();                                   // bar4
    }
}

// ---------------- K4: fused post-GRU: seq -> pairwise(factored) -> out head ----------------
// Pairwise LN restructured: group g = lane>>3 owns agent i=g (8 dims/lane over
// 8 lanes); 8 pairs run in parallel per round, reduce = 3 shfl_xor steps.
__global__ __launch_bounds__(256) void k_post(
    const f16* __restrict__ hf, const f16* __restrict__ hb,
    const void* __restrict__ sw, const void* __restrict__ sb,
    const void* __restrict__ mw, const void* __restrict__ mb,
    const void* __restrict__ ow1, const void* __restrict__ ob1,
    const void* __restrict__ ow2, const void* __restrict__ ob2,
    const void* __restrict__ probe,
    void* __restrict__ outp)
{
    __shared__ u32 swp[64*64];     // [kp][unit]
    __shared__ u32 mwp[32*64];     // [kp][unit]
    __shared__ u32 w1p[64*32];     // [kp][e<32]
    __shared__ __align__(16) u32 xr[4][8][64];   // x=(hf+hb)/2 pairs; later uuT alias
    __shared__ __align__(16) u32 fr[4][8][64];   // full=[seq|ave] pairs
    int F = detect_f32(probe);
    int tid = threadIdx.x;
    for (int i = tid; i < 4096; i += 256){
        int u = i & 63, kp = i >> 6;
        swp[kp*64+u] = ld_pair(sw, u*64 + kp, F);      // sw [64][128]
    }
    for (int i = tid; i < 2048; i += 256){
        int u = i & 63, kp = i >> 6;   // kp < 32
        mwp[kp*64+u] = ld_pair(mw, u*32 + kp, F);      // mw [64][64]
    }
    for (int i = tid; i < 2048; i += 256){
        int e = i & 31, kp = i >> 5;   // kp < 64
        w1p[kp*32+e] = ld_pair(ow1, e*64 + kp, F);     // ow1 [32][128]
    }
    int w = tid >> 6, lane = tid & 63;
    int unit = blockIdx.x*4 + w;        // t*512 + scene
    int t = unit >> 9, sc = unit & 511;
    int base = sc * 8;
    size_t rowbase = (size_t)t*NAG + base;
    const u32* hfu = (const u32*)hf;
    const u32* hbu = (const u32*)hb;
    #pragma unroll
    for (int r = 0; r < 8; r++){
        f32x2 a = unpk_h2(hfu[(rowbase + r)*64 + lane]);
        f32x2 b = unpk_h2(hbu[(rowbase + r)*64 + lane]);
        xr[w][r][lane] = pk_h2(0.5f*(a[0]+b[0]), 0.5f*(a[1]+b[1]));
    }
    __syncthreads();

    float bs = ldin(sb, lane, F);
    float y[8];
    #pragma unroll
    for (int r = 0; r < 8; r++) y[r] = bs;
    for (int kp = 0; kp < 64; kp++){
        u32 wv = swp[kp*64 + lane];
        #pragma unroll
        for (int r = 0; r < 8; r++) y[r] = fdot2u(xr[w][r][kp], wv, y[r]);
    }
    #pragma unroll
    for (int r = 0; r < 8; r++){
        float s = y[r], q = y[r]*y[r]; wred64(s, q);
        float m = s*(1.f/64.f), v = q*(1.f/64.f) - m*m;
        float rs = rsqrtf(fmaxf(v, 0.f) + LN_EPS);
        float sv = lrelu((y[r] - m)*rs);
        float e0 = __shfl(sv, 2*(lane & 31)), e1 = __shfl(sv, 2*(lane & 31) + 1);
        if (lane < 32) fr[w][r][lane] = pk_h2(e0, e1);
    }
    // ---- uu = seq @ mw.T (no bias); unit = lane ----
    float uu[8];
    #pragma unroll
    for (int r = 0; r < 8; r++) uu[r] = 0.f;
    for (int kp = 0; kp < 32; kp++){
        u32 wv = mwp[kp*64 + lane];
        #pragma unroll
        for (int r = 0; r < 8; r++) uu[r] = fdot2u(fr[w][r][kp], wv, uu[r]);
    }
    // ---- transpose uu -> uuT (aliases xr[w], which is dead now) ----
    // row r dim d stored at pos (d + 8r) & 63 (rotate-swizzle, bank-friendly)
    float* uuT = (float*)&xr[w][0][0];
    #pragma unroll
    for (int r = 0; r < 8; r++)
        uuT[r*64 + ((lane + r*8) & 63)] = uu[r];
    // ---- pairwise: group g owns agent i=g; lane l=lane&7 owns dims 8l..8l+7 ----
    int g = lane >> 3, l8 = (lane & 7) * 8;
    float bmv[8];
    #pragma unroll
    for (int d = 0; d < 8; d++) bmv[d] = ldin(mb, l8 + d, F);
    const f32x4v* up = (const f32x4v*)&uuT[g*64 + ((l8 + g*8) & 63)];
    f32x4v ui0 = up[0], ui1 = up[1];
    float acc[8];
    #pragma unroll
    for (int d = 0; d < 8; d++) acc[d] = 0.f;
    #pragma unroll
    for (int rr = 0; rr < 7; rr++){
        int j = (g + 1 + rr) & 7;
        const f32x4v* jp = (const f32x4v*)&uuT[j*64 + ((l8 + j*8) & 63)];
        f32x4v uj0 = jp[0], uj1 = jp[1];
        float p[8]; float s = 0.f, q = 0.f;
        #pragma unroll
        for (int d = 0; d < 4; d++){
            float v0 = ui0[d] - uj0[d] + bmv[d];
            float v1 = ui1[d] - uj1[d] + bmv[4+d];
            p[d] = v0; p[4+d] = v1;
            s += v0 + v1; q += v0*v0 + v1*v1;
        }
        #pragma unroll
        for (int m = 1; m < 8; m <<= 1){ s += __shfl_xor(s, m); q += __shfl_xor(q, m); }
        float mm = s*(1.f/64.f), vv = q*(1.f/64.f) - mm*mm;
        float rs = rsqrtf(fmaxf(vv, 0.f) + LN_EPS);
        #pragma unroll
        for (int d = 0; d < 8; d++) acc[d] += lrelu((p[d] - mm)*rs);
    }
    // ave -> fr[w][g][32 + l*4 ..], pairs of dims (8l+2k, 8l+2k+1)
    u32x4 av;
    #pragma unroll
    for (int k = 0; k < 4; k++) av[k] = pk_h2(acc[2*k]*(1.f/7.f), acc[2*k+1]*(1.f/7.f));
    *(u32x4*)&fr[w][g][32 + (lane & 7)*4] = av;
    // ---- head: full=[seq|ave] -> block(ow1) -> Linear(ow2) -> tanh ----
    int ll = lane & 31;
    float b1v = ldin(ob1, ll, F);
    float o20 = ldin(ow2, ll, F);
    float o21 = ldin(ow2, 32 + ll, F);
    float bo0 = ldin(ob2, 0, F), bo1 = ldin(ob2, 1, F);
    #pragma unroll
    for (int rp = 0; rp < 4; rp++){
        int r = rp*2 + (lane >> 5);
        float h = b1v;
        for (int kp = 0; kp < 64; kp++)
            h = fdot2u(fr[w][r][kp], w1p[kp*32 + ll], h);
        float s = h, q = h*h; wred32(s, q);
        float m = s*(1.f/32.f), v = q*(1.f/32.f) - m*m;
        float rs = rsqrtf(fmaxf(v, 0.f) + LN_EPS);
        float hv = lrelu((h - m)*rs);
        float p0 = hv*o20, p1 = hv*o21;
        wred32(p0, p1);
        if (ll == 0){
            int n = base + r;
            float v0 = ftanh(p0 + bo0), v1 = ftanh(p1 + bo1);
            size_t i0 = (size_t)(n*2)*T_STEPS + t, i1 = (size_t)(n*2+1)*T_STEPS + t;
            if (F){ ((float*)outp)[i0] = v0; ((float*)outp)[i1] = v1; }
            else  { ((u16*)outp)[i0] = f2bf(v0); ((u16*)outp)[i1] = f2bf(v1); }
        }
    }
}

extern "C" void kernel_launch(void* const* d_in, const int* in_sizes, int n_in,
                              void* d_out, int out_size, void* d_ws, size_t ws_size,
                              hipStream_t stream)
{
    const void* cond = d_in[0];
    const void* z    = d_in[1];
    const void* cw1  = d_in[2];
    const void* cb1  = d_in[3];
    const void* cw2  = d_in[4];
    const void* cb2  = d_in[5];
    const void* cbw1 = d_in[6];
    const void* cbb1 = d_in[7];
    const void* cbw2 = d_in[8];
    const void* cbb2 = d_in[9];
    const void* iw1  = d_in[10];
    const void* ib1  = d_in[11];
    const void* iw2  = d_in[12];
    const void* ib2  = d_in[13];
    const void* wih  = d_in[14];
    const void* whh  = d_in[15];
    const void* bih  = d_in[16];
    const void* bhh  = d_in[17];
    const void* wihb = d_in[18];
    const void* whhb = d_in[19];
    const void* bihb = d_in[20];
    const void* bhhb = d_in[21];
    const void* sw   = d_in[22];
    const void* sb   = d_in[23];
    const void* mw   = d_in[24];
    const void* mb   = d_in[25];
    const void* ow1  = d_in[26];
    const void* ob1  = d_in[27];
    const void* ow2  = d_in[28];
    const void* ob2  = d_in[29];
    const void* probe = whh;   // dtype-detection probe buffer

    char* ws = (char*)d_ws;
    size_t off = 0;
    f16* disp  = (f16*)(ws + off); off += (size_t)2*NAG*128*2;          //  2 MB
    f16* semb  = (f16*)(ws + off); off += (size_t)T_STEPS*NAG*64*2;     // 15.7 MB
    f16* hencF = (f16*)(ws + off); off += (size_t)T_STEPS*NAG*128*2;    // 31.5 MB
    f16* hencB = (f16*)(ws + off); off += (size_t)T_STEPS*NAG*128*2;    // 31.5 MB

    k_cond<<<dim3(NAG/8,2), 256, 0, stream>>>(cond, cw1,cb1,cw2,cb2, cbw1,cbb1,cbw2,cbb2, probe, disp);
    k_emb<<<3840, 256, 0, stream>>>(z, iw1,ib1,iw2,ib2, probe, semb);
    k_gru_mfma<<<NAG/16, 768, 0, stream>>>(semb, disp, wih,whh,bih,bhh, wihb,whhb,bihb,bhhb, probe, hencF, hencB);
    k_post<<<3840, 256, 0, stream>>>(hencF, hencB, sw,sb, mw,mb, ow1,ob1,ow2,ob2, probe, d_out);
}

// Round 12
// 511.883 us; speedup vs baseline: 1.0469x; 1.0469x over previous
//
#include <hip/hip_runtime.h>
#include <hip/hip_bf16.h>

typedef unsigned int u32;
typedef unsigned short u16;
typedef _Float16 f16;
typedef float f32x2 __attribute__((ext_vector_type(2)));
typedef _Float16 f16x2 __attribute__((ext_vector_type(2)));
typedef u32 u32x4 __attribute__((ext_vector_type(4)));
typedef u32 u32x2v __attribute__((ext_vector_type(2)));
typedef _Float16 f16x8 __attribute__((ext_vector_type(8)));
typedef float f32x4v __attribute__((ext_vector_type(4)));

#define LN_EPS 1e-5f
#define T_STEPS 30
#define NAG 4096

__device__ __forceinline__ float bf2f(u16 v){
    union { u32 u; float f; } c; c.u = ((u32)v) << 16; return c.f;
}
__device__ __forceinline__ u16 f2bf(float f){
    union { float f; u32 u; } c; c.f = f;
    return (u16)((c.u + 0x7FFFu + ((c.u >> 16) & 1u)) >> 16);
}
__device__ __forceinline__ u32 pk_h2(float a, float b){
    f16x2 h; h[0] = (f16)a; h[1] = (f16)b;
    return __builtin_bit_cast(u32, h);
}
__device__ __forceinline__ f32x2 unpk_h2(u32 p){
    f16x2 h = __builtin_bit_cast(f16x2, p);
    f32x2 r; r[0] = (float)h[0]; r[1] = (float)h[1]; return r;
}
__device__ __forceinline__ u32 bfp2h2(u32 p){
    union { u32 u; float f; } a, b;
    a.u = p << 16; b.u = p & 0xFFFF0000u;
    return pk_h2(a.f, b.f);
}
__device__ __forceinline__ float fdot2u(u32 a, u32 b, float c){
    return __builtin_amdgcn_fdot2(__builtin_bit_cast(f16x2, a),
                                  __builtin_bit_cast(f16x2, b), c, false);
}
// dtype probe: fp32 buffers read as u16 have random mantissa halves at even
// positions (~50% decode to |x|>=128); bf16 weight buffers (|w| < 1) never do.
__device__ __forceinline__ int detect_f32(const void* probe){
    const u16* p = (const u16*)probe;
    int bad = 0;
    #pragma unroll
    for (int i = 0; i < 32; i++){
        u32 e = (p[2*i] >> 7) & 0xFF;
        bad += (e >= 0x86) ? 1 : 0;
    }
    return bad > 4;
}
__device__ __forceinline__ float ldin(const void* p, int i, int F){
    float v;
    if (F) v = ((const float*)p)[i];
    else   v = bf2f(((const u16*)p)[i]);
    return v;
}
__device__ __forceinline__ u32 ld_pair(const void* p, int pairIdx, int F){
    if (F){ const float* f = (const float*)p; return pk_h2(f[2*pairIdx], f[2*pairIdx+1]); }
    return bfp2h2(((const u32*)p)[pairIdx]);
}
__device__ __forceinline__ void wred64(float& s, float& q){
    #pragma unroll
    for (int m = 1; m < 64; m <<= 1){ s += __shfl_xor(s, m); q += __shfl_xor(q, m); }
}
__device__ __forceinline__ void wred32(float& s, float& q){
    #pragma unroll
    for (int m = 1; m < 32; m <<= 1){ s += __shfl_xor(s, m); q += __shfl_xor(q, m); }
}
__device__ __forceinline__ float lrelu(float x){ return fmaxf(x, 0.1f * x); }
__device__ __forceinline__ float sigm(float x){ return 1.0f / (1.0f + __expf(-x)); }
__device__ __forceinline__ float ftanh(float x){ return 1.0f - 2.0f / (1.0f + __expf(2.0f * x)); }
__device__ __forceinline__ void ln128(float a0, float a1, float& o0, float& o1){
    float s = a0 + a1, q = a0*a0 + a1*a1;
    wred64(s, q);
    float m = s * (1.f/128.f), v = q * (1.f/128.f) - m*m;
    float rs = rsqrtf(fmaxf(v, 0.f) + LN_EPS);
    o0 = (a0 - m) * rs; o1 = (a1 - m) * rs;
}
// Light barrier: LDS-only drain + hw barrier. Avoids __syncthreads()'s
// vmcnt(0) drain so global loads/stores stay in flight across barriers.
// "memory" clobber = compiler fence; sched_barrier(0) pins backend motion
// (guide rule #18).
#define LBAR() do { \
    asm volatile("s_waitcnt lgkmcnt(0)" ::: "memory"); \
    __builtin_amdgcn_s_barrier(); \
    __builtin_amdgcn_sched_barrier(0); \
} while (0)

// ---------------- K1: cond embeddings (both dirs): [N,2] -> 64 -> 128 ----------------
// 256 thr / 8 agents per block; w2 staged TRANSPOSED in LDS (coalesced global
// reads; +2-pad stride 130, reads conflict-free). One barrier total.
__global__ __launch_bounds__(256) void k_cond(
    const void* __restrict__ cond,
    const void* __restrict__ w1a, const void* __restrict__ b1a,
    const void* __restrict__ w2a, const void* __restrict__ b2a,
    const void* __restrict__ w1b, const void* __restrict__ b1b,
    const void* __restrict__ w2b, const void* __restrict__ b2b,
    const void* __restrict__ probe,
    f16* __restrict__ disp)
{
    __shared__ float w2T[64*130];     // [k][u], padded stride 130 (33.3 KB)
    __shared__ float w1s[128], b1s[64], b2s[128];
    __shared__ float x1s[4][64];      // layer-1 outs, per wave
    int F = detect_f32(probe);
    int tid = threadIdx.x, dir = blockIdx.y;
    const void* w1 = dir ? w1b : w1a; const void* b1 = dir ? b1b : b1a;
    const void* w2 = dir ? w2b : w2a; const void* b2 = dir ? b2b : b2a;
    // stage w2 transposed: global idx i = u*64 + k, k fastest -> coalesced reads
    for (int i = tid; i < 8192; i += 256){
        int u = i >> 6, k = i & 63;
        w2T[k*130 + u] = ldin(w2, i, F);
    }
    if (tid < 128) w1s[tid] = ldin(w1, tid, F);
    else           b2s[tid - 128] = ldin(b2, tid - 128, F);
    if (tid < 64)  b1s[tid] = ldin(b1, tid, F);
    __syncthreads();

    int w = tid >> 6, lane = tid & 63;
    int nb = blockIdx.x * 8 + w * 2;
    #pragma unroll
    for (int a = 0; a < 2; a++){
        int n = nb + a;
        float c0 = ldin(cond, n*2, F), c1 = ldin(cond, n*2+1, F);
        float y = w1s[lane*2] * c0 + w1s[lane*2+1] * c1 + b1s[lane];
        float s = y, q = y*y; wred64(s, q);
        float m = s * (1.f/64.f), v = q * (1.f/64.f) - m*m;
        float rs = rsqrtf(fmaxf(v, 0.f) + LN_EPS);
        x1s[w][lane] = lrelu((y - m) * rs);   // per-wave buffer, no barrier needed
        float y0 = b2s[lane], y1 = b2s[lane + 64];
        #pragma unroll 8
        for (int k = 0; k < 64; k++){
            float xv = x1s[w][k];
            y0 = fmaf(xv, w2T[k*130 + lane], y0);
            y1 = fmaf(xv, w2T[k*130 + 64 + lane], y1);
        }
        float o0, o1; ln128(y0, y1, o0, o1);
        f16* dp = disp + ((size_t)dir * NAG + n) * 128;
        dp[lane] = (f16)lrelu(o0);
        dp[lane+64] = (f16)lrelu(o1);
    }
}

// ---------------- K2: scene embedding: z[T,N,128] -> 32 -> 64 (packed fdot2) ----------
__global__ __launch_bounds__(256) void k_emb(
    const void* __restrict__ z,
    const void* __restrict__ iw1, const void* __restrict__ ib1,
    const void* __restrict__ iw2, const void* __restrict__ ib2,
    const void* __restrict__ probe,
    f16* __restrict__ semb)
{
    __shared__ u32 w1p[64*32];      // [kp<64][e<32]
    __shared__ u32 w2p[16*64];      // [kp<16][e<64]
    __shared__ u32 zp[4][2][64];    // z rows packed, 2 rows per wave pass
    __shared__ u32 x1p[4][2][16];   // layer-1 outs packed
    int F = detect_f32(probe);
    int tid = threadIdx.x;
    for (int i = tid; i < 2048; i += 256){
        int kp = i >> 5, e = i & 31;
        w1p[kp*32+e] = ld_pair(iw1, e*64 + kp, F);      // iw1 [32][128]
    }
    for (int i = tid; i < 1024; i += 256){
        int kp = i >> 6, e = i & 63;
        w2p[kp*64+e] = ld_pair(iw2, e*16 + kp, F);      // iw2 [64][32]
    }
    __syncthreads();
    int w = tid >> 6, lane = tid & 63;
    int rp = lane >> 5, ll = lane & 31;
    float b1v = ldin(ib1, ll, F);
    float b2v = ldin(ib2, lane, F);
    int rowbase = (blockIdx.x * 4 + w) * 8;
    #pragma unroll 1
    for (int pass = 0; pass < 4; pass++){
        int row = rowbase + pass*2 + rp;                // half-wave rp owns this row
        zp[w][rp][ll]    = ld_pair(z, row*64 + ll, F);
        zp[w][rp][ll+32] = ld_pair(z, row*64 + ll + 32, F);
        float y1 = b1v;
        #pragma unroll 8
        for (int kp = 0; kp < 64; kp++)
            y1 = fdot2u(zp[w][rp][kp], w1p[kp*32+ll], y1);
        float s = y1, q = y1*y1; wred32(s, q);
        float m = s*(1.f/32.f), v = q*(1.f/32.f)-m*m, rs = rsqrtf(fmaxf(v,0.f)+LN_EPS);
        float sv = lrelu((y1-m)*rs);
        float e0 = __shfl(sv, (lane & 32) + 2*(lane & 15));
        float e1 = __shfl(sv, (lane & 32) + 2*(lane & 15) + 1);
        if (ll < 16) x1p[w][rp][ll] = pk_h2(e0, e1);
        #pragma unroll
        for (int r2 = 0; r2 < 2; r2++){
            float y2 = b2v;
            #pragma unroll
            for (int kp = 0; kp < 16; kp++)
                y2 = fdot2u(x1p[w][r2][kp], w2p[kp*64+lane], y2);
            s = y2; q = y2*y2; wred64(s, q);
            m = s*(1.f/64.f); v = q*(1.f/64.f)-m*m; rs = rsqrtf(fmaxf(v,0.f)+LN_EPS);
            semb[(size_t)(rowbase + pass*2 + r2)*64 + lane] = (f16)lrelu((y2-m)*rs);
        }
    }
}

// ---------------- K3: MFMA bidirectional LN-GRU ----------------
// R3-winner geometry (the measured best: 168 us): grid (128,2), 32 agents/block,
// 384 thr = 6 waves. [R6 2-block split: 195 us; R9 12-wave dir-fusion: 197 us
// despite 2x occupancy -> K3 is NOT TLP-starved; per-wave work per barrier
// crossing is what matters.]
// This round: barrier surgery. __syncthreads() drains vmcnt(0) at all 4 barriers
// per step, exposing the semb prefetch latency (issued phase1, drained bar1)
// and henc store retires. Replaced with LBAR (lgkmcnt-only) and the prefetch
// LOAD hoisted to the step top (regs), ds_write deferred to phase2 where
// n-waves are idle -> ~2 kcy of MFMA/LN work hides the load latency.
// Wave w owns M-tiles 4w..4w+3 -> gate = w>>1 (r: w0,1; z: w2,3; n: w4,5).
// Verified gfx950 16x16x32 f16 fragment layouts (m89/m91/m120):
//   A[m=lane&15][k=quad*8+j], B[k=quad*8+j][n=lane&15], C col=lane&15 row=quad*4+reg.
__global__ __launch_bounds__(384) void k_gru_mfma(
    const f16* __restrict__ semb, const f16* __restrict__ disp,
    const void* __restrict__ wihA, const void* __restrict__ whhA,
    const void* __restrict__ bihA, const void* __restrict__ bhhA,
    const void* __restrict__ wihB, const void* __restrict__ whhB,
    const void* __restrict__ bihB, const void* __restrict__ bhhB,
    const void* __restrict__ probe,
    f16* __restrict__ hencF, f16* __restrict__ hencB)
{
    __shared__ __align__(16) f16 hbuf[32][136];      // h per agent (pad 8 f16)
    __shared__ __align__(16) f16 xbuf[2][32][72];    // x per agent, double-buffered
    __shared__ __align__(16) f16 rzbuf[2][32][136];  // r,z values [gate][agent][d]
    __shared__ __align__(16) float bias1[384];       // u<256: bih+bhh; u>=256: bih
    __shared__ __align__(16) float bias2[128];       // bhh for n-units
    __shared__ float redS[6][32], redQ[6][32];
    int F = detect_f32(probe);
    int tid = threadIdx.x, dir = blockIdx.y;
    int w = tid >> 6, lane = tid & 63;
    int quad = lane >> 4, l15 = lane & 15;
    int gate = w >> 1;
    const void* wih = dir ? wihB : wihA;  const void* whh = dir ? whhB : whhA;
    const void* bih = dir ? bihB : bihA;  const void* bhh = dir ? bhhB : bhhA;
    f16* henc = dir ? hencB : hencF;

    // ---- A fragments: Af[mt][kt]; lane supplies A[m=l15][k=quad*8+j] ----
    f16x8 Af[4][6];
    if (F){
        #pragma unroll
        for (int mt = 0; mt < 4; mt++){
            int u = (w*4+mt)*16 + l15;
            #pragma unroll
            for (int kt = 0; kt < 6; kt++){
                const float* src = (kt < 4)
                    ? ((const float*)whh + (size_t)u*128 + kt*32 + quad*8)
                    : ((const float*)wih + (size_t)u*64 + (kt-4)*32 + quad*8);
                f16x8 v;
                #pragma unroll
                for (int j = 0; j < 8; j++) v[j] = (f16)src[j];
                Af[mt][kt] = v;
            }
        }
    } else {
        #pragma unroll
        for (int mt = 0; mt < 4; mt++){
            int u = (w*4+mt)*16 + l15;
            #pragma unroll
            for (int kt = 0; kt < 6; kt++){
                const u16* src = (kt < 4)
                    ? ((const u16*)whh + (size_t)u*128 + kt*32 + quad*8)
                    : ((const u16*)wih + (size_t)u*64 + (kt-4)*32 + quad*8);
                f16x8 v;
                #pragma unroll
                for (int j = 0; j < 8; j++) v[j] = (f16)bf2f(src[j]);
                Af[mt][kt] = v;
            }
        }
    }
    // biases -> LDS (keeps VGPR pressure down; C-frags init from these per step)
    if (tid < 384){
        float bi = ldin(bih, tid, F), bh = ldin(bhh, tid, F);
        bias1[tid] = (tid < 256) ? (bi + bh) : bi;
        if (tid >= 256) bias2[tid - 256] = bh;
    }

    int nb = blockIdx.x * 32;
    // stage h0 (from disp) and x(t0)
    for (int i = tid; i < 512; i += 384){
        int a = i >> 4, c = i & 15;
        u32x4 v = *(const u32x4*)(disp + ((size_t)dir*NAG + nb + a)*128 + c*8);
        *(u32x4*)&hbuf[a][c*8] = v;
    }
    int tx0 = dir ? (T_STEPS-1) : 0;
    for (int i = tid; i < 256; i += 384){
        int a = i >> 3, c = i & 7;
        u32x4 v = *(const u32x4*)(semb + ((size_t)tx0*NAG + nb + a)*64 + c*8);
        *(u32x4*)&xbuf[0][a][c*8] = v;
    }
    __syncthreads();   // full barrier once before the loop (drains staging loads)

    #pragma unroll 1
    for (int t = 0; t < T_STEPS; t++){
        int tx = dir ? (T_STEPS-1-t) : t;
        int cur = t & 1;
        // ---- prefetch issue (n-waves): load next-step x into REGISTERS now;
        //      ds_write deferred to phase2. MFMA phase + bar1 hide the latency. ----
        u32x4 pf[2];
        int havepf = (gate == 2) && (t + 1 < T_STEPS);
        if (havepf){
            int txn = dir ? (T_STEPS-2-t) : (t+1);
            int i0 = (w-4)*64 + lane;                  // [0,128)
            #pragma unroll
            for (int rep = 0; rep < 2; rep++){
                int i = i0 + rep*128;
                int a = i >> 3, c = i & 7;
                pf[rep] = *(const u32x4*)(semb + ((size_t)txn*NAG + nb + a)*64 + c*8);
            }
        }
        // ---- C init from biases ----
        f32x4v C0[4][2], C1[4][2];
        #pragma unroll
        for (int mt = 0; mt < 4; mt++){
            f32x4v b1f = *(const f32x4v*)&bias1[(w*4+mt)*16 + quad*4];
            if (gate < 2){
                C0[mt][0] = b1f; C0[mt][1] = b1f;          // combined bias
                C1[mt][0] = b1f; C1[mt][1] = b1f;          // unused on this path
            } else {
                f32x4v b2f = *(const f32x4v*)&bias2[((w&1)*4+mt)*16 + quad*4];
                C0[mt][0] = b2f; C0[mt][1] = b2f;          // hh + bhh
                C1[mt][0] = b1f; C1[mt][1] = b1f;          // ih + bih
            }
        }
        // ---- MFMA phase ----
        #pragma unroll
        for (int nt = 0; nt < 2; nt++){
            int ag = nt*16 + l15;
            f16x8 B0 = *(const f16x8*)&hbuf[ag][0*32 + quad*8];
            f16x8 B1 = *(const f16x8*)&hbuf[ag][1*32 + quad*8];
            f16x8 B2 = *(const f16x8*)&hbuf[ag][2*32 + quad*8];
            f16x8 B3 = *(const f16x8*)&hbuf[ag][3*32 + quad*8];
            f16x8 B4 = *(const f16x8*)&xbuf[cur][ag][0*32 + quad*8];
            f16x8 B5 = *(const f16x8*)&xbuf[cur][ag][1*32 + quad*8];
            if (gate < 2){
                #pragma unroll
                for (int mt = 0; mt < 4; mt++){
                    f32x4v c = C0[mt][nt];
                    c = __builtin_amdgcn_mfma_f32_16x16x32_f16(Af[mt][0], B0, c, 0, 0, 0);
                    c = __builtin_amdgcn_mfma_f32_16x16x32_f16(Af[mt][1], B1, c, 0, 0, 0);
                    c = __builtin_amdgcn_mfma_f32_16x16x32_f16(Af[mt][2], B2, c, 0, 0, 0);
                    c = __builtin_amdgcn_mfma_f32_16x16x32_f16(Af[mt][3], B3, c, 0, 0, 0);
                    c = __builtin_amdgcn_mfma_f32_16x16x32_f16(Af[mt][4], B4, c, 0, 0, 0);
                    c = __builtin_amdgcn_mfma_f32_16x16x32_f16(Af[mt][5], B5, c, 0, 0, 0);
                    C0[mt][nt] = c;
                }
            } else {
                #pragma unroll
                for (int mt = 0; mt < 4; mt++){
                    f32x4v c = C0[mt][nt];
                    c = __builtin_amdgcn_mfma_f32_16x16x32_f16(Af[mt][0], B0, c, 0, 0, 0);
                    c = __builtin_amdgcn_mfma_f32_16x16x32_f16(Af[mt][1], B1, c, 0, 0, 0);
                    c = __builtin_amdgcn_mfma_f32_16x16x32_f16(Af[mt][2], B2, c, 0, 0, 0);
                    c = __builtin_amdgcn_mfma_f32_16x16x32_f16(Af[mt][3], B3, c, 0, 0, 0);
                    C0[mt][nt] = c;
                    f32x4v d = C1[mt][nt];
                    d = __builtin_amdgcn_mfma_f32_16x16x32_f16(Af[mt][4], B4, d, 0, 0, 0);
                    d = __builtin_amdgcn_mfma_f32_16x16x32_f16(Af[mt][5], B5, d, 0, 0, 0);
                    C1[mt][nt] = d;
                }
            }
        }
        // ---- phase1 tail: r/z LN partials ----
        if (gate < 2){
            #pragma unroll
            for (int nt = 0; nt < 2; nt++){
                float s = 0.f, q = 0.f;
                #pragma unroll
                for (int mt = 0; mt < 4; mt++)
                    #pragma unroll
                    for (int r = 0; r < 4; r++){
                        float v = C0[mt][nt][r];
                        s += v; q += v*v;
                    }
                s += __shfl_xor(s, 16); q += __shfl_xor(q, 16);
                s += __shfl_xor(s, 32); q += __shfl_xor(q, 32);
                if (lane < 16){ redS[w][nt*16 + l15] = s; redQ[w][nt*16 + l15] = q; }
            }
        }
        LBAR();                                            // bar1 (lgkm only)
        // ---- phase2: r/z finalize LN + sigmoid -> rzbuf; n-waves land prefetch ----
        if (gate < 2){
            #pragma unroll
            for (int nt = 0; nt < 2; nt++){
                int ag = nt*16 + l15;
                float s = redS[w][ag] + redS[w^1][ag];
                float q = redQ[w][ag] + redQ[w^1][ag];
                float m = s*(1.f/128.f), vv = q*(1.f/128.f) - m*m;
                float rs = rsqrtf(fmaxf(vv, 0.f) + LN_EPS);
                #pragma unroll
                for (int mt = 0; mt < 4; mt++){
                    float g0 = sigm((C0[mt][nt][0] - m)*rs);
                    float g1 = sigm((C0[mt][nt][1] - m)*rs);
                    float g2 = sigm((C0[mt][nt][2] - m)*rs);
                    float g3 = sigm((C0[mt][nt][3] - m)*rs);
                    int dg = ((w&1)*4 + mt)*16 + quad*4;
                    u32x2v p; p.x = pk_h2(g0, g1); p.y = pk_h2(g2, g3);
                    *(u32x2v*)&rzbuf[gate][ag][dg] = p;
                }
            }
        } else if (havepf){
            int i0 = (w-4)*64 + lane;
            #pragma unroll
            for (int rep = 0; rep < 2; rep++){
                int i = i0 + rep*128;
                int a = i >> 3, c = i & 7;
                *(u32x4*)&xbuf[cur^1][a][c*8] = pf[rep];
            }
        }
        LBAR();                                            // bar2
        // ---- phase3: n-pre = ih + r * hh ; LN partials ----
        if (gate == 2){
            #pragma unroll
            for (int nt = 0; nt < 2; nt++){
                int ag = nt*16 + l15;
                float s = 0.f, q = 0.f;
                #pragma unroll
                for (int mt = 0; mt < 4; mt++){
                    int dg = ((w&1)*4 + mt)*16 + quad*4;
                    u32x2v rp = *(const u32x2v*)&rzbuf[0][ag][dg];
                    f32x2 ra = unpk_h2(rp.x), rb = unpk_h2(rp.y);
                    float p0 = C1[mt][nt][0] + ra[0]*C0[mt][nt][0];
                    float p1 = C1[mt][nt][1] + ra[1]*C0[mt][nt][1];
                    float p2 = C1[mt][nt][2] + rb[0]*C0[mt][nt][2];
                    float p3 = C1[mt][nt][3] + rb[1]*C0[mt][nt][3];
                    C0[mt][nt][0] = p0; C0[mt][nt][1] = p1;
                    C0[mt][nt][2] = p2; C0[mt][nt][3] = p3;
                    s += p0 + p1 + p2 + p3;
                    q += p0*p0 + p1*p1 + p2*p2 + p3*p3;
                }
                s += __shfl_xor(s, 16); q += __shfl_xor(q, 16);
                s += __shfl_xor(s, 32); q += __shfl_xor(q, 32);
                if (lane < 16){ redS[w][ag] = s; redQ[w][ag] = q; }
            }
        }
        LBAR();                                            // bar3
        // ---- phase4: n finalize, h update, write back ----
        if (gate == 2){
            #pragma unroll
            for (int nt = 0; nt < 2; nt++){
                int ag = nt*16 + l15;
                float s = redS[4][ag] + redS[5][ag];
                float q = redQ[4][ag] + redQ[5][ag];
                float m = s*(1.f/128.f), vv = q*(1.f/128.f) - m*m;
                float rs = rsqrtf(fmaxf(vv, 0.f) + LN_EPS);
                #pragma unroll
                for (int mt = 0; mt < 4; mt++){
                    int dg = ((w&1)*4 + mt)*16 + quad*4;
                    float n0 = ftanh((C0[mt][nt][0] - m)*rs);
                    float n1 = ftanh((C0[mt][nt][1] - m)*rs);
                    float n2 = ftanh((C0[mt][nt][2] - m)*rs);
                    float n3 = ftanh((C0[mt][nt][3] - m)*rs);
                    u32x2v zp = *(const u32x2v*)&rzbuf[1][ag][dg];
                    f32x2 za = unpk_h2(zp.x), zb = unpk_h2(zp.y);
                    u32x2v hp = *(const u32x2v*)&hbuf[ag][dg];
                    f32x2 ha = unpk_h2(hp.x), hb2 = unpk_h2(hp.y);
                    float h0 = (1.f - za[0])*n0 + za[0]*ha[0];
                    float h1 = (1.f - za[1])*n1 + za[1]*ha[1];
                    float h2 = (1.f - zb[0])*n2 + zb[0]*hb2[0];
                    float h3 = (1.f - zb[1])*n3 + zb[1]*hb2[1];
                    u32x2v o; o.x = pk_h2(h0, h1); o.y = pk_h2(h2, h3);
                    *(u32x2v*)&hbuf[ag][dg] = o;
                    *(u32x2v*)(henc + ((size_t)tx*NAG + nb + ag)*128 + dg) = o;
                }
            }
        }
        LBAR();                                            // bar4
    }
}

// ---------------- K4: fused post-GRU: seq -> pairwise(factored) -> out head ----------------
// Pairwise LN restructured: group g = lane>>3 owns agent i=g (8 dims/lane over
// 8 lanes); 8 pairs run in parallel per round, reduce = 3 shfl_xor steps.
__global__ __launch_bounds__(256) void k_post(
    const f16* __restrict__ hf, const f16* __restrict__ hb,
    const void* __restrict__ sw, const void* __restrict__ sb,
    const void* __restrict__ mw, const void* __restrict__ mb,
    const void* __restrict__ ow1, const void* __restrict__ ob1,
    const void* __restrict__ ow2, const void* __restrict__ ob2,
    const void* __restrict__ probe,
    void* __restrict__ outp)
{
    __shared__ u32 swp[64*64];     // [kp][unit]
    __shared__ u32 mwp[32*64];     // [kp][unit]
    __shared__ u32 w1p[64*32];     // [kp][e<32]
    __shared__ __align__(16) u32 xr[4][8][64];   // x=(hf+hb)/2 pairs; later uuT alias
    __shared__ __align__(16) u32 fr[4][8][64];   // full=[seq|ave] pairs
    int F = detect_f32(probe);
    int tid = threadIdx.x;
    for (int i = tid; i < 4096; i += 256){
        int u = i & 63, kp = i >> 6;
        swp[kp*64+u] = ld_pair(sw, u*64 + kp, F);      // sw [64][128]
    }
    for (int i = tid; i < 2048; i += 256){
        int u = i & 63, kp = i >> 6;   // kp < 32
        mwp[kp*64+u] = ld_pair(mw, u*32 + kp, F);      // mw [64][64]
    }
    for (int i = tid; i < 2048; i += 256){
        int e = i & 31, kp = i >> 5;   // kp < 64
        w1p[kp*32+e] = ld_pair(ow1, e*64 + kp, F);     // ow1 [32][128]
    }
    int w = tid >> 6, lane = tid & 63;
    int unit = blockIdx.x*4 + w;        // t*512 + scene
    int t = unit >> 9, sc = unit & 511;
    int base = sc * 8;
    size_t rowbase = (size_t)t*NAG + base;
    const u32* hfu = (const u32*)hf;
    const u32* hbu = (const u32*)hb;
    #pragma unroll
    for (int r = 0; r < 8; r++){
        f32x2 a = unpk_h2(hfu[(rowbase + r)*64 + lane]);
        f32x2 b = unpk_h2(hbu[(rowbase + r)*64 + lane]);
        xr[w][r][lane] = pk_h2(0.5f*(a[0]+b[0]), 0.5f*(a[1]+b[1]));
    }
    __syncthreads();

    float bs = ldin(sb, lane, F);
    float y[8];
    #pragma unroll
    for (int r = 0; r < 8; r++) y[r] = bs;
    for (int kp = 0; kp < 64; kp++){
        u32 wv = swp[kp*64 + lane];
        #pragma unroll
        for (int r = 0; r < 8; r++) y[r] = fdot2u(xr[w][r][kp], wv, y[r]);
    }
    #pragma unroll
    for (int r = 0; r < 8; r++){
        float s = y[r], q = y[r]*y[r]; wred64(s, q);
        float m = s*(1.f/64.f), v = q*(1.f/64.f) - m*m;
        float rs = rsqrtf(fmaxf(v, 0.f) + LN_EPS);
        float sv = lrelu((y[r] - m)*rs);
        float e0 = __shfl(sv, 2*(lane & 31)), e1 = __shfl(sv, 2*(lane & 31) + 1);
        if (lane < 32) fr[w][r][lane] = pk_h2(e0, e1);
    }
    // ---- uu = seq @ mw.T (no bias); unit = lane ----
    float uu[8];
    #pragma unroll
    for (int r = 0; r < 8; r++) uu[r] = 0.f;
    for (int kp = 0; kp < 32; kp++){
        u32 wv = mwp[kp*64 + lane];
        #pragma unroll
        for (int r = 0; r < 8; r++) uu[r] = fdot2u(fr[w][r][kp], wv, uu[r]);
    }
    // ---- transpose uu -> uuT (aliases xr[w], which is dead now) ----
    // row r dim d stored at pos (d + 8r) & 63 (rotate-swizzle, bank-friendly)
    float* uuT = (float*)&xr[w][0][0];
    #pragma unroll
    for (int r = 0; r < 8; r++)
        uuT[r*64 + ((lane + r*8) & 63)] = uu[r];
    // ---- pairwise: group g owns agent i=g; lane l=lane&7 owns dims 8l..8l+7 ----
    int g = lane >> 3, l8 = (lane & 7) * 8;
    float bmv[8];
    #pragma unroll
    for (int d = 0; d < 8; d++) bmv[d] = ldin(mb, l8 + d, F);
    const f32x4v* up = (const f32x4v*)&uuT[g*64 + ((l8 + g*8) & 63)];
    f32x4v ui0 = up[0], ui1 = up[1];
    float acc[8];
    #pragma unroll
    for (int d = 0; d < 8; d++) acc[d] = 0.f;
    #pragma unroll
    for (int rr = 0; rr < 7; rr++){
        int j = (g + 1 + rr) & 7;
        const f32x4v* jp = (const f32x4v*)&uuT[j*64 + ((l8 + j*8) & 63)];
        f32x4v uj0 = jp[0], uj1 = jp[1];
        float p[8]; float s = 0.f, q = 0.f;
        #pragma unroll
        for (int d = 0; d < 4; d++){
            float v0 = ui0[d] - uj0[d] + bmv[d];
            float v1 = ui1[d] - uj1[d] + bmv[4+d];
            p[d] = v0; p[4+d] = v1;
            s += v0 + v1; q += v0*v0 + v1*v1;
        }
        #pragma unroll
        for (int m = 1; m < 8; m <<= 1){ s += __shfl_xor(s, m); q += __shfl_xor(q, m); }
        float mm = s*(1.f/64.f), vv = q*(1.f/64.f) - mm*mm;
        float rs = rsqrtf(fmaxf(vv, 0.f) + LN_EPS);
        #pragma unroll
        for (int d = 0; d < 8; d++) acc[d] += lrelu((p[d] - mm)*rs);
    }
    // ave -> fr[w][g][32 + l*4 ..], pairs of dims (8l+2k, 8l+2k+1)
    u32x4 av;
    #pragma unroll
    for (int k = 0; k < 4; k++) av[k] = pk_h2(acc[2*k]*(1.f/7.f), acc[2*k+1]*(1.f/7.f));
    *(u32x4*)&fr[w][g][32 + (lane & 7)*4] = av;
    // ---- head: full=[seq|ave] -> block(ow1) -> Linear(ow2) -> tanh ----
    int ll = lane & 31;
    float b1v = ldin(ob1, ll, F);
    float o20 = ldin(ow2, ll, F);
    float o21 = ldin(ow2, 32 + ll, F);
    float bo0 = ldin(ob2, 0, F), bo1 = ldin(ob2, 1, F);
    #pragma unroll
    for (int rp = 0; rp < 4; rp++){
        int r = rp*2 + (lane >> 5);
        float h = b1v;
        for (int kp = 0; kp < 64; kp++)
            h = fdot2u(fr[w][r][kp], w1p[kp*32 + ll], h);
        float s = h, q = h*h; wred32(s, q);
        float m = s*(1.f/32.f), v = q*(1.f/32.f) - m*m;
        float rs = rsqrtf(fmaxf(v, 0.f) + LN_EPS);
        float hv = lrelu((h - m)*rs);
        float p0 = hv*o20, p1 = hv*o21;
        wred32(p0, p1);
        if (ll == 0){
            int n = base + r;
            float v0 = ftanh(p0 + bo0), v1 = ftanh(p1 + bo1);
            size_t i0 = (size_t)(n*2)*T_STEPS + t, i1 = (size_t)(n*2+1)*T_STEPS + t;
            if (F){ ((float*)outp)[i0] = v0; ((float*)outp)[i1] = v1; }
            else  { ((u16*)outp)[i0] = f2bf(v0); ((u16*)outp)[i1] = f2bf(v1); }
        }
    }
}

extern "C" void kernel_launch(void* const* d_in, const int* in_sizes, int n_in,
                              void* d_out, int out_size, void* d_ws, size_t ws_size,
                              hipStream_t stream)
{
    const void* cond = d_in[0];
    const void* z    = d_in[1];
    const void* cw1  = d_in[2];
    const void* cb1  = d_in[3];
    const void* cw2  = d_in[4];
    const void* cb2  = d_in[5];
    const void* cbw1 = d_in[6];
    const void* cbb1 = d_in[7];
    const void* cbw2 = d_in[8];
    const void* cbb2 = d_in[9];
    const void* iw1  = d_in[10];
    const void* ib1  = d_in[11];
    const void* iw2  = d_in[12];
    const void* ib2  = d_in[13];
    const void* wih  = d_in[14];
    const void* whh  = d_in[15];
    const void* bih  = d_in[16];
    const void* bhh  = d_in[17];
    const void* wihb = d_in[18];
    const void* whhb = d_in[19];
    const void* bihb = d_in[20];
    const void* bhhb = d_in[21];
    const void* sw   = d_in[22];
    const void* sb   = d_in[23];
    const void* mw   = d_in[24];
    const void* mb   = d_in[25];
    const void* ow1  = d_in[26];
    const void* ob1  = d_in[27];
    const void* ow2  = d_in[28];
    const void* ob2  = d_in[29];
    const void* probe = whh;   // dtype-detection probe buffer

    char* ws = (char*)d_ws;
    size_t off = 0;
    f16* disp  = (f16*)(ws + off); off += (size_t)2*NAG*128*2;          //  2 MB
    f16* semb  = (f16*)(ws + off); off += (size_t)T_STEPS*NAG*64*2;     // 15.7 MB
    f16* hencF = (f16*)(ws + off); off += (size_t)T_STEPS*NAG*128*2;    // 31.5 MB
    f16* hencB = (f16*)(ws + off); off += (size_t)T_STEPS*NAG*128*2;    // 31.5 MB

    k_cond<<<dim3(NAG/8,2), 256, 0, stream>>>(cond, cw1,cb1,cw2,cb2, cbw1,cbb1,cbw2,cbb2, probe, disp);
    k_emb<<<3840, 256, 0, stream>>>(z, iw1,ib1,iw2,ib2, probe, semb);
    k_gru_mfma<<<dim3(NAG/32,2), 384, 0, stream>>>(semb, disp, wih,whh,bih,bhh, wihb,whhb,bihb,bhhb, probe, hencF, hencB);
    k_post<<<3840, 256, 0, stream>>>(hencF, hencB, sw,sb, mw,mb, ow1,ob1,ow2,ob2, probe, d_out);
}

// Round 15
// 497.620 us; speedup vs baseline: 1.0769x; 1.0287x over previous
//
#include <hip/hip_runtime.h>
#include <hip/hip_bf16.h>

typedef unsigned int u32;
typedef unsigned short u16;
typedef _Float16 f16;
typedef float f32x2 __attribute__((ext_vector_type(2)));
typedef _Float16 f16x2 __attribute__((ext_vector_type(2)));
typedef u32 u32x4 __attribute__((ext_vector_type(4)));
typedef u32 u32x2v __attribute__((ext_vector_type(2)));
typedef _Float16 f16x8 __attribute__((ext_vector_type(8)));
typedef float f32x4v __attribute__((ext_vector_type(4)));

#define LN_EPS 1e-5f
#define T_STEPS 30
#define NAG 4096

__device__ __forceinline__ float bf2f(u16 v){
    union { u32 u; float f; } c; c.u = ((u32)v) << 16; return c.f;
}
__device__ __forceinline__ u16 f2bf(float f){
    union { float f; u32 u; } c; c.f = f;
    return (u16)((c.u + 0x7FFFu + ((c.u >> 16) & 1u)) >> 16);
}
__device__ __forceinline__ u32 pk_h2(float a, float b){
    f16x2 h; h[0] = (f16)a; h[1] = (f16)b;
    return __builtin_bit_cast(u32, h);
}
__device__ __forceinline__ f32x2 unpk_h2(u32 p){
    f16x2 h = __builtin_bit_cast(f16x2, p);
    f32x2 r; r[0] = (float)h[0]; r[1] = (float)h[1]; return r;
}
__device__ __forceinline__ u32 bfp2h2(u32 p){
    union { u32 u; float f; } a, b;
    a.u = p << 16; b.u = p & 0xFFFF0000u;
    return pk_h2(a.f, b.f);
}
__device__ __forceinline__ float fdot2u(u32 a, u32 b, float c){
    return __builtin_amdgcn_fdot2(__builtin_bit_cast(f16x2, a),
                                  __builtin_bit_cast(f16x2, b), c, false);
}
// dtype probe: fp32 buffers read as u16 have random mantissa halves at even
// positions (~50% decode to |x|>=128); bf16 weight buffers (|w| < 1) never do.
__device__ __forceinline__ int detect_f32(const void* probe){
    const u16* p = (const u16*)probe;
    int bad = 0;
    #pragma unroll
    for (int i = 0; i < 32; i++){
        u32 e = (p[2*i] >> 7) & 0xFF;
        bad += (e >= 0x86) ? 1 : 0;
    }
    return bad > 4;
}
__device__ __forceinline__ float ldin(const void* p, int i, int F){
    float v;
    if (F) v = ((const float*)p)[i];
    else   v = bf2f(((const u16*)p)[i]);
    return v;
}
__device__ __forceinline__ u32 ld_pair(const void* p, int pairIdx, int F){
    if (F){ const float* f = (const float*)p; return pk_h2(f[2*pairIdx], f[2*pairIdx+1]); }
    return bfp2h2(((const u32*)p)[pairIdx]);
}
__device__ __forceinline__ void wred64(float& s, float& q){
    #pragma unroll
    for (int m = 1; m < 64; m <<= 1){ s += __shfl_xor(s, m); q += __shfl_xor(q, m); }
}
__device__ __forceinline__ void wred32(float& s, float& q){
    #pragma unroll
    for (int m = 1; m < 32; m <<= 1){ s += __shfl_xor(s, m); q += __shfl_xor(q, m); }
}
__device__ __forceinline__ float lrelu(float x){ return fmaxf(x, 0.1f * x); }
__device__ __forceinline__ float sigm(float x){ return 1.0f / (1.0f + __expf(-x)); }
__device__ __forceinline__ float ftanh(float x){ return 1.0f - 2.0f / (1.0f + __expf(2.0f * x)); }
__device__ __forceinline__ void ln128(float a0, float a1, float& o0, float& o1){
    float s = a0 + a1, q = a0*a0 + a1*a1;
    wred64(s, q);
    float m = s * (1.f/128.f), v = q * (1.f/128.f) - m*m;
    float rs = rsqrtf(fmaxf(v, 0.f) + LN_EPS);
    o0 = (a0 - m) * rs; o1 = (a1 - m) * rs;
}

// ---------------- K1: cond embeddings (both dirs): [N,2] -> 64 -> 128 ----------------
// 256 thr / 8 agents per block; w2 staged TRANSPOSED in LDS (coalesced global
// reads; +2-pad stride 130, reads conflict-free). One barrier total.
__global__ __launch_bounds__(256) void k_cond(
    const void* __restrict__ cond,
    const void* __restrict__ w1a, const void* __restrict__ b1a,
    const void* __restrict__ w2a, const void* __restrict__ b2a,
    const void* __restrict__ w1b, const void* __restrict__ b1b,
    const void* __restrict__ w2b, const void* __restrict__ b2b,
    const void* __restrict__ probe,
    f16* __restrict__ disp)
{
    __shared__ float w2T[64*130];     // [k][u], padded stride 130 (33.3 KB)
    __shared__ float w1s[128], b1s[64], b2s[128];
    __shared__ float x1s[4][64];      // layer-1 outs, per wave
    int F = detect_f32(probe);
    int tid = threadIdx.x, dir = blockIdx.y;
    const void* w1 = dir ? w1b : w1a; const void* b1 = dir ? b1b : b1a;
    const void* w2 = dir ? w2b : w2a; const void* b2 = dir ? b2b : b2a;
    // stage w2 transposed: global idx i = u*64 + k, k fastest -> coalesced reads
    for (int i = tid; i < 8192; i += 256){
        int u = i >> 6, k = i & 63;
        w2T[k*130 + u] = ldin(w2, i, F);
    }
    if (tid < 128) w1s[tid] = ldin(w1, tid, F);
    else           b2s[tid - 128] = ldin(b2, tid - 128, F);
    if (tid < 64)  b1s[tid] = ldin(b1, tid, F);
    __syncthreads();

    int w = tid >> 6, lane = tid & 63;
    int nb = blockIdx.x * 8 + w * 2;
    #pragma unroll
    for (int a = 0; a < 2; a++){
        int n = nb + a;
        float c0 = ldin(cond, n*2, F), c1 = ldin(cond, n*2+1, F);
        float y = w1s[lane*2] * c0 + w1s[lane*2+1] * c1 + b1s[lane];
        float s = y, q = y*y; wred64(s, q);
        float m = s * (1.f/64.f), v = q * (1.f/64.f) - m*m;
        float rs = rsqrtf(fmaxf(v, 0.f) + LN_EPS);
        x1s[w][lane] = lrelu((y - m) * rs);   // per-wave buffer, no barrier needed
        float y0 = b2s[lane], y1 = b2s[lane + 64];
        #pragma unroll 8
        for (int k = 0; k < 64; k++){
            float xv = x1s[w][k];
            y0 = fmaf(xv, w2T[k*130 + lane], y0);
            y1 = fmaf(xv, w2T[k*130 + 64 + lane], y1);
        }
        float o0, o1; ln128(y0, y1, o0, o1);
        f16* dp = disp + ((size_t)dir * NAG + n) * 128;
        dp[lane] = (f16)lrelu(o0);
        dp[lane+64] = (f16)lrelu(o1);
    }
}

// ---------------- K2: scene embedding: z[T,N,128] -> 32 -> 64 (packed fdot2) ----------
__global__ __launch_bounds__(256) void k_emb(
    const void* __restrict__ z,
    const void* __restrict__ iw1, const void* __restrict__ ib1,
    const void* __restrict__ iw2, const void* __restrict__ ib2,
    const void* __restrict__ probe,
    f16* __restrict__ semb)
{
    __shared__ u32 w1p[64*32];      // [kp<64][e<32]
    __shared__ u32 w2p[16*64];      // [kp<16][e<64]
    __shared__ u32 zp[4][2][64];    // z rows packed, 2 rows per wave pass
    __shared__ u32 x1p[4][2][16];   // layer-1 outs packed
    int F = detect_f32(probe);
    int tid = threadIdx.x;
    for (int i = tid; i < 2048; i += 256){
        int kp = i >> 5, e = i & 31;
        w1p[kp*32+e] = ld_pair(iw1, e*64 + kp, F);      // iw1 [32][128]
    }
    for (int i = tid; i < 1024; i += 256){
        int kp = i >> 6, e = i & 63;
        w2p[kp*64+e] = ld_pair(iw2, e*16 + kp, F);      // iw2 [64][32]
    }
    __syncthreads();
    int w = tid >> 6, lane = tid & 63;
    int rp = lane >> 5, ll = lane & 31;
    float b1v = ldin(ib1, ll, F);
    float b2v = ldin(ib2, lane, F);
    int rowbase = (blockIdx.x * 4 + w) * 8;
    #pragma unroll 1
    for (int pass = 0; pass < 4; pass++){
        int row = rowbase + pass*2 + rp;                // half-wave rp owns this row
        zp[w][rp][ll]    = ld_pair(z, row*64 + ll, F);
        zp[w][rp][ll+32] = ld_pair(z, row*64 + ll + 32, F);
        float y1 = b1v;
        #pragma unroll 8
        for (int kp = 0; kp < 64; kp++)
            y1 = fdot2u(zp[w][rp][kp], w1p[kp*32+ll], y1);
        float s = y1, q = y1*y1; wred32(s, q);
        float m = s*(1.f/32.f), v = q*(1.f/32.f)-m*m, rs = rsqrtf(fmaxf(v,0.f)+LN_EPS);
        float sv = lrelu((y1-m)*rs);
        float e0 = __shfl(sv, (lane & 32) + 2*(lane & 15));
        float e1 = __shfl(sv, (lane & 32) + 2*(lane & 15) + 1);
        if (ll < 16) x1p[w][rp][ll] = pk_h2(e0, e1);
        #pragma unroll
        for (int r2 = 0; r2 < 2; r2++){
            float y2 = b2v;
            #pragma unroll
            for (int kp = 0; kp < 16; kp++)
                y2 = fdot2u(x1p[w][r2][kp], w2p[kp*64+lane], y2);
            s = y2; q = y2*y2; wred64(s, q);
            m = s*(1.f/64.f); v = q*(1.f/64.f)-m*m; rs = rsqrtf(fmaxf(v,0.f)+LN_EPS);
            semb[(size_t)(rowbase + pass*2 + r2)*64 + lane] = (f16)lrelu((y2-m)*rs);
        }
    }
}

// ---------------- K3: MFMA bidirectional LN-GRU ----------------
// REVERTED to the R3/R7 winner verbatim (measured 168 us). Falsified levers:
// R6 2-block split (195), R9 12-wave dir-fusion (197, occupancy 2x but slower),
// R12 LBAR barrier-surgery + reg-prefetch (187; sched_barrier pins defeated the
// compiler's own scheduling -- guide common-mistake #5). Conclusion: the step
// cost is intra-phase dependent chains, not sync overhead, not TLP. Leave as-is.
// Wave w owns M-tiles 4w..4w+3 -> gate = w>>1 (r: w0,1; z: w2,3; n: w4,5).
// Verified gfx950 16x16x32 f16 fragment layouts (m89/m91/m120):
//   A[m=lane&15][k=quad*8+j], B[k=quad*8+j][n=lane&15], C col=lane&15 row=quad*4+reg.
__global__ __launch_bounds__(384) void k_gru_mfma(
    const f16* __restrict__ semb, const f16* __restrict__ disp,
    const void* __restrict__ wihA, const void* __restrict__ whhA,
    const void* __restrict__ bihA, const void* __restrict__ bhhA,
    const void* __restrict__ wihB, const void* __restrict__ whhB,
    const void* __restrict__ bihB, const void* __restrict__ bhhB,
    const void* __restrict__ probe,
    f16* __restrict__ hencF, f16* __restrict__ hencB)
{
    __shared__ __align__(16) f16 hbuf[32][136];      // h per agent (pad 8 f16)
    __shared__ __align__(16) f16 xbuf[2][32][72];    // x per agent, double-buffered
    __shared__ __align__(16) f16 rzbuf[2][32][136];  // r,z values [gate][agent][d]
    __shared__ __align__(16) float bias1[384];       // u<256: bih+bhh; u>=256: bih
    __shared__ __align__(16) float bias2[128];       // bhh for n-units
    __shared__ float redS[6][32], redQ[6][32];
    int F = detect_f32(probe);
    int tid = threadIdx.x, dir = blockIdx.y;
    int w = tid >> 6, lane = tid & 63;
    int quad = lane >> 4, l15 = lane & 15;
    int gate = w >> 1;
    const void* wih = dir ? wihB : wihA;  const void* whh = dir ? whhB : whhA;
    const void* bih = dir ? bihB : bihA;  const void* bhh = dir ? bhhB : bhhA;
    f16* henc = dir ? hencB : hencF;

    // ---- A fragments: Af[mt][kt]; lane supplies A[m=l15][k=quad*8+j] ----
    f16x8 Af[4][6];
    if (F){
        #pragma unroll
        for (int mt = 0; mt < 4; mt++){
            int u = (w*4+mt)*16 + l15;
            #pragma unroll
            for (int kt = 0; kt < 6; kt++){
                const float* src = (kt < 4)
                    ? ((const float*)whh + (size_t)u*128 + kt*32 + quad*8)
                    : ((const float*)wih + (size_t)u*64 + (kt-4)*32 + quad*8);
                f16x8 v;
                #pragma unroll
                for (int j = 0; j < 8; j++) v[j] = (f16)src[j];
                Af[mt][kt] = v;
            }
        }
    } else {
        #pragma unroll
        for (int mt = 0; mt < 4; mt++){
            int u = (w*4+mt)*16 + l15;
            #pragma unroll
            for (int kt = 0; kt < 6; kt++){
                const u16* src = (kt < 4)
                    ? ((const u16*)whh + (size_t)u*128 + kt*32 + quad*8)
                    : ((const u16*)wih + (size_t)u*64 + (kt-4)*32 + quad*8);
                f16x8 v;
                #pragma unroll
                for (int j = 0; j < 8; j++) v[j] = (f16)bf2f(src[j]);
                Af[mt][kt] = v;
            }
        }
    }
    // biases -> LDS (keeps VGPR pressure down; C-frags init from these per step)
    if (tid < 384){
        float bi = ldin(bih, tid, F), bh = ldin(bhh, tid, F);
        bias1[tid] = (tid < 256) ? (bi + bh) : bi;
        if (tid >= 256) bias2[tid - 256] = bh;
    }

    int nb = blockIdx.x * 32;
    // stage h0 (from disp) and x(t0)
    for (int i = tid; i < 512; i += 384){
        int a = i >> 4, c = i & 15;
        u32x4 v = *(const u32x4*)(disp + ((size_t)dir*NAG + nb + a)*128 + c*8);
        *(u32x4*)&hbuf[a][c*8] = v;
    }
    int tx0 = dir ? (T_STEPS-1) : 0;
    for (int i = tid; i < 256; i += 384){
        int a = i >> 3, c = i & 7;
        u32x4 v = *(const u32x4*)(semb + ((size_t)tx0*NAG + nb + a)*64 + c*8);
        *(u32x4*)&xbuf[0][a][c*8] = v;
    }
    __syncthreads();

    #pragma unroll 1
    for (int t = 0; t < T_STEPS; t++){
        int tx = dir ? (T_STEPS-1-t) : t;
        int cur = t & 1;
        // ---- C init from biases ----
        f32x4v C0[4][2], C1[4][2];
        #pragma unroll
        for (int mt = 0; mt < 4; mt++){
            f32x4v b1f = *(const f32x4v*)&bias1[(w*4+mt)*16 + quad*4];
            if (gate < 2){
                C0[mt][0] = b1f; C0[mt][1] = b1f;          // combined bias
                C1[mt][0] = b1f; C1[mt][1] = b1f;          // unused on this path
            } else {
                f32x4v b2f = *(const f32x4v*)&bias2[((w&1)*4+mt)*16 + quad*4];
                C0[mt][0] = b2f; C0[mt][1] = b2f;          // hh + bhh
                C1[mt][0] = b1f; C1[mt][1] = b1f;          // ih + bih
            }
        }
        // ---- MFMA phase ----
        #pragma unroll
        for (int nt = 0; nt < 2; nt++){
            int ag = nt*16 + l15;
            f16x8 B0 = *(const f16x8*)&hbuf[ag][0*32 + quad*8];
            f16x8 B1 = *(const f16x8*)&hbuf[ag][1*32 + quad*8];
            f16x8 B2 = *(const f16x8*)&hbuf[ag][2*32 + quad*8];
            f16x8 B3 = *(const f16x8*)&hbuf[ag][3*32 + quad*8];
            f16x8 B4 = *(const f16x8*)&xbuf[cur][ag][0*32 + quad*8];
            f16x8 B5 = *(const f16x8*)&xbuf[cur][ag][1*32 + quad*8];
            if (gate < 2){
                #pragma unroll
                for (int mt = 0; mt < 4; mt++){
                    f32x4v c = C0[mt][nt];
                    c = __builtin_amdgcn_mfma_f32_16x16x32_f16(Af[mt][0], B0, c, 0, 0, 0);
                    c = __builtin_amdgcn_mfma_f32_16x16x32_f16(Af[mt][1], B1, c, 0, 0, 0);
                    c = __builtin_amdgcn_mfma_f32_16x16x32_f16(Af[mt][2], B2, c, 0, 0, 0);
                    c = __builtin_amdgcn_mfma_f32_16x16x32_f16(Af[mt][3], B3, c, 0, 0, 0);
                    c = __builtin_amdgcn_mfma_f32_16x16x32_f16(Af[mt][4], B4, c, 0, 0, 0);
                    c = __builtin_amdgcn_mfma_f32_16x16x32_f16(Af[mt][5], B5, c, 0, 0, 0);
                    C0[mt][nt] = c;
                }
            } else {
                #pragma unroll
                for (int mt = 0; mt < 4; mt++){
                    f32x4v c = C0[mt][nt];
                    c = __builtin_amdgcn_mfma_f32_16x16x32_f16(Af[mt][0], B0, c, 0, 0, 0);
                    c = __builtin_amdgcn_mfma_f32_16x16x32_f16(Af[mt][1], B1, c, 0, 0, 0);
                    c = __builtin_amdgcn_mfma_f32_16x16x32_f16(Af[mt][2], B2, c, 0, 0, 0);
                    c = __builtin_amdgcn_mfma_f32_16x16x32_f16(Af[mt][3], B3, c, 0, 0, 0);
                    C0[mt][nt] = c;
                    f32x4v d = C1[mt][nt];
                    d = __builtin_amdgcn_mfma_f32_16x16x32_f16(Af[mt][4], B4, d, 0, 0, 0);
                    d = __builtin_amdgcn_mfma_f32_16x16x32_f16(Af[mt][5], B5, d, 0, 0, 0);
                    C1[mt][nt] = d;
                }
            }
        }
        // ---- phase1 tail: r/z LN partials; n-waves stage next x ----
        if (gate < 2){
            #pragma unroll
            for (int nt = 0; nt < 2; nt++){
                float s = 0.f, q = 0.f;
                #pragma unroll
                for (int mt = 0; mt < 4; mt++)
                    #pragma unroll
                    for (int r = 0; r < 4; r++){
                        float v = C0[mt][nt][r];
                        s += v; q += v*v;
                    }
                s += __shfl_xor(s, 16); q += __shfl_xor(q, 16);
                s += __shfl_xor(s, 32); q += __shfl_xor(q, 32);
                if (lane < 16){ redS[w][nt*16 + l15] = s; redQ[w][nt*16 + l15] = q; }
            }
        } else {
            if (t + 1 < T_STEPS){
                int txn = dir ? (T_STEPS-2-t) : (t+1);
                int i0 = (w-4)*64 + lane;                  // [0,128)
                #pragma unroll
                for (int rep = 0; rep < 2; rep++){
                    int i = i0 + rep*128;
                    int a = i >> 3, c = i & 7;
                    u32x4 v = *(const u32x4*)(semb + ((size_t)txn*NAG + nb + a)*64 + c*8);
                    *(u32x4*)&xbuf[cur^1][a][c*8] = v;
                }
            }
        }
        __syncthreads();                                   // bar1
        // ---- phase2: r/z finalize LN + sigmoid -> rzbuf ----
        if (gate < 2){
            #pragma unroll
            for (int nt = 0; nt < 2; nt++){
                int ag = nt*16 + l15;
                float s = redS[w][ag] + redS[w^1][ag];
                float q = redQ[w][ag] + redQ[w^1][ag];
                float m = s*(1.f/128.f), vv = q*(1.f/128.f) - m*m;
                float rs = rsqrtf(fmaxf(vv, 0.f) + LN_EPS);
                #pragma unroll
                for (int mt = 0; mt < 4; mt++){
                    float g0 = sigm((C0[mt][nt][0] - m)*rs);
                    float g1 = sigm((C0[mt][nt][1] - m)*rs);
                    float g2 = sigm((C0[mt][nt][2] - m)*rs);
                    float g3 = sigm((C0[mt][nt][3] - m)*rs);
                    int dg = ((w&1)*4 + mt)*16 + quad*4;
                    u32x2v p; p.x = pk_h2(g0, g1); p.y = pk_h2(g2, g3);
                    *(u32x2v*)&rzbuf[gate][ag][dg] = p;
                }
            }
        }
        __syncthreads();                                   // bar2
        // ---- phase3: n-pre = ih + r * hh ; LN partials ----
        if (gate == 2){
            #pragma unroll
            for (int nt = 0; nt < 2; nt++){
                int ag = nt*16 + l15;
                float s = 0.f, q = 0.f;
                #pragma unroll
                for (int mt = 0; mt < 4; mt++){
                    int dg = ((w&1)*4 + mt)*16 + quad*4;
                    u32x2v rp = *(const u32x2v*)&rzbuf[0][ag][dg];
                    f32x2 ra = unpk_h2(rp.x), rb = unpk_h2(rp.y);
                    float p0 = C1[mt][nt][0] + ra[0]*C0[mt][nt][0];
                    float p1 = C1[mt][nt][1] + ra[1]*C0[mt][nt][1];
                    float p2 = C1[mt][nt][2] + rb[0]*C0[mt][nt][2];
                    float p3 = C1[mt][nt][3] + rb[1]*C0[mt][nt][3];
                    C0[mt][nt][0] = p0; C0[mt][nt][1] = p1;
                    C0[mt][nt][2] = p2; C0[mt][nt][3] = p3;
                    s += p0 + p1 + p2 + p3;
                    q += p0*p0 + p1*p1 + p2*p2 + p3*p3;
                }
                s += __shfl_xor(s, 16); q += __shfl_xor(q, 16);
                s += __shfl_xor(s, 32); q += __shfl_xor(q, 32);
                if (lane < 16){ redS[w][ag] = s; redQ[w][ag] = q; }
            }
        }
        __syncthreads();                                   // bar3
        // ---- phase4: n finalize, h update, write back ----
        if (gate == 2){
            #pragma unroll
            for (int nt = 0; nt < 2; nt++){
                int ag = nt*16 + l15;
                float s = redS[4][ag] + redS[5][ag];
                float q = redQ[4][ag] + redQ[5][ag];
                float m = s*(1.f/128.f), vv = q*(1.f/128.f) - m*m;
                float rs = rsqrtf(fmaxf(vv, 0.f) + LN_EPS);
                #pragma unroll
                for (int mt = 0; mt < 4; mt++){
                    int dg = ((w&1)*4 + mt)*16 + quad*4;
                    float n0 = ftanh((C0[mt][nt][0] - m)*rs);
                    float n1 = ftanh((C0[mt][nt][1] - m)*rs);
                    float n2 = ftanh((C0[mt][nt][2] - m)*rs);
                    float n3 = ftanh((C0[mt][nt][3] - m)*rs);
                    u32x2v zp = *(const u32x2v*)&rzbuf[1][ag][dg];
                    f32x2 za = unpk_h2(zp.x), zb = unpk_h2(zp.y);
                    u32x2v hp = *(const u32x2v*)&hbuf[ag][dg];
                    f32x2 ha = unpk_h2(hp.x), hb2 = unpk_h2(hp.y);
                    float h0 = (1.f - za[0])*n0 + za[0]*ha[0];
                    float h1 = (1.f - za[1])*n1 + za[1]*ha[1];
                    float h2 = (1.f - zb[0])*n2 + zb[0]*hb2[0];
                    float h3 = (1.f - zb[1])*n3 + zb[1]*hb2[1];
                    u32x2v o; o.x = pk_h2(h0, h1); o.y = pk_h2(h2, h3);
                    *(u32x2v*)&hbuf[ag][dg] = o;
                    *(u32x2v*)(henc + ((size_t)tx*NAG + nb + ag)*128 + dg) = o;
                }
            }
        }
        __syncthreads();                                   // bar4
    }
}

// ---------------- K4: fused post-GRU: seq -> pairwise(factored) -> out head ----------------
// Pairwise LN (R0 fix): 8-lane groups, 8 pairs parallel, 3-hop reduce.
// This round: seq-LN gets the same transform. The 8 serial wred64s (96
// dependent shuffle hops ~3.8kcy, the dominant remaining serial chain at
// VALUBusy 22%) are replaced by one LDS transpose (through dead xr scratch,
// rotate-swizzle = 2-way banks, free) + a single 3-hop 8-lane reduce that
// handles all 8 rows in parallel.
__global__ __launch_bounds__(256) void k_post(
    const f16* __restrict__ hf, const f16* __restrict__ hb,
    const void* __restrict__ sw, const void* __restrict__ sb,
    const void* __restrict__ mw, const void* __restrict__ mb,
    const void* __restrict__ ow1, const void* __restrict__ ob1,
    const void* __restrict__ ow2, const void* __restrict__ ob2,
    const void* __restrict__ probe,
    void* __restrict__ outp)
{
    __shared__ u32 swp[64*64];     // [kp][unit]
    __shared__ u32 mwp[32*64];     // [kp][unit]
    __shared__ u32 w1p[64*32];     // [kp][e<32]
    __shared__ __align__(16) u32 xr[4][8][64];   // x pairs; later yT / uuT alias
    __shared__ __align__(16) u32 fr[4][8][64];   // full=[seq|ave] pairs
    int F = detect_f32(probe);
    int tid = threadIdx.x;
    for (int i = tid; i < 4096; i += 256){
        int u = i & 63, kp = i >> 6;
        swp[kp*64+u] = ld_pair(sw, u*64 + kp, F);      // sw [64][128]
    }
    for (int i = tid; i < 2048; i += 256){
        int u = i & 63, kp = i >> 6;   // kp < 32
        mwp[kp*64+u] = ld_pair(mw, u*32 + kp, F);      // mw [64][64]
    }
    for (int i = tid; i < 2048; i += 256){
        int e = i & 31, kp = i >> 5;   // kp < 64
        w1p[kp*32+e] = ld_pair(ow1, e*64 + kp, F);     // ow1 [32][128]
    }
    int w = tid >> 6, lane = tid & 63;
    int unit = blockIdx.x*4 + w;        // t*512 + scene
    int t = unit >> 9, sc = unit & 511;
    int base = sc * 8;
    size_t rowbase = (size_t)t*NAG + base;
    const u32* hfu = (const u32*)hf;
    const u32* hbu = (const u32*)hb;
    #pragma unroll
    for (int r = 0; r < 8; r++){
        f32x2 a = unpk_h2(hfu[(rowbase + r)*64 + lane]);
        f32x2 b = unpk_h2(hbu[(rowbase + r)*64 + lane]);
        xr[w][r][lane] = pk_h2(0.5f*(a[0]+b[0]), 0.5f*(a[1]+b[1]));
    }
    __syncthreads();

    float bs = ldin(sb, lane, F);
    float y[8];
    #pragma unroll
    for (int r = 0; r < 8; r++) y[r] = bs;
    for (int kp = 0; kp < 64; kp++){
        u32 wv = swp[kp*64 + lane];
        #pragma unroll
        for (int r = 0; r < 8; r++) y[r] = fdot2u(xr[w][r][kp], wv, y[r]);
    }
    // ---- seq-LN transposed: group g owns row g; lane l=lane&7 owns outs 8l..8l+7.
    // xr[w] is dead after the y-loop; reuse as yT scratch (rotate-swizzle). ----
    float* yT = (float*)&xr[w][0][0];
    #pragma unroll
    for (int r = 0; r < 8; r++)
        yT[r*64 + ((lane + r*8) & 63)] = y[r];
    {
        int g = lane >> 3, l8 = (lane & 7) * 8;
        const f32x4v* yp = (const f32x4v*)&yT[g*64 + ((l8 + g*8) & 63)];
        f32x4v ya = yp[0], yb = yp[1];
        float s = 0.f, q = 0.f;
        #pragma unroll
        for (int d = 0; d < 4; d++){
            s += ya[d] + yb[d];
            q += ya[d]*ya[d] + yb[d]*yb[d];
        }
        #pragma unroll
        for (int m = 1; m < 8; m <<= 1){ s += __shfl_xor(s, m); q += __shfl_xor(q, m); }
        float mm = s*(1.f/64.f), vv = q*(1.f/64.f) - mm*mm;
        float rs = rsqrtf(fmaxf(vv, 0.f) + LN_EPS);
        u32x4 sv;
        sv[0] = pk_h2(lrelu((ya[0]-mm)*rs), lrelu((ya[1]-mm)*rs));
        sv[1] = pk_h2(lrelu((ya[2]-mm)*rs), lrelu((ya[3]-mm)*rs));
        sv[2] = pk_h2(lrelu((yb[0]-mm)*rs), lrelu((yb[1]-mm)*rs));
        sv[3] = pk_h2(lrelu((yb[2]-mm)*rs), lrelu((yb[3]-mm)*rs));
        *(u32x4*)&fr[w][g][(lane & 7)*4] = sv;      // seq pairs 4l..4l+3 of row g
    }
    // ---- uu = seq @ mw.T (no bias); unit = lane ----
    float uu[8];
    #pragma unroll
    for (int r = 0; r < 8; r++) uu[r] = 0.f;
    for (int kp = 0; kp < 32; kp++){
        u32 wv = mwp[kp*64 + lane];
        #pragma unroll
        for (int r = 0; r < 8; r++) uu[r] = fdot2u(fr[w][r][kp], wv, uu[r]);
    }
    // ---- transpose uu -> uuT (aliases xr[w], dead again after yT use) ----
    // row r dim d stored at pos (d + 8r) & 63 (rotate-swizzle, bank-friendly)
    float* uuT = (float*)&xr[w][0][0];
    #pragma unroll
    for (int r = 0; r < 8; r++)
        uuT[r*64 + ((lane + r*8) & 63)] = uu[r];
    // ---- pairwise: group g owns agent i=g; lane l=lane&7 owns dims 8l..8l+7 ----
    int g = lane >> 3, l8 = (lane & 7) * 8;
    float bmv[8];
    #pragma unroll
    for (int d = 0; d < 8; d++) bmv[d] = ldin(mb, l8 + d, F);
    const f32x4v* up = (const f32x4v*)&uuT[g*64 + ((l8 + g*8) & 63)];
    f32x4v ui0 = up[0], ui1 = up[1];
    float acc[8];
    #pragma unroll
    for (int d = 0; d < 8; d++) acc[d] = 0.f;
    #pragma unroll
    for (int rr = 0; rr < 7; rr++){
        int j = (g + 1 + rr) & 7;
        const f32x4v* jp = (const f32x4v*)&uuT[j*64 + ((l8 + j*8) & 63)];
        f32x4v uj0 = jp[0], uj1 = jp[1];
        float p[8]; float s = 0.f, q = 0.f;
        #pragma unroll
        for (int d = 0; d < 4; d++){
            float v0 = ui0[d] - uj0[d] + bmv[d];
            float v1 = ui1[d] - uj1[d] + bmv[4+d];
            p[d] = v0; p[4+d] = v1;
            s += v0 + v1; q += v0*v0 + v1*v1;
        }
        #pragma unroll
        for (int m = 1; m < 8; m <<= 1){ s += __shfl_xor(s, m); q += __shfl_xor(q, m); }
        float mm = s*(1.f/64.f), vv = q*(1.f/64.f) - mm*mm;
        float rs = rsqrtf(fmaxf(vv, 0.f) + LN_EPS);
        #pragma unroll
        for (int d = 0; d < 8; d++) acc[d] += lrelu((p[d] - mm)*rs);
    }
    // ave -> fr[w][g][32 + l*4 ..], pairs of dims (8l+2k, 8l+2k+1)
    u32x4 av;
    #pragma unroll
    for (int k = 0; k < 4; k++) av[k] = pk_h2(acc[2*k]*(1.f/7.f), acc[2*k+1]*(1.f/7.f));
    *(u32x4*)&fr[w][g][32 + (lane & 7)*4] = av;
    // ---- head: full=[seq|ave] -> block(ow1) -> Linear(ow2) -> tanh ----
    int ll = lane & 31;
    float b1v = ldin(ob1, ll, F);
    float o20 = ldin(ow2, ll, F);
    float o21 = ldin(ow2, 32 + ll, F);
    float bo0 = ldin(ob2, 0, F), bo1 = ldin(ob2, 1, F);
    #pragma unroll
    for (int rp = 0; rp < 4; rp++){
        int r = rp*2 + (lane >> 5);
        float h = b1v;
        for (int kp = 0; kp < 64; kp++)
            h = fdot2u(fr[w][r][kp], w1p[kp*32 + ll], h);
        float s = h, q = h*h; wred32(s, q);
        float m = s*(1.f/32.f), v = q*(1.f/32.f) - m*m;
        float rs = rsqrtf(fmaxf(v, 0.f) + LN_EPS);
        float hv = lrelu((h - m)*rs);
        float p0 = hv*o20, p1 = hv*o21;
        wred32(p0, p1);
        if (ll == 0){
            int n = base + r;
            float v0 = ftanh(p0 + bo0), v1 = ftanh(p1 + bo1);
            size_t i0 = (size_t)(n*2)*T_STEPS + t, i1 = (size_t)(n*2+1)*T_STEPS + t;
            if (F){ ((float*)outp)[i0] = v0; ((float*)outp)[i1] = v1; }
            else  { ((u16*)outp)[i0] = f2bf(v0); ((u16*)outp)[i1] = f2bf(v1); }
        }
    }
}

extern "C" void kernel_launch(void* const* d_in, const int* in_sizes, int n_in,
                              void* d_out, int out_size, void* d_ws, size_t ws_size,
                              hipStream_t stream)
{
    const void* cond = d_in[0];
    const void* z    = d_in[1];
    const void* cw1  = d_in[2];
    const void* cb1  = d_in[3];
    const void* cw2  = d_in[4];
    const void* cb2  = d_in[5];
    const void* cbw1 = d_in[6];
    const void* cbb1 = d_in[7];
    const void* cbw2 = d_in[8];
    const void* cbb2 = d_in[9];
    const void* iw1  = d_in[10];
    const void* ib1  = d_in[11];
    const void* iw2  = d_in[12];
    const void* ib2  = d_in[13];
    const void* wih  = d_in[14];
    const void* whh  = d_in[15];
    const void* bih  = d_in[16];
    const void* bhh  = d_in[17];
    const void* wihb = d_in[18];
    const void* whhb = d_in[19];
    const void* bihb = d_in[20];
    const void* bhhb = d_in[21];
    const void* sw   = d_in[22];
    const void* sb   = d_in[23];
    const void* mw   = d_in[24];
    const void* mb   = d_in[25];
    const void* ow1  = d_in[26];
    const void* ob1  = d_in[27];
    const void* ow2  = d_in[28];
    const void* ob2  = d_in[29];
    const void* probe = whh;   // dtype-detection probe buffer

    char* ws = (char*)d_ws;
    size_t off = 0;
    f16* disp  = (f16*)(ws + off); off += (size_t)2*NAG*128*2;          //  2 MB
    f16* semb  = (f16*)(ws + off); off += (size_t)T_STEPS*NAG*64*2;     // 15.7 MB
    f16* hencF = (f16*)(ws + off); off += (size_t)T_STEPS*NAG*128*2;    // 31.5 MB
    f16* hencB = (f16*)(ws + off); off += (size_t)T_STEPS*NAG*128*2;    // 31.5 MB

    k_cond<<<dim3(NAG/8,2), 256, 0, stream>>>(cond, cw1,cb1,cw2,cb2, cbw1,cbb1,cbw2,cbb2, probe, disp);
    k_emb<<<3840, 256, 0, stream>>>(z, iw1,ib1,iw2,ib2, probe, semb);
    k_gru_mfma<<<dim3(NAG/32,2), 384, 0, stream>>>(semb, disp, wih,whh,bih,bhh, wihb,whhb,bihb,bhhb, probe, hencF, hencB);
    k_post<<<3840, 256, 0, stream>>>(hencF, hencB, sw,sb, mw,mb, ow1,ob1,ow2,ob2, probe, d_out);
}

// Round 19
// 485.105 us; speedup vs baseline: 1.1047x; 1.0258x over previous
//
#include <hip/hip_runtime.h>
#include <hip/hip_bf16.h>

typedef unsigned int u32;
typedef unsigned short u16;
typedef _Float16 f16;
typedef float f32x2 __attribute__((ext_vector_type(2)));
typedef _Float16 f16x2 __attribute__((ext_vector_type(2)));
typedef u32 u32x4 __attribute__((ext_vector_type(4)));
typedef u32 u32x2v __attribute__((ext_vector_type(2)));
typedef _Float16 f16x8 __attribute__((ext_vector_type(8)));
typedef float f32x4v __attribute__((ext_vector_type(4)));

#define LN_EPS 1e-5f
#define T_STEPS 30
#define NAG 4096

__device__ __forceinline__ float bf2f(u16 v){
    union { u32 u; float f; } c; c.u = ((u32)v) << 16; return c.f;
}
__device__ __forceinline__ u16 f2bf(float f){
    union { float f; u32 u; } c; c.f = f;
    return (u16)((c.u + 0x7FFFu + ((c.u >> 16) & 1u)) >> 16);
}
__device__ __forceinline__ u32 pk_h2(float a, float b){
    f16x2 h; h[0] = (f16)a; h[1] = (f16)b;
    return __builtin_bit_cast(u32, h);
}
__device__ __forceinline__ f32x2 unpk_h2(u32 p){
    f16x2 h = __builtin_bit_cast(f16x2, p);
    f32x2 r; r[0] = (float)h[0]; r[1] = (float)h[1]; return r;
}
__device__ __forceinline__ u32 bfp2h2(u32 p){
    union { u32 u; float f; } a, b;
    a.u = p << 16; b.u = p & 0xFFFF0000u;
    return pk_h2(a.f, b.f);
}
__device__ __forceinline__ float fdot2u(u32 a, u32 b, float c){
    return __builtin_amdgcn_fdot2(__builtin_bit_cast(f16x2, a),
                                  __builtin_bit_cast(f16x2, b), c, false);
}
// dtype probe: fp32 buffers read as u16 have random mantissa halves at even
// positions (~50% decode to |x|>=128); bf16 weight buffers (|w| < 1) never do.
__device__ __forceinline__ int detect_f32(const void* probe){
    const u16* p = (const u16*)probe;
    int bad = 0;
    #pragma unroll
    for (int i = 0; i < 32; i++){
        u32 e = (p[2*i] >> 7) & 0xFF;
        bad += (e >= 0x86) ? 1 : 0;
    }
    return bad > 4;
}
__device__ __forceinline__ float ldin(const void* p, int i, int F){
    float v;
    if (F) v = ((const float*)p)[i];
    else   v = bf2f(((const u16*)p)[i]);
    return v;
}
__device__ __forceinline__ u32 ld_pair(const void* p, int pairIdx, int F){
    if (F){ const float* f = (const float*)p; return pk_h2(f[2*pairIdx], f[2*pairIdx+1]); }
    return bfp2h2(((const u32*)p)[pairIdx]);
}
__device__ __forceinline__ void wred64(float& s, float& q){
    #pragma unroll
    for (int m = 1; m < 64; m <<= 1){ s += __shfl_xor(s, m); q += __shfl_xor(q, m); }
}
__device__ __forceinline__ void wred32(float& s, float& q){
    #pragma unroll
    for (int m = 1; m < 32; m <<= 1){ s += __shfl_xor(s, m); q += __shfl_xor(q, m); }
}
__device__ __forceinline__ float lrelu(float x){ return fmaxf(x, 0.1f * x); }
__device__ __forceinline__ float sigm(float x){ return 1.0f / (1.0f + __expf(-x)); }
__device__ __forceinline__ float ftanh(float x){ return 1.0f - 2.0f / (1.0f + __expf(2.0f * x)); }
__device__ __forceinline__ void ln128(float a0, float a1, float& o0, float& o1){
    float s = a0 + a1, q = a0*a0 + a1*a1;
    wred64(s, q);
    float m = s * (1.f/128.f), v = q * (1.f/128.f) - m*m;
    float rs = rsqrtf(fmaxf(v, 0.f) + LN_EPS);
    o0 = (a0 - m) * rs; o1 = (a1 - m) * rs;
}

// ---------------- K1: cond embeddings (both dirs): [N,2] -> 64 -> 128 ----------------
// 256 thr / 8 agents per block; w2 staged TRANSPOSED in LDS (coalesced global
// reads; +2-pad stride 130, reads conflict-free). One barrier total.
__global__ __launch_bounds__(256) void k_cond(
    const void* __restrict__ cond,
    const void* __restrict__ w1a, const void* __restrict__ b1a,
    const void* __restrict__ w2a, const void* __restrict__ b2a,
    const void* __restrict__ w1b, const void* __restrict__ b1b,
    const void* __restrict__ w2b, const void* __restrict__ b2b,
    const void* __restrict__ probe,
    f16* __restrict__ disp)
{
    __shared__ float w2T[64*130];     // [k][u], padded stride 130 (33.3 KB)
    __shared__ float w1s[128], b1s[64], b2s[128];
    __shared__ float x1s[4][64];      // layer-1 outs, per wave
    int F = detect_f32(probe);
    int tid = threadIdx.x, dir = blockIdx.y;
    const void* w1 = dir ? w1b : w1a; const void* b1 = dir ? b1b : b1a;
    const void* w2 = dir ? w2b : w2a; const void* b2 = dir ? b2b : b2a;
    // stage w2 transposed: global idx i = u*64 + k, k fastest -> coalesced reads
    for (int i = tid; i < 8192; i += 256){
        int u = i >> 6, k = i & 63;
        w2T[k*130 + u] = ldin(w2, i, F);
    }
    if (tid < 128) w1s[tid] = ldin(w1, tid, F);
    else           b2s[tid - 128] = ldin(b2, tid - 128, F);
    if (tid < 64)  b1s[tid] = ldin(b1, tid, F);
    __syncthreads();

    int w = tid >> 6, lane = tid & 63;
    int nb = blockIdx.x * 8 + w * 2;
    #pragma unroll
    for (int a = 0; a < 2; a++){
        int n = nb + a;
        float c0 = ldin(cond, n*2, F), c1 = ldin(cond, n*2+1, F);
        float y = w1s[lane*2] * c0 + w1s[lane*2+1] * c1 + b1s[lane];
        float s = y, q = y*y; wred64(s, q);
        float m = s * (1.f/64.f), v = q * (1.f/64.f) - m*m;
        float rs = rsqrtf(fmaxf(v, 0.f) + LN_EPS);
        x1s[w][lane] = lrelu((y - m) * rs);   // per-wave buffer, no barrier needed
        float y0 = b2s[lane], y1 = b2s[lane + 64];
        #pragma unroll 8
        for (int k = 0; k < 64; k++){
            float xv = x1s[w][k];
            y0 = fmaf(xv, w2T[k*130 + lane], y0);
            y1 = fmaf(xv, w2T[k*130 + 64 + lane], y1);
        }
        float o0, o1; ln128(y0, y1, o0, o1);
        f16* dp = disp + ((size_t)dir * NAG + n) * 128;
        dp[lane] = (f16)lrelu(o0);
        dp[lane+64] = (f16)lrelu(o1);
    }
}

// ---------------- K2: scene embedding: z[T,N,128] -> 32 -> 64 (packed fdot2) ----------
__global__ __launch_bounds__(256) void k_emb(
    const void* __restrict__ z,
    const void* __restrict__ iw1, const void* __restrict__ ib1,
    const void* __restrict__ iw2, const void* __restrict__ ib2,
    const void* __restrict__ probe,
    f16* __restrict__ semb)
{
    __shared__ u32 w1p[64*32];      // [kp<64][e<32]
    __shared__ u32 w2p[16*64];      // [kp<16][e<64]
    __shared__ u32 zp[4][2][64];    // z rows packed, 2 rows per wave pass
    __shared__ u32 x1p[4][2][16];   // layer-1 outs packed
    int F = detect_f32(probe);
    int tid = threadIdx.x;
    for (int i = tid; i < 2048; i += 256){
        int kp = i >> 5, e = i & 31;
        w1p[kp*32+e] = ld_pair(iw1, e*64 + kp, F);      // iw1 [32][128]
    }
    for (int i = tid; i < 1024; i += 256){
        int kp = i >> 6, e = i & 63;
        w2p[kp*64+e] = ld_pair(iw2, e*16 + kp, F);      // iw2 [64][32]
    }
    __syncthreads();
    int w = tid >> 6, lane = tid & 63;
    int rp = lane >> 5, ll = lane & 31;
    float b1v = ldin(ib1, ll, F);
    float b2v = ldin(ib2, lane, F);
    int rowbase = (blockIdx.x * 4 + w) * 8;
    #pragma unroll 1
    for (int pass = 0; pass < 4; pass++){
        int row = rowbase + pass*2 + rp;                // half-wave rp owns this row
        zp[w][rp][ll]    = ld_pair(z, row*64 + ll, F);
        zp[w][rp][ll+32] = ld_pair(z, row*64 + ll + 32, F);
        float y1 = b1v;
        #pragma unroll 8
        for (int kp = 0; kp < 64; kp++)
            y1 = fdot2u(zp[w][rp][kp], w1p[kp*32+ll], y1);
        float s = y1, q = y1*y1; wred32(s, q);
        float m = s*(1.f/32.f), v = q*(1.f/32.f)-m*m, rs = rsqrtf(fmaxf(v,0.f)+LN_EPS);
        float sv = lrelu((y1-m)*rs);
        float e0 = __shfl(sv, (lane & 32) + 2*(lane & 15));
        float e1 = __shfl(sv, (lane & 32) + 2*(lane & 15) + 1);
        if (ll < 16) x1p[w][rp][ll] = pk_h2(e0, e1);
        #pragma unroll
        for (int r2 = 0; r2 < 2; r2++){
            float y2 = b2v;
            #pragma unroll
            for (int kp = 0; kp < 16; kp++)
                y2 = fdot2u(x1p[w][r2][kp], w2p[kp*64+lane], y2);
            s = y2; q = y2*y2; wred64(s, q);
            m = s*(1.f/64.f); v = q*(1.f/64.f)-m*m; rs = rsqrtf(fmaxf(v,0.f)+LN_EPS);
            semb[(size_t)(rowbase + pass*2 + r2)*64 + lane] = (f16)lrelu((y2-m)*rs);
        }
    }
}

// ---------------- K3: MFMA bidirectional LN-GRU ----------------
// R3/R7 winner verbatim (measured 168-170 us; revert confirmed R15). Falsified:
// R6 2-block split (195), R9 12-wave dir-fusion (197), R12 LBAR surgery (187).
// Step cost is intra-phase dependent chains; leave as-is.
__global__ __launch_bounds__(384) void k_gru_mfma(
    const f16* __restrict__ semb, const f16* __restrict__ disp,
    const void* __restrict__ wihA, const void* __restrict__ whhA,
    const void* __restrict__ bihA, const void* __restrict__ bhhA,
    const void* __restrict__ wihB, const void* __restrict__ whhB,
    const void* __restrict__ bihB, const void* __restrict__ bhhB,
    const void* __restrict__ probe,
    f16* __restrict__ hencF, f16* __restrict__ hencB)
{
    __shared__ __align__(16) f16 hbuf[32][136];      // h per agent (pad 8 f16)
    __shared__ __align__(16) f16 xbuf[2][32][72];    // x per agent, double-buffered
    __shared__ __align__(16) f16 rzbuf[2][32][136];  // r,z values [gate][agent][d]
    __shared__ __align__(16) float bias1[384];       // u<256: bih+bhh; u>=256: bih
    __shared__ __align__(16) float bias2[128];       // bhh for n-units
    __shared__ float redS[6][32], redQ[6][32];
    int F = detect_f32(probe);
    int tid = threadIdx.x, dir = blockIdx.y;
    int w = tid >> 6, lane = tid & 63;
    int quad = lane >> 4, l15 = lane & 15;
    int gate = w >> 1;
    const void* wih = dir ? wihB : wihA;  const void* whh = dir ? whhB : whhA;
    const void* bih = dir ? bihB : bihA;  const void* bhh = dir ? bhhB : bhhA;
    f16* henc = dir ? hencB : hencF;

    // ---- A fragments: Af[mt][kt]; lane supplies A[m=l15][k=quad*8+j] ----
    f16x8 Af[4][6];
    if (F){
        #pragma unroll
        for (int mt = 0; mt < 4; mt++){
            int u = (w*4+mt)*16 + l15;
            #pragma unroll
            for (int kt = 0; kt < 6; kt++){
                const float* src = (kt < 4)
                    ? ((const float*)whh + (size_t)u*128 + kt*32 + quad*8)
                    : ((const float*)wih + (size_t)u*64 + (kt-4)*32 + quad*8);
                f16x8 v;
                #pragma unroll
                for (int j = 0; j < 8; j++) v[j] = (f16)src[j];
                Af[mt][kt] = v;
            }
        }
    } else {
        #pragma unroll
        for (int mt = 0; mt < 4; mt++){
            int u = (w*4+mt)*16 + l15;
            #pragma unroll
            for (int kt = 0; kt < 6; kt++){
                const u16* src = (kt < 4)
                    ? ((const u16*)whh + (size_t)u*128 + kt*32 + quad*8)
                    : ((const u16*)wih + (size_t)u*64 + (kt-4)*32 + quad*8);
                f16x8 v;
                #pragma unroll
                for (int j = 0; j < 8; j++) v[j] = (f16)bf2f(src[j]);
                Af[mt][kt] = v;
            }
        }
    }
    // biases -> LDS (keeps VGPR pressure down; C-frags init from these per step)
    if (tid < 384){
        float bi = ldin(bih, tid, F), bh = ldin(bhh, tid, F);
        bias1[tid] = (tid < 256) ? (bi + bh) : bi;
        if (tid >= 256) bias2[tid - 256] = bh;
    }

    int nb = blockIdx.x * 32;
    // stage h0 (from disp) and x(t0)
    for (int i = tid; i < 512; i += 384){
        int a = i >> 4, c = i & 15;
        u32x4 v = *(const u32x4*)(disp + ((size_t)dir*NAG + nb + a)*128 + c*8);
        *(u32x4*)&hbuf[a][c*8] = v;
    }
    int tx0 = dir ? (T_STEPS-1) : 0;
    for (int i = tid; i < 256; i += 384){
        int a = i >> 3, c = i & 7;
        u32x4 v = *(const u32x4*)(semb + ((size_t)tx0*NAG + nb + a)*64 + c*8);
        *(u32x4*)&xbuf[0][a][c*8] = v;
    }
    __syncthreads();

    #pragma unroll 1
    for (int t = 0; t < T_STEPS; t++){
        int tx = dir ? (T_STEPS-1-t) : t;
        int cur = t & 1;
        // ---- C init from biases ----
        f32x4v C0[4][2], C1[4][2];
        #pragma unroll
        for (int mt = 0; mt < 4; mt++){
            f32x4v b1f = *(const f32x4v*)&bias1[(w*4+mt)*16 + quad*4];
            if (gate < 2){
                C0[mt][0] = b1f; C0[mt][1] = b1f;          // combined bias
                C1[mt][0] = b1f; C1[mt][1] = b1f;          // unused on this path
            } else {
                f32x4v b2f = *(const f32x4v*)&bias2[((w&1)*4+mt)*16 + quad*4];
                C0[mt][0] = b2f; C0[mt][1] = b2f;          // hh + bhh
                C1[mt][0] = b1f; C1[mt][1] = b1f;          // ih + bih
            }
        }
        // ---- MFMA phase ----
        #pragma unroll
        for (int nt = 0; nt < 2; nt++){
            int ag = nt*16 + l15;
            f16x8 B0 = *(const f16x8*)&hbuf[ag][0*32 + quad*8];
            f16x8 B1 = *(const f16x8*)&hbuf[ag][1*32 + quad*8];
            f16x8 B2 = *(const f16x8*)&hbuf[ag][2*32 + quad*8];
            f16x8 B3 = *(const f16x8*)&hbuf[ag][3*32 + quad*8];
            f16x8 B4 = *(const f16x8*)&xbuf[cur][ag][0*32 + quad*8];
            f16x8 B5 = *(const f16x8*)&xbuf[cur][ag][1*32 + quad*8];
            if (gate < 2){
                #pragma unroll
                for (int mt = 0; mt < 4; mt++){
                    f32x4v c = C0[mt][nt];
                    c = __builtin_amdgcn_mfma_f32_16x16x32_f16(Af[mt][0], B0, c, 0, 0, 0);
                    c = __builtin_amdgcn_mfma_f32_16x16x32_f16(Af[mt][1], B1, c, 0, 0, 0);
                    c = __builtin_amdgcn_mfma_f32_16x16x32_f16(Af[mt][2], B2, c, 0, 0, 0);
                    c = __builtin_amdgcn_mfma_f32_16x16x32_f16(Af[mt][3], B3, c, 0, 0, 0);
                    c = __builtin_amdgcn_mfma_f32_16x16x32_f16(Af[mt][4], B4, c, 0, 0, 0);
                    c = __builtin_amdgcn_mfma_f32_16x16x32_f16(Af[mt][5], B5, c, 0, 0, 0);
                    C0[mt][nt] = c;
                }
            } else {
                #pragma unroll
                for (int mt = 0; mt < 4; mt++){
                    f32x4v c = C0[mt][nt];
                    c = __builtin_amdgcn_mfma_f32_16x16x32_f16(Af[mt][0], B0, c, 0, 0, 0);
                    c = __builtin_amdgcn_mfma_f32_16x16x32_f16(Af[mt][1], B1, c, 0, 0, 0);
                    c = __builtin_amdgcn_mfma_f32_16x16x32_f16(Af[mt][2], B2, c, 0, 0, 0);
                    c = __builtin_amdgcn_mfma_f32_16x16x32_f16(Af[mt][3], B3, c, 0, 0, 0);
                    C0[mt][nt] = c;
                    f32x4v d = C1[mt][nt];
                    d = __builtin_amdgcn_mfma_f32_16x16x32_f16(Af[mt][4], B4, d, 0, 0, 0);
                    d = __builtin_amdgcn_mfma_f32_16x16x32_f16(Af[mt][5], B5, d, 0, 0, 0);
                    C1[mt][nt] = d;
                }
            }
        }
        // ---- phase1 tail: r/z LN partials; n-waves stage next x ----
        if (gate < 2){
            #pragma unroll
            for (int nt = 0; nt < 2; nt++){
                float s = 0.f, q = 0.f;
                #pragma unroll
                for (int mt = 0; mt < 4; mt++)
                    #pragma unroll
                    for (int r = 0; r < 4; r++){
                        float v = C0[mt][nt][r];
                        s += v; q += v*v;
                    }
                s += __shfl_xor(s, 16); q += __shfl_xor(q, 16);
                s += __shfl_xor(s, 32); q += __shfl_xor(q, 32);
                if (lane < 16){ redS[w][nt*16 + l15] = s; redQ[w][nt*16 + l15] = q; }
            }
        } else {
            if (t + 1 < T_STEPS){
                int txn = dir ? (T_STEPS-2-t) : (t+1);
                int i0 = (w-4)*64 + lane;                  // [0,128)
                #pragma unroll
                for (int rep = 0; rep < 2; rep++){
                    int i = i0 + rep*128;
                    int a = i >> 3, c = i & 7;
                    u32x4 v = *(const u32x4*)(semb + ((size_t)txn*NAG + nb + a)*64 + c*8);
                    *(u32x4*)&xbuf[cur^1][a][c*8] = v;
                }
            }
        }
        __syncthreads();                                   // bar1
        // ---- phase2: r/z finalize LN + sigmoid -> rzbuf ----
        if (gate < 2){
            #pragma unroll
            for (int nt = 0; nt < 2; nt++){
                int ag = nt*16 + l15;
                float s = redS[w][ag] + redS[w^1][ag];
                float q = redQ[w][ag] + redQ[w^1][ag];
                float m = s*(1.f/128.f), vv = q*(1.f/128.f) - m*m;
                float rs = rsqrtf(fmaxf(vv, 0.f) + LN_EPS);
                #pragma unroll
                for (int mt = 0; mt < 4; mt++){
                    float g0 = sigm((C0[mt][nt][0] - m)*rs);
                    float g1 = sigm((C0[mt][nt][1] - m)*rs);
                    float g2 = sigm((C0[mt][nt][2] - m)*rs);
                    float g3 = sigm((C0[mt][nt][3] - m)*rs);
                    int dg = ((w&1)*4 + mt)*16 + quad*4;
                    u32x2v p; p.x = pk_h2(g0, g1); p.y = pk_h2(g2, g3);
                    *(u32x2v*)&rzbuf[gate][ag][dg] = p;
                }
            }
        }
        __syncthreads();                                   // bar2
        // ---- phase3: n-pre = ih + r * hh ; LN partials ----
        if (gate == 2){
            #pragma unroll
            for (int nt = 0; nt < 2; nt++){
                int ag = nt*16 + l15;
                float s = 0.f, q = 0.f;
                #pragma unroll
                for (int mt = 0; mt < 4; mt++){
                    int dg = ((w&1)*4 + mt)*16 + quad*4;
                    u32x2v rp = *(const u32x2v*)&rzbuf[0][ag][dg];
                    f32x2 ra = unpk_h2(rp.x), rb = unpk_h2(rp.y);
                    float p0 = C1[mt][nt][0] + ra[0]*C0[mt][nt][0];
                    float p1 = C1[mt][nt][1] + ra[1]*C0[mt][nt][1];
                    float p2 = C1[mt][nt][2] + rb[0]*C0[mt][nt][2];
                    float p3 = C1[mt][nt][3] + rb[1]*C0[mt][nt][3];
                    C0[mt][nt][0] = p0; C0[mt][nt][1] = p1;
                    C0[mt][nt][2] = p2; C0[mt][nt][3] = p3;
                    s += p0 + p1 + p2 + p3;
                    q += p0*p0 + p1*p1 + p2*p2 + p3*p3;
                }
                s += __shfl_xor(s, 16); q += __shfl_xor(q, 16);
                s += __shfl_xor(s, 32); q += __shfl_xor(q, 32);
                if (lane < 16){ redS[w][ag] = s; redQ[w][ag] = q; }
            }
        }
        __syncthreads();                                   // bar3
        // ---- phase4: n finalize, h update, write back ----
        if (gate == 2){
            #pragma unroll
            for (int nt = 0; nt < 2; nt++){
                int ag = nt*16 + l15;
                float s = redS[4][ag] + redS[5][ag];
                float q = redQ[4][ag] + redQ[5][ag];
                float m = s*(1.f/128.f), vv = q*(1.f/128.f) - m*m;
                float rs = rsqrtf(fmaxf(vv, 0.f) + LN_EPS);
                #pragma unroll
                for (int mt = 0; mt < 4; mt++){
                    int dg = ((w&1)*4 + mt)*16 + quad*4;
                    float n0 = ftanh((C0[mt][nt][0] - m)*rs);
                    float n1 = ftanh((C0[mt][nt][1] - m)*rs);
                    float n2 = ftanh((C0[mt][nt][2] - m)*rs);
                    float n3 = ftanh((C0[mt][nt][3] - m)*rs);
                    u32x2v zp = *(const u32x2v*)&rzbuf[1][ag][dg];
                    f32x2 za = unpk_h2(zp.x), zb = unpk_h2(zp.y);
                    u32x2v hp = *(const u32x2v*)&hbuf[ag][dg];
                    f32x2 ha = unpk_h2(hp.x), hb2 = unpk_h2(hp.y);
                    float h0 = (1.f - za[0])*n0 + za[0]*ha[0];
                    float h1 = (1.f - za[1])*n1 + za[1]*ha[1];
                    float h2 = (1.f - zb[0])*n2 + zb[0]*hb2[0];
                    float h3 = (1.f - zb[1])*n3 + zb[1]*hb2[1];
                    u32x2v o; o.x = pk_h2(h0, h1); o.y = pk_h2(h2, h3);
                    *(u32x2v*)&hbuf[ag][dg] = o;
                    *(u32x2v*)(henc + ((size_t)tx*NAG + nb + ag)*128 + dg) = o;
                }
            }
        }
        __syncthreads();                                   // bar4
    }
}

// ---------------- K4: fused post-GRU: seq -> pairwise(factored) -> out head ----------------
// All three serial-LN phases now use the 8-lane-group transform (R0 pairwise
// +260us, R12 seq-LN +12us). This round: the HEAD. Was 4 iters x 2 wred32 =
// 80 dependent shuffle hops + 4x redundant w1p column re-reads + divergent
// ll==0 epilogue. Now: group g owns row g, lane l owns h-dims 4l..4l+3;
// w1p read as b128 (broadcast across groups); LN + ow2-dot = two 3-hop
// reduces. fr re-strided [8][68] (+4 pad): keeps 16B alignment (272B rows)
// and spreads group-rows across banks 4g -> head column reads conflict-free.
__global__ __launch_bounds__(256) void k_post(
    const f16* __restrict__ hf, const f16* __restrict__ hb,
    const void* __restrict__ sw, const void* __restrict__ sb,
    const void* __restrict__ mw, const void* __restrict__ mb,
    const void* __restrict__ ow1, const void* __restrict__ ob1,
    const void* __restrict__ ow2, const void* __restrict__ ob2,
    const void* __restrict__ probe,
    void* __restrict__ outp)
{
    __shared__ u32 swp[64*64];     // [kp][unit]
    __shared__ u32 mwp[32*64];     // [kp][unit]
    __shared__ u32 w1p[64*32];     // [kp][e<32]
    __shared__ __align__(16) u32 xr[4][8][64];   // x pairs; later yT / uuT alias
    __shared__ __align__(16) u32 fr[4][8][68];   // full=[seq|ave] pairs, stride 68
    int F = detect_f32(probe);
    int tid = threadIdx.x;
    for (int i = tid; i < 4096; i += 256){
        int u = i & 63, kp = i >> 6;
        swp[kp*64+u] = ld_pair(sw, u*64 + kp, F);      // sw [64][128]
    }
    for (int i = tid; i < 2048; i += 256){
        int u = i & 63, kp = i >> 6;   // kp < 32
        mwp[kp*64+u] = ld_pair(mw, u*32 + kp, F);      // mw [64][64]
    }
    for (int i = tid; i < 2048; i += 256){
        int e = i & 31, kp = i >> 5;   // kp < 64
        w1p[kp*32+e] = ld_pair(ow1, e*64 + kp, F);     // ow1 [32][128]
    }
    int w = tid >> 6, lane = tid & 63;
    int unit = blockIdx.x*4 + w;        // t*512 + scene
    int t = unit >> 9, sc = unit & 511;
    int base = sc * 8;
    size_t rowbase = (size_t)t*NAG + base;
    const u32* hfu = (const u32*)hf;
    const u32* hbu = (const u32*)hb;
    #pragma unroll
    for (int r = 0; r < 8; r++){
        f32x2 a = unpk_h2(hfu[(rowbase + r)*64 + lane]);
        f32x2 b = unpk_h2(hbu[(rowbase + r)*64 + lane]);
        xr[w][r][lane] = pk_h2(0.5f*(a[0]+b[0]), 0.5f*(a[1]+b[1]));
    }
    __syncthreads();

    float bs = ldin(sb, lane, F);
    float y[8];
    #pragma unroll
    for (int r = 0; r < 8; r++) y[r] = bs;
    for (int kp = 0; kp < 64; kp++){
        u32 wv = swp[kp*64 + lane];
        #pragma unroll
        for (int r = 0; r < 8; r++) y[r] = fdot2u(xr[w][r][kp], wv, y[r]);
    }
    // ---- seq-LN transposed: group g owns row g; lane l=lane&7 owns outs 8l..8l+7.
    // xr[w] is dead after the y-loop; reuse as yT scratch (rotate-swizzle). ----
    float* yT = (float*)&xr[w][0][0];
    #pragma unroll
    for (int r = 0; r < 8; r++)
        yT[r*64 + ((lane + r*8) & 63)] = y[r];
    {
        int g = lane >> 3, l8 = (lane & 7) * 8;
        const f32x4v* yp = (const f32x4v*)&yT[g*64 + ((l8 + g*8) & 63)];
        f32x4v ya = yp[0], yb = yp[1];
        float s = 0.f, q = 0.f;
        #pragma unroll
        for (int d = 0; d < 4; d++){
            s += ya[d] + yb[d];
            q += ya[d]*ya[d] + yb[d]*yb[d];
        }
        #pragma unroll
        for (int m = 1; m < 8; m <<= 1){ s += __shfl_xor(s, m); q += __shfl_xor(q, m); }
        float mm = s*(1.f/64.f), vv = q*(1.f/64.f) - mm*mm;
        float rs = rsqrtf(fmaxf(vv, 0.f) + LN_EPS);
        u32x4 sv;
        sv[0] = pk_h2(lrelu((ya[0]-mm)*rs), lrelu((ya[1]-mm)*rs));
        sv[1] = pk_h2(lrelu((ya[2]-mm)*rs), lrelu((ya[3]-mm)*rs));
        sv[2] = pk_h2(lrelu((yb[0]-mm)*rs), lrelu((yb[1]-mm)*rs));
        sv[3] = pk_h2(lrelu((yb[2]-mm)*rs), lrelu((yb[3]-mm)*rs));
        *(u32x4*)&fr[w][g][(lane & 7)*4] = sv;      // seq pairs 4l..4l+3 of row g
    }
    // ---- uu = seq @ mw.T (no bias); unit = lane ----
    float uu[8];
    #pragma unroll
    for (int r = 0; r < 8; r++) uu[r] = 0.f;
    for (int kp = 0; kp < 32; kp++){
        u32 wv = mwp[kp*64 + lane];
        #pragma unroll
        for (int r = 0; r < 8; r++) uu[r] = fdot2u(fr[w][r][kp], wv, uu[r]);
    }
    // ---- transpose uu -> uuT (aliases xr[w], dead again after yT use) ----
    // row r dim d stored at pos (d + 8r) & 63 (rotate-swizzle, bank-friendly)
    float* uuT = (float*)&xr[w][0][0];
    #pragma unroll
    for (int r = 0; r < 8; r++)
        uuT[r*64 + ((lane + r*8) & 63)] = uu[r];
    // ---- pairwise: group g owns agent i=g; lane l=lane&7 owns dims 8l..8l+7 ----
    int g = lane >> 3, l8 = (lane & 7) * 8;
    float bmv[8];
    #pragma unroll
    for (int d = 0; d < 8; d++) bmv[d] = ldin(mb, l8 + d, F);
    const f32x4v* up = (const f32x4v*)&uuT[g*64 + ((l8 + g*8) & 63)];
    f32x4v ui0 = up[0], ui1 = up[1];
    float acc[8];
    #pragma unroll
    for (int d = 0; d < 8; d++) acc[d] = 0.f;
    #pragma unroll
    for (int rr = 0; rr < 7; rr++){
        int j = (g + 1 + rr) & 7;
        const f32x4v* jp = (const f32x4v*)&uuT[j*64 + ((l8 + j*8) & 63)];
        f32x4v uj0 = jp[0], uj1 = jp[1];
        float p[8]; float s = 0.f, q = 0.f;
        #pragma unroll
        for (int d = 0; d < 4; d++){
            float v0 = ui0[d] - uj0[d] + bmv[d];
            float v1 = ui1[d] - uj1[d] + bmv[4+d];
            p[d] = v0; p[4+d] = v1;
            s += v0 + v1; q += v0*v0 + v1*v1;
        }
        #pragma unroll
        for (int m = 1; m < 8; m <<= 1){ s += __shfl_xor(s, m); q += __shfl_xor(q, m); }
        float mm = s*(1.f/64.f), vv = q*(1.f/64.f) - mm*mm;
        float rs = rsqrtf(fmaxf(vv, 0.f) + LN_EPS);
        #pragma unroll
        for (int d = 0; d < 8; d++) acc[d] += lrelu((p[d] - mm)*rs);
    }
    // ave -> fr[w][g][32 + l*4 ..], pairs of dims (8l+2k, 8l+2k+1)
    u32x4 av;
    #pragma unroll
    for (int k = 0; k < 4; k++) av[k] = pk_h2(acc[2*k]*(1.f/7.f), acc[2*k+1]*(1.f/7.f));
    *(u32x4*)&fr[w][g][32 + (lane & 7)*4] = av;
    __builtin_amdgcn_s_barrier();   // fr rows complete before head reads
    // ---- head (restructured): group g owns row g; lane l owns h-dims 4l..4l+3.
    // fr[w][g][kp]: broadcast within group; banks 4g across groups (stride 68)
    // -> conflict-free. w1p b128 read: same addr across groups -> broadcast. ----
    {
        int l4 = (lane & 7) * 4;
        float hb1[4], ho20[4], ho21[4];
        #pragma unroll
        for (int d = 0; d < 4; d++){
            hb1[d]  = ldin(ob1, l4 + d, F);
            ho20[d] = ldin(ow2, l4 + d, F);
            ho21[d] = ldin(ow2, 32 + l4 + d, F);
        }
        float h[4];
        #pragma unroll
        for (int d = 0; d < 4; d++) h[d] = hb1[d];
        for (int kp = 0; kp < 64; kp++){
            u32 fv = fr[w][g][kp];
            u32x4 wv4 = *(const u32x4*)&w1p[kp*32 + l4];
            #pragma unroll
            for (int d = 0; d < 4; d++) h[d] = fdot2u(fv, wv4[d], h[d]);
        }
        float s = 0.f, q = 0.f;
        #pragma unroll
        for (int d = 0; d < 4; d++){ s += h[d]; q += h[d]*h[d]; }
        #pragma unroll
        for (int m = 1; m < 8; m <<= 1){ s += __shfl_xor(s, m); q += __shfl_xor(q, m); }
        float mm = s*(1.f/32.f), vv = q*(1.f/32.f) - mm*mm;
        float rs = rsqrtf(fmaxf(vv, 0.f) + LN_EPS);
        float p0 = 0.f, p1 = 0.f;
        #pragma unroll
        for (int d = 0; d < 4; d++){
            float hv = lrelu((h[d] - mm)*rs);
            p0 = fmaf(hv, ho20[d], p0);
            p1 = fmaf(hv, ho21[d], p1);
        }
        #pragma unroll
        for (int m = 1; m < 8; m <<= 1){ p0 += __shfl_xor(p0, m); p1 += __shfl_xor(p1, m); }
        if ((lane & 7) == 0){
            float bo0 = ldin(ob2, 0, F), bo1 = ldin(ob2, 1, F);
            int n = base + g;
            float v0 = ftanh(p0 + bo0), v1 = ftanh(p1 + bo1);
            size_t i0 = (size_t)(n*2)*T_STEPS + t, i1 = (size_t)(n*2+1)*T_STEPS + t;
            if (F){ ((float*)outp)[i0] = v0; ((float*)outp)[i1] = v1; }
            else  { ((u16*)outp)[i0] = f2bf(v0); ((u16*)outp)[i1] = f2bf(v1); }
        }
    }
}

extern "C" void kernel_launch(void* const* d_in, const int* in_sizes, int n_in,
                              void* d_out, int out_size, void* d_ws, size_t ws_size,
                              hipStream_t stream)
{
    const void* cond = d_in[0];
    const void* z    = d_in[1];
    const void* cw1  = d_in[2];
    const void* cb1  = d_in[3];
    const void* cw2  = d_in[4];
    const void* cb2  = d_in[5];
    const void* cbw1 = d_in[6];
    const void* cbb1 = d_in[7];
    const void* cbw2 = d_in[8];
    const void* cbb2 = d_in[9];
    const void* iw1  = d_in[10];
    const void* ib1  = d_in[11];
    const void* iw2  = d_in[12];
    const void* ib2  = d_in[13];
    const void* wih  = d_in[14];
    const void* whh  = d_in[15];
    const void* bih  = d_in[16];
    const void* bhh  = d_in[17];
    const void* wihb = d_in[18];
    const void* whhb = d_in[19];
    const void* bihb = d_in[20];
    const void* bhhb = d_in[21];
    const void* sw   = d_in[22];
    const void* sb   = d_in[23];
    const void* mw   = d_in[24];
    const void* mb   = d_in[25];
    const void* ow1  = d_in[26];
    const void* ob1  = d_in[27];
    const void* ow2  = d_in[28];
    const void* ob2  = d_in[29];
    const void* probe = whh;   // dtype-detection probe buffer

    char* ws = (char*)d_ws;
    size_t off = 0;
    f16* disp  = (f16*)(ws + off); off += (size_t)2*NAG*128*2;          //  2 MB
    f16* semb  = (f16*)(ws + off); off += (size_t)T_STEPS*NAG*64*2;     // 15.7 MB
    f16* hencF = (f16*)(ws + off); off += (size_t)T_STEPS*NAG*128*2;    // 31.5 MB
    f16* hencB = (f16*)(ws + off); off += (size_t)T_STEPS*NAG*128*2;    // 31.5 MB

    k_cond<<<dim3(NAG/8,2), 256, 0, stream>>>(cond, cw1,cb1,cw2,cb2, cbw1,cbb1,cbw2,cbb2, probe, disp);
    k_emb<<<3840, 256, 0, stream>>>(z, iw1,ib1,iw2,ib2, probe, semb);
    k_gru_mfma<<<dim3(NAG/32,2), 384, 0, stream>>>(semb, disp, wih,whh,bih,bhh, wihb,whhb,bihb,bhhb, probe, hencF, hencB);
    k_post<<<3840, 256, 0, stream>>>(hencF, hencB, sw,sb, mw,mb, ow1,ob1,ow2,ob2, probe, d_out);
}

// Round 21
// 481.280 us; speedup vs baseline: 1.1135x; 1.0079x over previous
//
#include <hip/hip_runtime.h>
#include <hip/hip_bf16.h>

typedef unsigned int u32;
typedef unsigned short u16;
typedef _Float16 f16;
typedef float f32x2 __attribute__((ext_vector_type(2)));
typedef _Float16 f16x2 __attribute__((ext_vector_type(2)));
typedef u32 u32x4 __attribute__((ext_vector_type(4)));
typedef u32 u32x2v __attribute__((ext_vector_type(2)));
typedef _Float16 f16x8 __attribute__((ext_vector_type(8)));
typedef float f32x4v __attribute__((ext_vector_type(4)));

#define LN_EPS 1e-5f
#define T_STEPS 30
#define NAG 4096

__device__ __forceinline__ float bf2f(u16 v){
    union { u32 u; float f; } c; c.u = ((u32)v) << 16; return c.f;
}
__device__ __forceinline__ u16 f2bf(float f){
    union { float f; u32 u; } c; c.f = f;
    return (u16)((c.u + 0x7FFFu + ((c.u >> 16) & 1u)) >> 16);
}
__device__ __forceinline__ u32 pk_h2(float a, float b){
    f16x2 h; h[0] = (f16)a; h[1] = (f16)b;
    return __builtin_bit_cast(u32, h);
}
__device__ __forceinline__ f32x2 unpk_h2(u32 p){
    f16x2 h = __builtin_bit_cast(f16x2, p);
    f32x2 r; r[0] = (float)h[0]; r[1] = (float)h[1]; return r;
}
__device__ __forceinline__ u32 bfp2h2(u32 p){
    union { u32 u; float f; } a, b;
    a.u = p << 16; b.u = p & 0xFFFF0000u;
    return pk_h2(a.f, b.f);
}
__device__ __forceinline__ float fdot2u(u32 a, u32 b, float c){
    return __builtin_amdgcn_fdot2(__builtin_bit_cast(f16x2, a),
                                  __builtin_bit_cast(f16x2, b), c, false);
}
// dtype probe: fp32 buffers read as u16 have random mantissa halves at even
// positions (~50% decode to |x|>=128); bf16 weight buffers (|w| < 1) never do.
__device__ __forceinline__ int detect_f32(const void* probe){
    const u16* p = (const u16*)probe;
    int bad = 0;
    #pragma unroll
    for (int i = 0; i < 32; i++){
        u32 e = (p[2*i] >> 7) & 0xFF;
        bad += (e >= 0x86) ? 1 : 0;
    }
    return bad > 4;
}
__device__ __forceinline__ float ldin(const void* p, int i, int F){
    float v;
    if (F) v = ((const float*)p)[i];
    else   v = bf2f(((const u16*)p)[i]);
    return v;
}
__device__ __forceinline__ u32 ld_pair(const void* p, int pairIdx, int F){
    if (F){ const float* f = (const float*)p; return pk_h2(f[2*pairIdx], f[2*pairIdx+1]); }
    return bfp2h2(((const u32*)p)[pairIdx]);
}
__device__ __forceinline__ void wred64(float& s, float& q){
    #pragma unroll
    for (int m = 1; m < 64; m <<= 1){ s += __shfl_xor(s, m); q += __shfl_xor(q, m); }
}
__device__ __forceinline__ void wred32(float& s, float& q){
    #pragma unroll
    for (int m = 1; m < 32; m <<= 1){ s += __shfl_xor(s, m); q += __shfl_xor(q, m); }
}
__device__ __forceinline__ float lrelu(float x){ return fmaxf(x, 0.1f * x); }
__device__ __forceinline__ float sigm(float x){ return 1.0f / (1.0f + __expf(-x)); }
__device__ __forceinline__ float ftanh(float x){ return 1.0f - 2.0f / (1.0f + __expf(2.0f * x)); }
__device__ __forceinline__ void ln128(float a0, float a1, float& o0, float& o1){
    float s = a0 + a1, q = a0*a0 + a1*a1;
    wred64(s, q);
    float m = s * (1.f/128.f), v = q * (1.f/128.f) - m*m;
    float rs = rsqrtf(fmaxf(v, 0.f) + LN_EPS);
    o0 = (a0 - m) * rs; o1 = (a1 - m) * rs;
}

// ---------------- K1: cond embeddings (both dirs): [N,2] -> 64 -> 128 ----------------
// 256 thr / 8 agents per block; w2 staged TRANSPOSED in LDS (coalesced global
// reads; +2-pad stride 130, reads conflict-free). One barrier total.
__global__ __launch_bounds__(256) void k_cond(
    const void* __restrict__ cond,
    const void* __restrict__ w1a, const void* __restrict__ b1a,
    const void* __restrict__ w2a, const void* __restrict__ b2a,
    const void* __restrict__ w1b, const void* __restrict__ b1b,
    const void* __restrict__ w2b, const void* __restrict__ b2b,
    const void* __restrict__ probe,
    f16* __restrict__ disp)
{
    __shared__ float w2T[64*130];     // [k][u], padded stride 130 (33.3 KB)
    __shared__ float w1s[128], b1s[64], b2s[128];
    __shared__ float x1s[4][64];      // layer-1 outs, per wave
    int F = detect_f32(probe);
    int tid = threadIdx.x, dir = blockIdx.y;
    const void* w1 = dir ? w1b : w1a; const void* b1 = dir ? b1b : b1a;
    const void* w2 = dir ? w2b : w2a; const void* b2 = dir ? b2b : b2a;
    // stage w2 transposed: global idx i = u*64 + k, k fastest -> coalesced reads
    for (int i = tid; i < 8192; i += 256){
        int u = i >> 6, k = i & 63;
        w2T[k*130 + u] = ldin(w2, i, F);
    }
    if (tid < 128) w1s[tid] = ldin(w1, tid, F);
    else           b2s[tid - 128] = ldin(b2, tid - 128, F);
    if (tid < 64)  b1s[tid] = ldin(b1, tid, F);
    __syncthreads();

    int w = tid >> 6, lane = tid & 63;
    int nb = blockIdx.x * 8 + w * 2;
    #pragma unroll
    for (int a = 0; a < 2; a++){
        int n = nb + a;
        float c0 = ldin(cond, n*2, F), c1 = ldin(cond, n*2+1, F);
        float y = w1s[lane*2] * c0 + w1s[lane*2+1] * c1 + b1s[lane];
        float s = y, q = y*y; wred64(s, q);
        float m = s * (1.f/64.f), v = q * (1.f/64.f) - m*m;
        float rs = rsqrtf(fmaxf(v, 0.f) + LN_EPS);
        x1s[w][lane] = lrelu((y - m) * rs);   // per-wave buffer, no barrier needed
        float y0 = b2s[lane], y1 = b2s[lane + 64];
        #pragma unroll 8
        for (int k = 0; k < 64; k++){
            float xv = x1s[w][k];
            y0 = fmaf(xv, w2T[k*130 + lane], y0);
            y1 = fmaf(xv, w2T[k*130 + 64 + lane], y1);
        }
        float o0, o1; ln128(y0, y1, o0, o1);
        f16* dp = disp + ((size_t)dir * NAG + n) * 128;
        dp[lane] = (f16)lrelu(o0);
        dp[lane+64] = (f16)lrelu(o1);
    }
}

// ---------------- K2: scene embedding: z[T,N,128] -> 32 -> 64 (packed fdot2) ----------
// Layer-2 LN now batched via the 8-lane-group transform (4th application; R0
// pairwise +260us, R12 seq-LN +12us, R15 head +12.5us). Was: 4 passes x 2 rows
// x wred64 = 96 dependent shuffle hops/wave. Now: y2acc[8] accumulated in one
// 16-iter kp loop (w2p reads cut 128 -> 16 by reusing each weight word across
// 8 rows), transpose through y2T (rotate-swizzle), single 3-hop reduce
// normalizes all 8 rows, coalesced u32x4 output (128 B/row).
__global__ __launch_bounds__(256) void k_emb(
    const void* __restrict__ z,
    const void* __restrict__ iw1, const void* __restrict__ ib1,
    const void* __restrict__ iw2, const void* __restrict__ ib2,
    const void* __restrict__ probe,
    f16* __restrict__ semb)
{
    __shared__ u32 w1p[64*32];      // [kp<64][e<32]
    __shared__ u32 w2p[16*64];      // [kp<16][e<64]
    __shared__ u32 zp[4][2][64];    // z rows packed, 2 rows per wave pass
    __shared__ u32 x1p[4][8][16];   // layer-1 outs packed, all 8 rows
    __shared__ __align__(16) float y2T[4][512];  // layer-2 transpose scratch
    int F = detect_f32(probe);
    int tid = threadIdx.x;
    for (int i = tid; i < 2048; i += 256){
        int kp = i >> 5, e = i & 31;
        w1p[kp*32+e] = ld_pair(iw1, e*64 + kp, F);      // iw1 [32][128]
    }
    for (int i = tid; i < 1024; i += 256){
        int kp = i >> 6, e = i & 63;
        w2p[kp*64+e] = ld_pair(iw2, e*16 + kp, F);      // iw2 [64][32]
    }
    __syncthreads();
    int w = tid >> 6, lane = tid & 63;
    int rp = lane >> 5, ll = lane & 31;
    float b1v = ldin(ib1, ll, F);
    float b2v = ldin(ib2, lane, F);
    int rowbase = (blockIdx.x * 4 + w) * 8;
    // ---- layer 1: 4 passes x 2 rows; outs -> x1p[w][row][kp] ----
    #pragma unroll 1
    for (int pass = 0; pass < 4; pass++){
        int row = rowbase + pass*2 + rp;                // half-wave rp owns this row
        zp[w][rp][ll]    = ld_pair(z, row*64 + ll, F);
        zp[w][rp][ll+32] = ld_pair(z, row*64 + ll + 32, F);
        float y1 = b1v;
        #pragma unroll 8
        for (int kp = 0; kp < 64; kp++)
            y1 = fdot2u(zp[w][rp][kp], w1p[kp*32+ll], y1);
        float s = y1, q = y1*y1; wred32(s, q);
        float m = s*(1.f/32.f), v = q*(1.f/32.f)-m*m, rs = rsqrtf(fmaxf(v,0.f)+LN_EPS);
        float sv = lrelu((y1-m)*rs);
        float e0 = __shfl(sv, (lane & 32) + 2*(lane & 15));
        float e1 = __shfl(sv, (lane & 32) + 2*(lane & 15) + 1);
        if (ll < 16) x1p[w][pass*2+rp][ll] = pk_h2(e0, e1);
    }
    // ---- layer 2 batched: lane owns unit `lane` for all 8 rows ----
    float y2a[8];
    #pragma unroll
    for (int r = 0; r < 8; r++) y2a[r] = b2v;
    #pragma unroll
    for (int kp = 0; kp < 16; kp++){
        u32 wv = w2p[kp*64 + lane];
        #pragma unroll
        for (int r = 0; r < 8; r++)
            y2a[r] = fdot2u(x1p[w][r][kp], wv, y2a[r]);
    }
    // transpose (rotate-swizzle) -> 8-lane-group LN, all 8 rows in one reduce
    #pragma unroll
    for (int r = 0; r < 8; r++)
        y2T[w][r*64 + ((lane + r*8) & 63)] = y2a[r];
    {
        int g = lane >> 3, l8 = (lane & 7) * 8;
        const f32x4v* yp = (const f32x4v*)&y2T[w][g*64 + ((l8 + g*8) & 63)];
        f32x4v ya = yp[0], yb = yp[1];
        float s = 0.f, q = 0.f;
        #pragma unroll
        for (int d = 0; d < 4; d++){
            s += ya[d] + yb[d];
            q += ya[d]*ya[d] + yb[d]*yb[d];
        }
        #pragma unroll
        for (int m = 1; m < 8; m <<= 1){ s += __shfl_xor(s, m); q += __shfl_xor(q, m); }
        float mm = s*(1.f/64.f), vv = q*(1.f/64.f) - mm*mm;
        float rs = rsqrtf(fmaxf(vv, 0.f) + LN_EPS);
        u32x4 sv;
        sv[0] = pk_h2(lrelu((ya[0]-mm)*rs), lrelu((ya[1]-mm)*rs));
        sv[1] = pk_h2(lrelu((ya[2]-mm)*rs), lrelu((ya[3]-mm)*rs));
        sv[2] = pk_h2(lrelu((yb[0]-mm)*rs), lrelu((yb[1]-mm)*rs));
        sv[3] = pk_h2(lrelu((yb[2]-mm)*rs), lrelu((yb[3]-mm)*rs));
        *(u32x4*)(semb + (size_t)(rowbase + g)*64 + l8) = sv;   // 128B/row, coalesced
    }
}

// ---------------- K3: MFMA bidirectional LN-GRU ----------------
// R3/R7 winner verbatim (measured 168-170 us; revert confirmed R15). Falsified:
// R6 2-block split (195), R9 12-wave dir-fusion (197), R12 LBAR surgery (187).
// Step cost is intra-phase dependent chains; leave as-is.
__global__ __launch_bounds__(384) void k_gru_mfma(
    const f16* __restrict__ semb, const f16* __restrict__ disp,
    const void* __restrict__ wihA, const void* __restrict__ whhA,
    const void* __restrict__ bihA, const void* __restrict__ bhhA,
    const void* __restrict__ wihB, const void* __restrict__ whhB,
    const void* __restrict__ bihB, const void* __restrict__ bhhB,
    const void* __restrict__ probe,
    f16* __restrict__ hencF, f16* __restrict__ hencB)
{
    __shared__ __align__(16) f16 hbuf[32][136];      // h per agent (pad 8 f16)
    __shared__ __align__(16) f16 xbuf[2][32][72];    // x per agent, double-buffered
    __shared__ __align__(16) f16 rzbuf[2][32][136];  // r,z values [gate][agent][d]
    __shared__ __align__(16) float bias1[384];       // u<256: bih+bhh; u>=256: bih
    __shared__ __align__(16) float bias2[128];       // bhh for n-units
    __shared__ float redS[6][32], redQ[6][32];
    int F = detect_f32(probe);
    int tid = threadIdx.x, dir = blockIdx.y;
    int w = tid >> 6, lane = tid & 63;
    int quad = lane >> 4, l15 = lane & 15;
    int gate = w >> 1;
    const void* wih = dir ? wihB : wihA;  const void* whh = dir ? whhB : whhA;
    const void* bih = dir ? bihB : bihA;  const void* bhh = dir ? bhhB : bhhA;
    f16* henc = dir ? hencB : hencF;

    // ---- A fragments: Af[mt][kt]; lane supplies A[m=l15][k=quad*8+j] ----
    f16x8 Af[4][6];
    if (F){
        #pragma unroll
        for (int mt = 0; mt < 4; mt++){
            int u = (w*4+mt)*16 + l15;
            #pragma unroll
            for (int kt = 0; kt < 6; kt++){
                const float* src = (kt < 4)
                    ? ((const float*)whh + (size_t)u*128 + kt*32 + quad*8)
                    : ((const float*)wih + (size_t)u*64 + (kt-4)*32 + quad*8);
                f16x8 v;
                #pragma unroll
                for (int j = 0; j < 8; j++) v[j] = (f16)src[j];
                Af[mt][kt] = v;
            }
        }
    } else {
        #pragma unroll
        for (int mt = 0; mt < 4; mt++){
            int u = (w*4+mt)*16 + l15;
            #pragma unroll
            for (int kt = 0; kt < 6; kt++){
                const u16* src = (kt < 4)
                    ? ((const u16*)whh + (size_t)u*128 + kt*32 + quad*8)
                    : ((const u16*)wih + (size_t)u*64 + (kt-4)*32 + quad*8);
                f16x8 v;
                #pragma unroll
                for (int j = 0; j < 8; j++) v[j] = (f16)bf2f(src[j]);
                Af[mt][kt] = v;
            }
        }
    }
    // biases -> LDS (keeps VGPR pressure down; C-frags init from these per step)
    if (tid < 384){
        float bi = ldin(bih, tid, F), bh = ldin(bhh, tid, F);
        bias1[tid] = (tid < 256) ? (bi + bh) : bi;
        if (tid >= 256) bias2[tid - 256] = bh;
    }

    int nb = blockIdx.x * 32;
    // stage h0 (from disp) and x(t0)
    for (int i = tid; i < 512; i += 384){
        int a = i >> 4, c = i & 15;
        u32x4 v = *(const u32x4*)(disp + ((size_t)dir*NAG + nb + a)*128 + c*8);
        *(u32x4*)&hbuf[a][c*8] = v;
    }
    int tx0 = dir ? (T_STEPS-1) : 0;
    for (int i = tid; i < 256; i += 384){
        int a = i >> 3, c = i & 7;
        u32x4 v = *(const u32x4*)(semb + ((size_t)tx0*NAG + nb + a)*64 + c*8);
        *(u32x4*)&xbuf[0][a][c*8] = v;
    }
    __syncthreads();

    #pragma unroll 1
    for (int t = 0; t < T_STEPS; t++){
        int tx = dir ? (T_STEPS-1-t) : t;
        int cur = t & 1;
        // ---- C init from biases ----
        f32x4v C0[4][2], C1[4][2];
        #pragma unroll
        for (int mt = 0; mt < 4; mt++){
            f32x4v b1f = *(const f32x4v*)&bias1[(w*4+mt)*16 + quad*4];
            if (gate < 2){
                C0[mt][0] = b1f; C0[mt][1] = b1f;          // combined bias
                C1[mt][0] = b1f; C1[mt][1] = b1f;          // unused on this path
            } else {
                f32x4v b2f = *(const f32x4v*)&bias2[((w&1)*4+mt)*16 + quad*4];
                C0[mt][0] = b2f; C0[mt][1] = b2f;          // hh + bhh
                C1[mt][0] = b1f; C1[mt][1] = b1f;          // ih + bih
            }
        }
        // ---- MFMA phase ----
        #pragma unroll
        for (int nt = 0; nt < 2; nt++){
            int ag = nt*16 + l15;
            f16x8 B0 = *(const f16x8*)&hbuf[ag][0*32 + quad*8];
            f16x8 B1 = *(const f16x8*)&hbuf[ag][1*32 + quad*8];
            f16x8 B2 = *(const f16x8*)&hbuf[ag][2*32 + quad*8];
            f16x8 B3 = *(const f16x8*)&hbuf[ag][3*32 + quad*8];
            f16x8 B4 = *(const f16x8*)&xbuf[cur][ag][0*32 + quad*8];
            f16x8 B5 = *(const f16x8*)&xbuf[cur][ag][1*32 + quad*8];
            if (gate < 2){
                #pragma unroll
                for (int mt = 0; mt < 4; mt++){
                    f32x4v c = C0[mt][nt];
                    c = __builtin_amdgcn_mfma_f32_16x16x32_f16(Af[mt][0], B0, c, 0, 0, 0);
                    c = __builtin_amdgcn_mfma_f32_16x16x32_f16(Af[mt][1], B1, c, 0, 0, 0);
                    c = __builtin_amdgcn_mfma_f32_16x16x32_f16(Af[mt][2], B2, c, 0, 0, 0);
                    c = __builtin_amdgcn_mfma_f32_16x16x32_f16(Af[mt][3], B3, c, 0, 0, 0);
                    c = __builtin_amdgcn_mfma_f32_16x16x32_f16(Af[mt][4], B4, c, 0, 0, 0);
                    c = __builtin_amdgcn_mfma_f32_16x16x32_f16(Af[mt][5], B5, c, 0, 0, 0);
                    C0[mt][nt] = c;
                }
            } else {
                #pragma unroll
                for (int mt = 0; mt < 4; mt++){
                    f32x4v c = C0[mt][nt];
                    c = __builtin_amdgcn_mfma_f32_16x16x32_f16(Af[mt][0], B0, c, 0, 0, 0);
                    c = __builtin_amdgcn_mfma_f32_16x16x32_f16(Af[mt][1], B1, c, 0, 0, 0);
                    c = __builtin_amdgcn_mfma_f32_16x16x32_f16(Af[mt][2], B2, c, 0, 0, 0);
                    c = __builtin_amdgcn_mfma_f32_16x16x32_f16(Af[mt][3], B3, c, 0, 0, 0);
                    C0[mt][nt] = c;
                    f32x4v d = C1[mt][nt];
                    d = __builtin_amdgcn_mfma_f32_16x16x32_f16(Af[mt][4], B4, d, 0, 0, 0);
                    d = __builtin_amdgcn_mfma_f32_16x16x32_f16(Af[mt][5], B5, d, 0, 0, 0);
                    C1[mt][nt] = d;
                }
            }
        }
        // ---- phase1 tail: r/z LN partials; n-waves stage next x ----
        if (gate < 2){
            #pragma unroll
            for (int nt = 0; nt < 2; nt++){
                float s = 0.f, q = 0.f;
                #pragma unroll
                for (int mt = 0; mt < 4; mt++)
                    #pragma unroll
                    for (int r = 0; r < 4; r++){
                        float v = C0[mt][nt][r];
                        s += v; q += v*v;
                    }
                s += __shfl_xor(s, 16); q += __shfl_xor(q, 16);
                s += __shfl_xor(s, 32); q += __shfl_xor(q, 32);
                if (lane < 16){ redS[w][nt*16 + l15] = s; redQ[w][nt*16 + l15] = q; }
            }
        } else {
            if (t + 1 < T_STEPS){
                int txn = dir ? (T_STEPS-2-t) : (t+1);
                int i0 = (w-4)*64 + lane;                  // [0,128)
                #pragma unroll
                for (int rep = 0; rep < 2; rep++){
                    int i = i0 + rep*128;
                    int a = i >> 3, c = i & 7;
                    u32x4 v = *(const u32x4*)(semb + ((size_t)txn*NAG + nb + a)*64 + c*8);
                    *(u32x4*)&xbuf[cur^1][a][c*8] = v;
                }
            }
        }
        __syncthreads();                                   // bar1
        // ---- phase2: r/z finalize LN + sigmoid -> rzbuf ----
        if (gate < 2){
            #pragma unroll
            for (int nt = 0; nt < 2; nt++){
                int ag = nt*16 + l15;
                float s = redS[w][ag] + redS[w^1][ag];
                float q = redQ[w][ag] + redQ[w^1][ag];
                float m = s*(1.f/128.f), vv = q*(1.f/128.f) - m*m;
                float rs = rsqrtf(fmaxf(vv, 0.f) + LN_EPS);
                #pragma unroll
                for (int mt = 0; mt < 4; mt++){
                    float g0 = sigm((C0[mt][nt][0] - m)*rs);
                    float g1 = sigm((C0[mt][nt][1] - m)*rs);
                    float g2 = sigm((C0[mt][nt][2] - m)*rs);
                    float g3 = sigm((C0[mt][nt][3] - m)*rs);
                    int dg = ((w&1)*4 + mt)*16 + quad*4;
                    u32x2v p; p.x = pk_h2(g0, g1); p.y = pk_h2(g2, g3);
                    *(u32x2v*)&rzbuf[gate][ag][dg] = p;
                }
            }
        }
        __syncthreads();                                   // bar2
        // ---- phase3: n-pre = ih + r * hh ; LN partials ----
        if (gate == 2){
            #pragma unroll
            for (int nt = 0; nt < 2; nt++){
                int ag = nt*16 + l15;
                float s = 0.f, q = 0.f;
                #pragma unroll
                for (int mt = 0; mt < 4; mt++){
                    int dg = ((w&1)*4 + mt)*16 + quad*4;
                    u32x2v rp = *(const u32x2v*)&rzbuf[0][ag][dg];
                    f32x2 ra = unpk_h2(rp.x), rb = unpk_h2(rp.y);
                    float p0 = C1[mt][nt][0] + ra[0]*C0[mt][nt][0];
                    float p1 = C1[mt][nt][1] + ra[1]*C0[mt][nt][1];
                    float p2 = C1[mt][nt][2] + rb[0]*C0[mt][nt][2];
                    float p3 = C1[mt][nt][3] + rb[1]*C0[mt][nt][3];
                    C0[mt][nt][0] = p0; C0[mt][nt][1] = p1;
                    C0[mt][nt][2] = p2; C0[mt][nt][3] = p3;
                    s += p0 + p1 + p2 + p3;
                    q += p0*p0 + p1*p1 + p2*p2 + p3*p3;
                }
                s += __shfl_xor(s, 16); q += __shfl_xor(q, 16);
                s += __shfl_xor(s, 32); q += __shfl_xor(q, 32);
                if (lane < 16){ redS[w][ag] = s; redQ[w][ag] = q; }
            }
        }
        __syncthreads();                                   // bar3
        // ---- phase4: n finalize, h update, write back ----
        if (gate == 2){
            #pragma unroll
            for (int nt = 0; nt < 2; nt++){
                int ag = nt*16 + l15;
                float s = redS[4][ag] + redS[5][ag];
                float q = redQ[4][ag] + redQ[5][ag];
                float m = s*(1.f/128.f), vv = q*(1.f/128.f) - m*m;
                float rs = rsqrtf(fmaxf(vv, 0.f) + LN_EPS);
                #pragma unroll
                for (int mt = 0; mt < 4; mt++){
                    int dg = ((w&1)*4 + mt)*16 + quad*4;
                    float n0 = ftanh((C0[mt][nt][0] - m)*rs);
                    float n1 = ftanh((C0[mt][nt][1] - m)*rs);
                    float n2 = ftanh((C0[mt][nt][2] - m)*rs);
                    float n3 = ftanh((C0[mt][nt][3] - m)*rs);
                    u32x2v zp = *(const u32x2v*)&rzbuf[1][ag][dg];
                    f32x2 za = unpk_h2(zp.x), zb = unpk_h2(zp.y);
                    u32x2v hp = *(const u32x2v*)&hbuf[ag][dg];
                    f32x2 ha = unpk_h2(hp.x), hb2 = unpk_h2(hp.y);
                    float h0 = (1.f - za[0])*n0 + za[0]*ha[0];
                    float h1 = (1.f - za[1])*n1 + za[1]*ha[1];
                    float h2 = (1.f - zb[0])*n2 + zb[0]*hb2[0];
                    float h3 = (1.f - zb[1])*n3 + zb[1]*hb2[1];
                    u32x2v o; o.x = pk_h2(h0, h1); o.y = pk_h2(h2, h3);
                    *(u32x2v*)&hbuf[ag][dg] = o;
                    *(u32x2v*)(henc + ((size_t)tx*NAG + nb + ag)*128 + dg) = o;
                }
            }
        }
        __syncthreads();                                   // bar4
    }
}

// ---------------- K4: fused post-GRU: seq -> pairwise(factored) -> out head ----------------
// All serial-LN phases use the 8-lane-group transform (R0 pairwise +260us,
// R12 seq-LN +12us, R15 head +12.5us). fr strided [8][68] (+4 pad): 16B
// alignment kept, group-rows spread across banks -> head reads conflict-free.
__global__ __launch_bounds__(256) void k_post(
    const f16* __restrict__ hf, const f16* __restrict__ hb,
    const void* __restrict__ sw, const void* __restrict__ sb,
    const void* __restrict__ mw, const void* __restrict__ mb,
    const void* __restrict__ ow1, const void* __restrict__ ob1,
    const void* __restrict__ ow2, const void* __restrict__ ob2,
    const void* __restrict__ probe,
    void* __restrict__ outp)
{
    __shared__ u32 swp[64*64];     // [kp][unit]
    __shared__ u32 mwp[32*64];     // [kp][unit]
    __shared__ u32 w1p[64*32];     // [kp][e<32]
    __shared__ __align__(16) u32 xr[4][8][64];   // x pairs; later yT / uuT alias
    __shared__ __align__(16) u32 fr[4][8][68];   // full=[seq|ave] pairs, stride 68
    int F = detect_f32(probe);
    int tid = threadIdx.x;
    for (int i = tid; i < 4096; i += 256){
        int u = i & 63, kp = i >> 6;
        swp[kp*64+u] = ld_pair(sw, u*64 + kp, F);      // sw [64][128]
    }
    for (int i = tid; i < 2048; i += 256){
        int u = i & 63, kp = i >> 6;   // kp < 32
        mwp[kp*64+u] = ld_pair(mw, u*32 + kp, F);      // mw [64][64]
    }
    for (int i = tid; i < 2048; i += 256){
        int e = i & 31, kp = i >> 5;   // kp < 64
        w1p[kp*32+e] = ld_pair(ow1, e*64 + kp, F);     // ow1 [32][128]
    }
    int w = tid >> 6, lane = tid & 63;
    int unit = blockIdx.x*4 + w;        // t*512 + scene
    int t = unit >> 9, sc = unit & 511;
    int base = sc * 8;
    size_t rowbase = (size_t)t*NAG + base;
    const u32* hfu = (const u32*)hf;
    const u32* hbu = (const u32*)hb;
    #pragma unroll
    for (int r = 0; r < 8; r++){
        f32x2 a = unpk_h2(hfu[(rowbase + r)*64 + lane]);
        f32x2 b = unpk_h2(hbu[(rowbase + r)*64 + lane]);
        xr[w][r][lane] = pk_h2(0.5f*(a[0]+b[0]), 0.5f*(a[1]+b[1]));
    }
    __syncthreads();

    float bs = ldin(sb, lane, F);
    float y[8];
    #pragma unroll
    for (int r = 0; r < 8; r++) y[r] = bs;
    for (int kp = 0; kp < 64; kp++){
        u32 wv = swp[kp*64 + lane];
        #pragma unroll
        for (int r = 0; r < 8; r++) y[r] = fdot2u(xr[w][r][kp], wv, y[r]);
    }
    // ---- seq-LN transposed: group g owns row g; lane l=lane&7 owns outs 8l..8l+7.
    // xr[w] is dead after the y-loop; reuse as yT scratch (rotate-swizzle). ----
    float* yT = (float*)&xr[w][0][0];
    #pragma unroll
    for (int r = 0; r < 8; r++)
        yT[r*64 + ((lane + r*8) & 63)] = y[r];
    {
        int g = lane >> 3, l8 = (lane & 7) * 8;
        const f32x4v* yp = (const f32x4v*)&yT[g*64 + ((l8 + g*8) & 63)];
        f32x4v ya = yp[0], yb = yp[1];
        float s = 0.f, q = 0.f;
        #pragma unroll
        for (int d = 0; d < 4; d++){
            s += ya[d] + yb[d];
            q += ya[d]*ya[d] + yb[d]*yb[d];
        }
        #pragma unroll
        for (int m = 1; m < 8; m <<= 1){ s += __shfl_xor(s, m); q += __shfl_xor(q, m); }
        float mm = s*(1.f/64.f), vv = q*(1.f/64.f) - mm*mm;
        float rs = rsqrtf(fmaxf(vv, 0.f) + LN_EPS);
        u32x4 sv;
        sv[0] = pk_h2(lrelu((ya[0]-mm)*rs), lrelu((ya[1]-mm)*rs));
        sv[1] = pk_h2(lrelu((ya[2]-mm)*rs), lrelu((ya[3]-mm)*rs));
        sv[2] = pk_h2(lrelu((yb[0]-mm)*rs), lrelu((yb[1]-mm)*rs));
        sv[3] = pk_h2(lrelu((yb[2]-mm)*rs), lrelu((yb[3]-mm)*rs));
        *(u32x4*)&fr[w][g][(lane & 7)*4] = sv;      // seq pairs 4l..4l+3 of row g
    }
    // ---- uu = seq @ mw.T (no bias); unit = lane ----
    float uu[8];
    #pragma unroll
    for (int r = 0; r < 8; r++) uu[r] = 0.f;
    for (int kp = 0; kp < 32; kp++){
        u32 wv = mwp[kp*64 + lane];
        #pragma unroll
        for (int r = 0; r < 8; r++) uu[r] = fdot2u(fr[w][r][kp], wv, uu[r]);
    }
    // ---- transpose uu -> uuT (aliases xr[w], dead again after yT use) ----
    // row r dim d stored at pos (d + 8r) & 63 (rotate-swizzle, bank-friendly)
    float* uuT = (float*)&xr[w][0][0];
    #pragma unroll
    for (int r = 0; r < 8; r++)
        uuT[r*64 + ((lane + r*8) & 63)] = uu[r];
    // ---- pairwise: group g owns agent i=g; lane l=lane&7 owns dims 8l..8l+7 ----
    int g = lane >> 3, l8 = (lane & 7) * 8;
    float bmv[8];
    #pragma unroll
    for (int d = 0; d < 8; d++) bmv[d] = ldin(mb, l8 + d, F);
    const f32x4v* up = (const f32x4v*)&uuT[g*64 + ((l8 + g*8) & 63)];
    f32x4v ui0 = up[0], ui1 = up[1];
    float acc[8];
    #pragma unroll
    for (int d = 0; d < 8; d++) acc[d] = 0.f;
    #pragma unroll
    for (int rr = 0; rr < 7; rr++){
        int j = (g + 1 + rr) & 7;
        const f32x4v* jp = (const f32x4v*)&uuT[j*64 + ((l8 + j*8) & 63)];
        f32x4v uj0 = jp[0], uj1 = jp[1];
        float p[8]; float s = 0.f, q = 0.f;
        #pragma unroll
        for (int d = 0; d < 4; d++){
            float v0 = ui0[d] - uj0[d] + bmv[d];
            float v1 = ui1[d] - uj1[d] + bmv[4+d];
            p[d] = v0; p[4+d] = v1;
            s += v0 + v1; q += v0*v0 + v1*v1;
        }
        #pragma unroll
        for (int m = 1; m < 8; m <<= 1){ s += __shfl_xor(s, m); q += __shfl_xor(q, m); }
        float mm = s*(1.f/64.f), vv = q*(1.f/64.f) - mm*mm;
        float rs = rsqrtf(fmaxf(vv, 0.f) + LN_EPS);
        #pragma unroll
        for (int d = 0; d < 8; d++) acc[d] += lrelu((p[d] - mm)*rs);
    }
    // ave -> fr[w][g][32 + l*4 ..], pairs of dims (8l+2k, 8l+2k+1)
    u32x4 av;
    #pragma unroll
    for (int k = 0; k < 4; k++) av[k] = pk_h2(acc[2*k]*(1.f/7.f), acc[2*k+1]*(1.f/7.f));
    *(u32x4*)&fr[w][g][32 + (lane & 7)*4] = av;
    __builtin_amdgcn_s_barrier();   // fr rows complete before head reads
    // ---- head (restructured): group g owns row g; lane l owns h-dims 4l..4l+3.
    // fr[w][g][kp]: broadcast within group; banks 4g across groups (stride 68)
    // -> conflict-free. w1p b128 read: same addr across groups -> broadcast. ----
    {
        int l4 = (lane & 7) * 4;
        float hb1[4], ho20[4], ho21[4];
        #pragma unroll
        for (int d = 0; d < 4; d++){
            hb1[d]  = ldin(ob1, l4 + d, F);
            ho20[d] = ldin(ow2, l4 + d, F);
            ho21[d] = ldin(ow2, 32 + l4 + d, F);
        }
        float h[4];
        #pragma unroll
        for (int d = 0; d < 4; d++) h[d] = hb1[d];
        for (int kp = 0; kp < 64; kp++){
            u32 fv = fr[w][g][kp];
            u32x4 wv4 = *(const u32x4*)&w1p[kp*32 + l4];
            #pragma unroll
            for (int d = 0; d < 4; d++) h[d] = fdot2u(fv, wv4[d], h[d]);
        }
        float s = 0.f, q = 0.f;
        #pragma unroll
        for (int d = 0; d < 4; d++){ s += h[d]; q += h[d]*h[d]; }
        #pragma unroll
        for (int m = 1; m < 8; m <<= 1){ s += __shfl_xor(s, m); q += __shfl_xor(q, m); }
        float mm = s*(1.f/32.f), vv = q*(1.f/32.f) - mm*mm;
        float rs = rsqrtf(fmaxf(vv, 0.f) + LN_EPS);
        float p0 = 0.f, p1 = 0.f;
        #pragma unroll
        for (int d = 0; d < 4; d++){
            float hv = lrelu((h[d] - mm)*rs);
            p0 = fmaf(hv, ho20[d], p0);
            p1 = fmaf(hv, ho21[d], p1);
        }
        #pragma unroll
        for (int m = 1; m < 8; m <<= 1){ p0 += __shfl_xor(p0, m); p1 += __shfl_xor(p1, m); }
        if ((lane & 7) == 0){
            float bo0 = ldin(ob2, 0, F), bo1 = ldin(ob2, 1, F);
            int n = base + g;
            float v0 = ftanh(p0 + bo0), v1 = ftanh(p1 + bo1);
            size_t i0 = (size_t)(n*2)*T_STEPS + t, i1 = (size_t)(n*2+1)*T_STEPS + t;
            if (F){ ((float*)outp)[i0] = v0; ((float*)outp)[i1] = v1; }
            else  { ((u16*)outp)[i0] = f2bf(v0); ((u16*)outp)[i1] = f2bf(v1); }
        }
    }
}

extern "C" void kernel_launch(void* const* d_in, const int* in_sizes, int n_in,
                              void* d_out, int out_size, void* d_ws, size_t ws_size,
                              hipStream_t stream)
{
    const void* cond = d_in[0];
    const void* z    = d_in[1];
    const void* cw1  = d_in[2];
    const void* cb1  = d_in[3];
    const void* cw2  = d_in[4];
    const void* cb2  = d_in[5];
    const void* cbw1 = d_in[6];
    const void* cbb1 = d_in[7];
    const void* cbw2 = d_in[8];
    const void* cbb2 = d_in[9];
    const void* iw1  = d_in[10];
    const void* ib1  = d_in[11];
    const void* iw2  = d_in[12];
    const void* ib2  = d_in[13];
    const void* wih  = d_in[14];
    const void* whh  = d_in[15];
    const void* bih  = d_in[16];
    const void* bhh  = d_in[17];
    const void* wihb = d_in[18];
    const void* whhb = d_in[19];
    const void* bihb = d_in[20];
    const void* bhhb = d_in[21];
    const void* sw   = d_in[22];
    const void* sb   = d_in[23];
    const void* mw   = d_in[24];
    const void* mb   = d_in[25];
    const void* ow1  = d_in[26];
    const void* ob1  = d_in[27];
    const void* ow2  = d_in[28];
    const void* ob2  = d_in[29];
    const void* probe = whh;   // dtype-detection probe buffer

    char* ws = (char*)d_ws;
    size_t off = 0;
    f16* disp  = (f16*)(ws + off); off += (size_t)2*NAG*128*2;          //  2 MB
    f16* semb  = (f16*)(ws + off); off += (size_t)T_STEPS*NAG*64*2;     // 15.7 MB
    f16* hencF = (f16*)(ws + off); off += (size_t)T_STEPS*NAG*128*2;    // 31.5 MB
    f16* hencB = (f16*)(ws + off); off += (size_t)T_STEPS*NAG*128*2;    // 31.5 MB

    k_cond<<<dim3(NAG/8,2), 256, 0, stream>>>(cond, cw1,cb1,cw2,cb2, cbw1,cbb1,cbw2,cbb2, probe, disp);
    k_emb<<<3840, 256, 0, stream>>>(z, iw1,ib1,iw2,ib2, probe, semb);
    k_gru_mfma<<<dim3(NAG/32,2), 384, 0, stream>>>(semb, disp, wih,whh,bih,bhh, wihb,whhb,bihb,bhhb, probe, hencF, hencB);
    k_post<<<3840, 256, 0, stream>>>(hencF, hencB, sw,sb, mw,mb, ow1,ob1,ow2,ob2, probe, d_out);
}

// Round 22
// 477.617 us; speedup vs baseline: 1.1220x; 1.0077x over previous
//
#include <hip/hip_runtime.h>
#include <hip/hip_bf16.h>

typedef unsigned int u32;
typedef unsigned short u16;
typedef _Float16 f16;
typedef float f32x2 __attribute__((ext_vector_type(2)));
typedef _Float16 f16x2 __attribute__((ext_vector_type(2)));
typedef u32 u32x4 __attribute__((ext_vector_type(4)));
typedef u32 u32x2v __attribute__((ext_vector_type(2)));
typedef _Float16 f16x8 __attribute__((ext_vector_type(8)));
typedef float f32x4v __attribute__((ext_vector_type(4)));

#define LN_EPS 1e-5f
#define T_STEPS 30
#define NAG 4096

__device__ __forceinline__ float bf2f(u16 v){
    union { u32 u; float f; } c; c.u = ((u32)v) << 16; return c.f;
}
__device__ __forceinline__ u16 f2bf(float f){
    union { float f; u32 u; } c; c.f = f;
    return (u16)((c.u + 0x7FFFu + ((c.u >> 16) & 1u)) >> 16);
}
__device__ __forceinline__ u32 pk_h2(float a, float b){
    f16x2 h; h[0] = (f16)a; h[1] = (f16)b;
    return __builtin_bit_cast(u32, h);
}
__device__ __forceinline__ f32x2 unpk_h2(u32 p){
    f16x2 h = __builtin_bit_cast(f16x2, p);
    f32x2 r; r[0] = (float)h[0]; r[1] = (float)h[1]; return r;
}
__device__ __forceinline__ u32 bfp2h2(u32 p){
    union { u32 u; float f; } a, b;
    a.u = p << 16; b.u = p & 0xFFFF0000u;
    return pk_h2(a.f, b.f);
}
__device__ __forceinline__ float fdot2u(u32 a, u32 b, float c){
    return __builtin_amdgcn_fdot2(__builtin_bit_cast(f16x2, a),
                                  __builtin_bit_cast(f16x2, b), c, false);
}
// dtype probe: fp32 buffers read as u16 have random mantissa halves at even
// positions (~50% decode to |x|>=128); bf16 weight buffers (|w| < 1) never do.
__device__ __forceinline__ int detect_f32(const void* probe){
    const u16* p = (const u16*)probe;
    int bad = 0;
    #pragma unroll
    for (int i = 0; i < 32; i++){
        u32 e = (p[2*i] >> 7) & 0xFF;
        bad += (e >= 0x86) ? 1 : 0;
    }
    return bad > 4;
}
__device__ __forceinline__ float ldin(const void* p, int i, int F){
    float v;
    if (F) v = ((const float*)p)[i];
    else   v = bf2f(((const u16*)p)[i]);
    return v;
}
__device__ __forceinline__ u32 ld_pair(const void* p, int pairIdx, int F){
    if (F){ const float* f = (const float*)p; return pk_h2(f[2*pairIdx], f[2*pairIdx+1]); }
    return bfp2h2(((const u32*)p)[pairIdx]);
}
__device__ __forceinline__ void wred64(float& s, float& q){
    #pragma unroll
    for (int m = 1; m < 64; m <<= 1){ s += __shfl_xor(s, m); q += __shfl_xor(q, m); }
}
__device__ __forceinline__ void wred32(float& s, float& q){
    #pragma unroll
    for (int m = 1; m < 32; m <<= 1){ s += __shfl_xor(s, m); q += __shfl_xor(q, m); }
}
__device__ __forceinline__ float lrelu(float x){ return fmaxf(x, 0.1f * x); }
__device__ __forceinline__ float sigm(float x){ return 1.0f / (1.0f + __expf(-x)); }
__device__ __forceinline__ float ftanh(float x){ return 1.0f - 2.0f / (1.0f + __expf(2.0f * x)); }
__device__ __forceinline__ void ln128(float a0, float a1, float& o0, float& o1){
    float s = a0 + a1, q = a0*a0 + a1*a1;
    wred64(s, q);
    float m = s * (1.f/128.f), v = q * (1.f/128.f) - m*m;
    float rs = rsqrtf(fmaxf(v, 0.f) + LN_EPS);
    o0 = (a0 - m) * rs; o1 = (a1 - m) * rs;
}

// ---------------- K1: cond embeddings (both dirs): [N,2] -> 64 -> 128 ----------------
// 256 thr / 8 agents per block; w2 staged TRANSPOSED in LDS (coalesced global
// reads; +2-pad stride 130, reads conflict-free). One barrier total.
__global__ __launch_bounds__(256) void k_cond(
    const void* __restrict__ cond,
    const void* __restrict__ w1a, const void* __restrict__ b1a,
    const void* __restrict__ w2a, const void* __restrict__ b2a,
    const void* __restrict__ w1b, const void* __restrict__ b1b,
    const void* __restrict__ w2b, const void* __restrict__ b2b,
    const void* __restrict__ probe,
    f16* __restrict__ disp)
{
    __shared__ float w2T[64*130];     // [k][u], padded stride 130 (33.3 KB)
    __shared__ float w1s[128], b1s[64], b2s[128];
    __shared__ float x1s[4][64];      // layer-1 outs, per wave
    int F = detect_f32(probe);
    int tid = threadIdx.x, dir = blockIdx.y;
    const void* w1 = dir ? w1b : w1a; const void* b1 = dir ? b1b : b1a;
    const void* w2 = dir ? w2b : w2a; const void* b2 = dir ? b2b : b2a;
    // stage w2 transposed: global idx i = u*64 + k, k fastest -> coalesced reads
    for (int i = tid; i < 8192; i += 256){
        int u = i >> 6, k = i & 63;
        w2T[k*130 + u] = ldin(w2, i, F);
    }
    if (tid < 128) w1s[tid] = ldin(w1, tid, F);
    else           b2s[tid - 128] = ldin(b2, tid - 128, F);
    if (tid < 64)  b1s[tid] = ldin(b1, tid, F);
    __syncthreads();

    int w = tid >> 6, lane = tid & 63;
    int nb = blockIdx.x * 8 + w * 2;
    #pragma unroll
    for (int a = 0; a < 2; a++){
        int n = nb + a;
        float c0 = ldin(cond, n*2, F), c1 = ldin(cond, n*2+1, F);
        float y = w1s[lane*2] * c0 + w1s[lane*2+1] * c1 + b1s[lane];
        float s = y, q = y*y; wred64(s, q);
        float m = s * (1.f/64.f), v = q * (1.f/64.f) - m*m;
        float rs = rsqrtf(fmaxf(v, 0.f) + LN_EPS);
        x1s[w][lane] = lrelu((y - m) * rs);   // per-wave buffer, no barrier needed
        float y0 = b2s[lane], y1 = b2s[lane + 64];
        #pragma unroll 8
        for (int k = 0; k < 64; k++){
            float xv = x1s[w][k];
            y0 = fmaf(xv, w2T[k*130 + lane], y0);
            y1 = fmaf(xv, w2T[k*130 + 64 + lane], y1);
        }
        float o0, o1; ln128(y0, y1, o0, o1);
        f16* dp = disp + ((size_t)dir * NAG + n) * 128;
        dp[lane] = (f16)lrelu(o0);
        dp[lane+64] = (f16)lrelu(o1);
    }
}

// ---------------- K2: scene embedding: z[T,N,128] -> 32 -> 64 (packed fdot2) ----------
// Layer-2 LN batched via the 8-lane-group transform (R19, measured 485->481).
__global__ __launch_bounds__(256) void k_emb(
    const void* __restrict__ z,
    const void* __restrict__ iw1, const void* __restrict__ ib1,
    const void* __restrict__ iw2, const void* __restrict__ ib2,
    const void* __restrict__ probe,
    f16* __restrict__ semb)
{
    __shared__ u32 w1p[64*32];      // [kp<64][e<32]
    __shared__ u32 w2p[16*64];      // [kp<16][e<64]
    __shared__ u32 zp[4][2][64];    // z rows packed, 2 rows per wave pass
    __shared__ u32 x1p[4][8][16];   // layer-1 outs packed, all 8 rows
    __shared__ __align__(16) float y2T[4][512];  // layer-2 transpose scratch
    int F = detect_f32(probe);
    int tid = threadIdx.x;
    for (int i = tid; i < 2048; i += 256){
        int kp = i >> 5, e = i & 31;
        w1p[kp*32+e] = ld_pair(iw1, e*64 + kp, F);      // iw1 [32][128]
    }
    for (int i = tid; i < 1024; i += 256){
        int kp = i >> 6, e = i & 63;
        w2p[kp*64+e] = ld_pair(iw2, e*16 + kp, F);      // iw2 [64][32]
    }
    __syncthreads();
    int w = tid >> 6, lane = tid & 63;
    int rp = lane >> 5, ll = lane & 31;
    float b1v = ldin(ib1, ll, F);
    float b2v = ldin(ib2, lane, F);
    int rowbase = (blockIdx.x * 4 + w) * 8;
    // ---- layer 1: 4 passes x 2 rows; outs -> x1p[w][row][kp] ----
    #pragma unroll 1
    for (int pass = 0; pass < 4; pass++){
        int row = rowbase + pass*2 + rp;                // half-wave rp owns this row
        zp[w][rp][ll]    = ld_pair(z, row*64 + ll, F);
        zp[w][rp][ll+32] = ld_pair(z, row*64 + ll + 32, F);
        float y1 = b1v;
        #pragma unroll 8
        for (int kp = 0; kp < 64; kp++)
            y1 = fdot2u(zp[w][rp][kp], w1p[kp*32+ll], y1);
        float s = y1, q = y1*y1; wred32(s, q);
        float m = s*(1.f/32.f), v = q*(1.f/32.f)-m*m, rs = rsqrtf(fmaxf(v,0.f)+LN_EPS);
        float sv = lrelu((y1-m)*rs);
        float e0 = __shfl(sv, (lane & 32) + 2*(lane & 15));
        float e1 = __shfl(sv, (lane & 32) + 2*(lane & 15) + 1);
        if (ll < 16) x1p[w][pass*2+rp][ll] = pk_h2(e0, e1);
    }
    // ---- layer 2 batched: lane owns unit `lane` for all 8 rows ----
    float y2a[8];
    #pragma unroll
    for (int r = 0; r < 8; r++) y2a[r] = b2v;
    #pragma unroll
    for (int kp = 0; kp < 16; kp++){
        u32 wv = w2p[kp*64 + lane];
        #pragma unroll
        for (int r = 0; r < 8; r++)
            y2a[r] = fdot2u(x1p[w][r][kp], wv, y2a[r]);
    }
    // transpose (rotate-swizzle) -> 8-lane-group LN, all 8 rows in one reduce
    #pragma unroll
    for (int r = 0; r < 8; r++)
        y2T[w][r*64 + ((lane + r*8) & 63)] = y2a[r];
    {
        int g = lane >> 3, l8 = (lane & 7) * 8;
        const f32x4v* yp = (const f32x4v*)&y2T[w][g*64 + ((l8 + g*8) & 63)];
        f32x4v ya = yp[0], yb = yp[1];
        float s = 0.f, q = 0.f;
        #pragma unroll
        for (int d = 0; d < 4; d++){
            s += ya[d] + yb[d];
            q += ya[d]*ya[d] + yb[d]*yb[d];
        }
        #pragma unroll
        for (int m = 1; m < 8; m <<= 1){ s += __shfl_xor(s, m); q += __shfl_xor(q, m); }
        float mm = s*(1.f/64.f), vv = q*(1.f/64.f) - mm*mm;
        float rs = rsqrtf(fmaxf(vv, 0.f) + LN_EPS);
        u32x4 sv;
        sv[0] = pk_h2(lrelu((ya[0]-mm)*rs), lrelu((ya[1]-mm)*rs));
        sv[1] = pk_h2(lrelu((ya[2]-mm)*rs), lrelu((ya[3]-mm)*rs));
        sv[2] = pk_h2(lrelu((yb[0]-mm)*rs), lrelu((yb[1]-mm)*rs));
        sv[3] = pk_h2(lrelu((yb[2]-mm)*rs), lrelu((yb[3]-mm)*rs));
        *(u32x4*)(semb + (size_t)(rowbase + g)*64 + l8) = sv;   // 128B/row, coalesced
    }
}

// ---------------- K3: MFMA bidirectional LN-GRU ----------------
// R3/R7 winner verbatim (measured 168-170 us; revert confirmed R15). Falsified:
// R6 2-block split (195), R9 12-wave dir-fusion (197), R12 LBAR surgery (187).
// Step cost is intra-phase dependent chains; leave as-is.
__global__ __launch_bounds__(384) void k_gru_mfma(
    const f16* __restrict__ semb, const f16* __restrict__ disp,
    const void* __restrict__ wihA, const void* __restrict__ whhA,
    const void* __restrict__ bihA, const void* __restrict__ bhhA,
    const void* __restrict__ wihB, const void* __restrict__ whhB,
    const void* __restrict__ bihB, const void* __restrict__ bhhB,
    const void* __restrict__ probe,
    f16* __restrict__ hencF, f16* __restrict__ hencB)
{
    __shared__ __align__(16) f16 hbuf[32][136];      // h per agent (pad 8 f16)
    __shared__ __align__(16) f16 xbuf[2][32][72];    // x per agent, double-buffered
    __shared__ __align__(16) f16 rzbuf[2][32][136];  // r,z values [gate][agent][d]
    __shared__ __align__(16) float bias1[384];       // u<256: bih+bhh; u>=256: bih
    __shared__ __align__(16) float bias2[128];       // bhh for n-units
    __shared__ float redS[6][32], redQ[6][32];
    int F = detect_f32(probe);
    int tid = threadIdx.x, dir = blockIdx.y;
    int w = tid >> 6, lane = tid & 63;
    int quad = lane >> 4, l15 = lane & 15;
    int gate = w >> 1;
    const void* wih = dir ? wihB : wihA;  const void* whh = dir ? whhB : whhA;
    const void* bih = dir ? bihB : bihA;  const void* bhh = dir ? bhhB : bhhA;
    f16* henc = dir ? hencB : hencF;

    // ---- A fragments: Af[mt][kt]; lane supplies A[m=l15][k=quad*8+j] ----
    f16x8 Af[4][6];
    if (F){
        #pragma unroll
        for (int mt = 0; mt < 4; mt++){
            int u = (w*4+mt)*16 + l15;
            #pragma unroll
            for (int kt = 0; kt < 6; kt++){
                const float* src = (kt < 4)
                    ? ((const float*)whh + (size_t)u*128 + kt*32 + quad*8)
                    : ((const float*)wih + (size_t)u*64 + (kt-4)*32 + quad*8);
                f16x8 v;
                #pragma unroll
                for (int j = 0; j < 8; j++) v[j] = (f16)src[j];
                Af[mt][kt] = v;
            }
        }
    } else {
        #pragma unroll
        for (int mt = 0; mt < 4; mt++){
            int u = (w*4+mt)*16 + l15;
            #pragma unroll
            for (int kt = 0; kt < 6; kt++){
                const u16* src = (kt < 4)
                    ? ((const u16*)whh + (size_t)u*128 + kt*32 + quad*8)
                    : ((const u16*)wih + (size_t)u*64 + (kt-4)*32 + quad*8);
                f16x8 v;
                #pragma unroll
                for (int j = 0; j < 8; j++) v[j] = (f16)bf2f(src[j]);
                Af[mt][kt] = v;
            }
        }
    }
    // biases -> LDS (keeps VGPR pressure down; C-frags init from these per step)
    if (tid < 384){
        float bi = ldin(bih, tid, F), bh = ldin(bhh, tid, F);
        bias1[tid] = (tid < 256) ? (bi + bh) : bi;
        if (tid >= 256) bias2[tid - 256] = bh;
    }

    int nb = blockIdx.x * 32;
    // stage h0 (from disp) and x(t0)
    for (int i = tid; i < 512; i += 384){
        int a = i >> 4, c = i & 15;
        u32x4 v = *(const u32x4*)(disp + ((size_t)dir*NAG + nb + a)*128 + c*8);
        *(u32x4*)&hbuf[a][c*8] = v;
    }
    int tx0 = dir ? (T_STEPS-1) : 0;
    for (int i = tid; i < 256; i += 384){
        int a = i >> 3, c = i & 7;
        u32x4 v = *(const u32x4*)(semb + ((size_t)tx0*NAG + nb + a)*64 + c*8);
        *(u32x4*)&xbuf[0][a][c*8] = v;
    }
    __syncthreads();

    #pragma unroll 1
    for (int t = 0; t < T_STEPS; t++){
        int tx = dir ? (T_STEPS-1-t) : t;
        int cur = t & 1;
        // ---- C init from biases ----
        f32x4v C0[4][2], C1[4][2];
        #pragma unroll
        for (int mt = 0; mt < 4; mt++){
            f32x4v b1f = *(const f32x4v*)&bias1[(w*4+mt)*16 + quad*4];
            if (gate < 2){
                C0[mt][0] = b1f; C0[mt][1] = b1f;          // combined bias
                C1[mt][0] = b1f; C1[mt][1] = b1f;          // unused on this path
            } else {
                f32x4v b2f = *(const f32x4v*)&bias2[((w&1)*4+mt)*16 + quad*4];
                C0[mt][0] = b2f; C0[mt][1] = b2f;          // hh + bhh
                C1[mt][0] = b1f; C1[mt][1] = b1f;          // ih + bih
            }
        }
        // ---- MFMA phase ----
        #pragma unroll
        for (int nt = 0; nt < 2; nt++){
            int ag = nt*16 + l15;
            f16x8 B0 = *(const f16x8*)&hbuf[ag][0*32 + quad*8];
            f16x8 B1 = *(const f16x8*)&hbuf[ag][1*32 + quad*8];
            f16x8 B2 = *(const f16x8*)&hbuf[ag][2*32 + quad*8];
            f16x8 B3 = *(const f16x8*)&hbuf[ag][3*32 + quad*8];
            f16x8 B4 = *(const f16x8*)&xbuf[cur][ag][0*32 + quad*8];
            f16x8 B5 = *(const f16x8*)&xbuf[cur][ag][1*32 + quad*8];
            if (gate < 2){
                #pragma unroll
                for (int mt = 0; mt < 4; mt++){
                    f32x4v c = C0[mt][nt];
                    c = __builtin_amdgcn_mfma_f32_16x16x32_f16(Af[mt][0], B0, c, 0, 0, 0);
                    c = __builtin_amdgcn_mfma_f32_16x16x32_f16(Af[mt][1], B1, c, 0, 0, 0);
                    c = __builtin_amdgcn_mfma_f32_16x16x32_f16(Af[mt][2], B2, c, 0, 0, 0);
                    c = __builtin_amdgcn_mfma_f32_16x16x32_f16(Af[mt][3], B3, c, 0, 0, 0);
                    c = __builtin_amdgcn_mfma_f32_16x16x32_f16(Af[mt][4], B4, c, 0, 0, 0);
                    c = __builtin_amdgcn_mfma_f32_16x16x32_f16(Af[mt][5], B5, c, 0, 0, 0);
                    C0[mt][nt] = c;
                }
            } else {
                #pragma unroll
                for (int mt = 0; mt < 4; mt++){
                    f32x4v c = C0[mt][nt];
                    c = __builtin_amdgcn_mfma_f32_16x16x32_f16(Af[mt][0], B0, c, 0, 0, 0);
                    c = __builtin_amdgcn_mfma_f32_16x16x32_f16(Af[mt][1], B1, c, 0, 0, 0);
                    c = __builtin_amdgcn_mfma_f32_16x16x32_f16(Af[mt][2], B2, c, 0, 0, 0);
                    c = __builtin_amdgcn_mfma_f32_16x16x32_f16(Af[mt][3], B3, c, 0, 0, 0);
                    C0[mt][nt] = c;
                    f32x4v d = C1[mt][nt];
                    d = __builtin_amdgcn_mfma_f32_16x16x32_f16(Af[mt][4], B4, d, 0, 0, 0);
                    d = __builtin_amdgcn_mfma_f32_16x16x32_f16(Af[mt][5], B5, d, 0, 0, 0);
                    C1[mt][nt] = d;
                }
            }
        }
        // ---- phase1 tail: r/z LN partials; n-waves stage next x ----
        if (gate < 2){
            #pragma unroll
            for (int nt = 0; nt < 2; nt++){
                float s = 0.f, q = 0.f;
                #pragma unroll
                for (int mt = 0; mt < 4; mt++)
                    #pragma unroll
                    for (int r = 0; r < 4; r++){
                        float v = C0[mt][nt][r];
                        s += v; q += v*v;
                    }
                s += __shfl_xor(s, 16); q += __shfl_xor(q, 16);
                s += __shfl_xor(s, 32); q += __shfl_xor(q, 32);
                if (lane < 16){ redS[w][nt*16 + l15] = s; redQ[w][nt*16 + l15] = q; }
            }
        } else {
            if (t + 1 < T_STEPS){
                int txn = dir ? (T_STEPS-2-t) : (t+1);
                int i0 = (w-4)*64 + lane;                  // [0,128)
                #pragma unroll
                for (int rep = 0; rep < 2; rep++){
                    int i = i0 + rep*128;
                    int a = i >> 3, c = i & 7;
                    u32x4 v = *(const u32x4*)(semb + ((size_t)txn*NAG + nb + a)*64 + c*8);
                    *(u32x4*)&xbuf[cur^1][a][c*8] = v;
                }
            }
        }
        __syncthreads();                                   // bar1
        // ---- phase2: r/z finalize LN + sigmoid -> rzbuf ----
        if (gate < 2){
            #pragma unroll
            for (int nt = 0; nt < 2; nt++){
                int ag = nt*16 + l15;
                float s = redS[w][ag] + redS[w^1][ag];
                float q = redQ[w][ag] + redQ[w^1][ag];
                float m = s*(1.f/128.f), vv = q*(1.f/128.f) - m*m;
                float rs = rsqrtf(fmaxf(vv, 0.f) + LN_EPS);
                #pragma unroll
                for (int mt = 0; mt < 4; mt++){
                    float g0 = sigm((C0[mt][nt][0] - m)*rs);
                    float g1 = sigm((C0[mt][nt][1] - m)*rs);
                    float g2 = sigm((C0[mt][nt][2] - m)*rs);
                    float g3 = sigm((C0[mt][nt][3] - m)*rs);
                    int dg = ((w&1)*4 + mt)*16 + quad*4;
                    u32x2v p; p.x = pk_h2(g0, g1); p.y = pk_h2(g2, g3);
                    *(u32x2v*)&rzbuf[gate][ag][dg] = p;
                }
            }
        }
        __syncthreads();                                   // bar2
        // ---- phase3: n-pre = ih + r * hh ; LN partials ----
        if (gate == 2){
            #pragma unroll
            for (int nt = 0; nt < 2; nt++){
                int ag = nt*16 + l15;
                float s = 0.f, q = 0.f;
                #pragma unroll
                for (int mt = 0; mt < 4; mt++){
                    int dg = ((w&1)*4 + mt)*16 + quad*4;
                    u32x2v rp = *(const u32x2v*)&rzbuf[0][ag][dg];
                    f32x2 ra = unpk_h2(rp.x), rb = unpk_h2(rp.y);
                    float p0 = C1[mt][nt][0] + ra[0]*C0[mt][nt][0];
                    float p1 = C1[mt][nt][1] + ra[1]*C0[mt][nt][1];
                    float p2 = C1[mt][nt][2] + rb[0]*C0[mt][nt][2];
                    float p3 = C1[mt][nt][3] + rb[1]*C0[mt][nt][3];
                    C0[mt][nt][0] = p0; C0[mt][nt][1] = p1;
                    C0[mt][nt][2] = p2; C0[mt][nt][3] = p3;
                    s += p0 + p1 + p2 + p3;
                    q += p0*p0 + p1*p1 + p2*p2 + p3*p3;
                }
                s += __shfl_xor(s, 16); q += __shfl_xor(q, 16);
                s += __shfl_xor(s, 32); q += __shfl_xor(q, 32);
                if (lane < 16){ redS[w][ag] = s; redQ[w][ag] = q; }
            }
        }
        __syncthreads();                                   // bar3
        // ---- phase4: n finalize, h update, write back ----
        if (gate == 2){
            #pragma unroll
            for (int nt = 0; nt < 2; nt++){
                int ag = nt*16 + l15;
                float s = redS[4][ag] + redS[5][ag];
                float q = redQ[4][ag] + redQ[5][ag];
                float m = s*(1.f/128.f), vv = q*(1.f/128.f) - m*m;
                float rs = rsqrtf(fmaxf(vv, 0.f) + LN_EPS);
                #pragma unroll
                for (int mt = 0; mt < 4; mt++){
                    int dg = ((w&1)*4 + mt)*16 + quad*4;
                    float n0 = ftanh((C0[mt][nt][0] - m)*rs);
                    float n1 = ftanh((C0[mt][nt][1] - m)*rs);
                    float n2 = ftanh((C0[mt][nt][2] - m)*rs);
                    float n3 = ftanh((C0[mt][nt][3] - m)*rs);
                    u32x2v zp = *(const u32x2v*)&rzbuf[1][ag][dg];
                    f32x2 za = unpk_h2(zp.x), zb = unpk_h2(zp.y);
                    u32x2v hp = *(const u32x2v*)&hbuf[ag][dg];
                    f32x2 ha = unpk_h2(hp.x), hb2 = unpk_h2(hp.y);
                    float h0 = (1.f - za[0])*n0 + za[0]*ha[0];
                    float h1 = (1.f - za[1])*n1 + za[1]*ha[1];
                    float h2 = (1.f - zb[0])*n2 + zb[0]*hb2[0];
                    float h3 = (1.f - zb[1])*n3 + zb[1]*hb2[1];
                    u32x2v o; o.x = pk_h2(h0, h1); o.y = pk_h2(h2, h3);
                    *(u32x2v*)&hbuf[ag][dg] = o;
                    *(u32x2v*)(henc + ((size_t)tx*NAG + nb + ag)*128 + dg) = o;
                }
            }
        }
        __syncthreads();                                   // bar4
    }
}

// ---------------- K4: fused post-GRU: seq -> pairwise(factored) -> out head ----------------
// Serial-LN phases all use the 8-lane-group transform (R0/R12/R15, 4-for-4 with
// R19). This round: VECTORIZE the broadcast LDS reads in the three dot-product
// loops. y-loop was 64x(8 scalar xr bcasts + 1 swp) = 576 b32 reads; now tiled
// over 4-kp blocks with b128 row fetches: 128 b128 + 64 b32 (~3.3 -> 1.9 kcy).
// Same for uu (288 -> 96) and head (128 -> 80). fdot2 order unchanged ->
// bit-identical numerics.
__global__ __launch_bounds__(256) void k_post(
    const f16* __restrict__ hf, const f16* __restrict__ hb,
    const void* __restrict__ sw, const void* __restrict__ sb,
    const void* __restrict__ mw, const void* __restrict__ mb,
    const void* __restrict__ ow1, const void* __restrict__ ob1,
    const void* __restrict__ ow2, const void* __restrict__ ob2,
    const void* __restrict__ probe,
    void* __restrict__ outp)
{
    __shared__ u32 swp[64*64];     // [kp][unit]
    __shared__ u32 mwp[32*64];     // [kp][unit]
    __shared__ u32 w1p[64*32];     // [kp][e<32]
    __shared__ __align__(16) u32 xr[4][8][64];   // x pairs; later yT / uuT alias
    __shared__ __align__(16) u32 fr[4][8][68];   // full=[seq|ave] pairs, stride 68
    int F = detect_f32(probe);
    int tid = threadIdx.x;
    for (int i = tid; i < 4096; i += 256){
        int u = i & 63, kp = i >> 6;
        swp[kp*64+u] = ld_pair(sw, u*64 + kp, F);      // sw [64][128]
    }
    for (int i = tid; i < 2048; i += 256){
        int u = i & 63, kp = i >> 6;   // kp < 32
        mwp[kp*64+u] = ld_pair(mw, u*32 + kp, F);      // mw [64][64]
    }
    for (int i = tid; i < 2048; i += 256){
        int e = i & 31, kp = i >> 5;   // kp < 64
        w1p[kp*32+e] = ld_pair(ow1, e*64 + kp, F);     // ow1 [32][128]
    }
    int w = tid >> 6, lane = tid & 63;
    int unit = blockIdx.x*4 + w;        // t*512 + scene
    int t = unit >> 9, sc = unit & 511;
    int base = sc * 8;
    size_t rowbase = (size_t)t*NAG + base;
    const u32* hfu = (const u32*)hf;
    const u32* hbu = (const u32*)hb;
    #pragma unroll
    for (int r = 0; r < 8; r++){
        f32x2 a = unpk_h2(hfu[(rowbase + r)*64 + lane]);
        f32x2 b = unpk_h2(hbu[(rowbase + r)*64 + lane]);
        xr[w][r][lane] = pk_h2(0.5f*(a[0]+b[0]), 0.5f*(a[1]+b[1]));
    }
    __syncthreads();

    float bs = ldin(sb, lane, F);
    float y[8];
    #pragma unroll
    for (int r = 0; r < 8; r++) y[r] = bs;
    // vectorized: 4 kp per iter, xr rows fetched as b128 broadcasts
    for (int kb = 0; kb < 16; kb++){
        u32x4 xv[8];
        #pragma unroll
        for (int r = 0; r < 8; r++) xv[r] = *(const u32x4*)&xr[w][r][kb*4];
        #pragma unroll
        for (int j = 0; j < 4; j++){
            u32 wv = swp[(kb*4+j)*64 + lane];
            #pragma unroll
            for (int r = 0; r < 8; r++) y[r] = fdot2u(xv[r][j], wv, y[r]);
        }
    }
    // ---- seq-LN transposed: group g owns row g; lane l=lane&7 owns outs 8l..8l+7.
    // xr[w] is dead after the y-loop; reuse as yT scratch (rotate-swizzle). ----
    float* yT = (float*)&xr[w][0][0];
    #pragma unroll
    for (int r = 0; r < 8; r++)
        yT[r*64 + ((lane + r*8) & 63)] = y[r];
    {
        int g = lane >> 3, l8 = (lane & 7) * 8;
        const f32x4v* yp = (const f32x4v*)&yT[g*64 + ((l8 + g*8) & 63)];
        f32x4v ya = yp[0], yb = yp[1];
        float s = 0.f, q = 0.f;
        #pragma unroll
        for (int d = 0; d < 4; d++){
            s += ya[d] + yb[d];
            q += ya[d]*ya[d] + yb[d]*yb[d];
        }
        #pragma unroll
        for (int m = 1; m < 8; m <<= 1){ s += __shfl_xor(s, m); q += __shfl_xor(q, m); }
        float mm = s*(1.f/64.f), vv = q*(1.f/64.f) - mm*mm;
        float rs = rsqrtf(fmaxf(vv, 0.f) + LN_EPS);
        u32x4 sv;
        sv[0] = pk_h2(lrelu((ya[0]-mm)*rs), lrelu((ya[1]-mm)*rs));
        sv[1] = pk_h2(lrelu((ya[2]-mm)*rs), lrelu((ya[3]-mm)*rs));
        sv[2] = pk_h2(lrelu((yb[0]-mm)*rs), lrelu((yb[1]-mm)*rs));
        sv[3] = pk_h2(lrelu((yb[2]-mm)*rs), lrelu((yb[3]-mm)*rs));
        *(u32x4*)&fr[w][g][(lane & 7)*4] = sv;      // seq pairs 4l..4l+3 of row g
    }
    // ---- uu = seq @ mw.T (no bias); unit = lane; vectorized fr fetches ----
    float uu[8];
    #pragma unroll
    for (int r = 0; r < 8; r++) uu[r] = 0.f;
    for (int kb = 0; kb < 8; kb++){
        u32x4 fv[8];
        #pragma unroll
        for (int r = 0; r < 8; r++) fv[r] = *(const u32x4*)&fr[w][r][kb*4];
        #pragma unroll
        for (int j = 0; j < 4; j++){
            u32 wv = mwp[(kb*4+j)*64 + lane];
            #pragma unroll
            for (int r = 0; r < 8; r++) uu[r] = fdot2u(fv[r][j], wv, uu[r]);
        }
    }
    // ---- transpose uu -> uuT (aliases xr[w], dead again after yT use) ----
    // row r dim d stored at pos (d + 8r) & 63 (rotate-swizzle, bank-friendly)
    float* uuT = (float*)&xr[w][0][0];
    #pragma unroll
    for (int r = 0; r < 8; r++)
        uuT[r*64 + ((lane + r*8) & 63)] = uu[r];
    // ---- pairwise: group g owns agent i=g; lane l=lane&7 owns dims 8l..8l+7 ----
    int g = lane >> 3, l8 = (lane & 7) * 8;
    float bmv[8];
    #pragma unroll
    for (int d = 0; d < 8; d++) bmv[d] = ldin(mb, l8 + d, F);
    const f32x4v* up = (const f32x4v*)&uuT[g*64 + ((l8 + g*8) & 63)];
    f32x4v ui0 = up[0], ui1 = up[1];
    float acc[8];
    #pragma unroll
    for (int d = 0; d < 8; d++) acc[d] = 0.f;
    #pragma unroll
    for (int rr = 0; rr < 7; rr++){
        int j = (g + 1 + rr) & 7;
        const f32x4v* jp = (const f32x4v*)&uuT[j*64 + ((l8 + j*8) & 63)];
        f32x4v uj0 = jp[0], uj1 = jp[1];
        float p[8]; float s = 0.f, q = 0.f;
        #pragma unroll
        for (int d = 0; d < 4; d++){
            float v0 = ui0[d] - uj0[d] + bmv[d];
            float v1 = ui1[d] - uj1[d] + bmv[4+d];
            p[d] = v0; p[4+d] = v1;
            s += v0 + v1; q += v0*v0 + v1*v1;
        }
        #pragma unroll
        for (int m = 1; m < 8; m <<= 1){ s += __shfl_xor(s, m); q += __shfl_xor(q, m); }
        float mm = s*(1.f/64.f), vv = q*(1.f/64.f) - mm*mm;
        float rs = rsqrtf(fmaxf(vv, 0.f) + LN_EPS);
        #pragma unroll
        for (int d = 0; d < 8; d++) acc[d] += lrelu((p[d] - mm)*rs);
    }
    // ave -> fr[w][g][32 + l*4 ..], pairs of dims (8l+2k, 8l+2k+1)
    u32x4 av;
    #pragma unroll
    for (int k = 0; k < 4; k++) av[k] = pk_h2(acc[2*k]*(1.f/7.f), acc[2*k+1]*(1.f/7.f));
    *(u32x4*)&fr[w][g][32 + (lane & 7)*4] = av;
    __builtin_amdgcn_s_barrier();   // fr rows complete before head reads
    // ---- head: group g owns row g; lane l owns h-dims 4l..4l+3; fr fetched
    // as b128 (4 kp per iter), w1p as b128 -> 16+64 b128 reads total. ----
    {
        int l4 = (lane & 7) * 4;
        float hb1[4], ho20[4], ho21[4];
        #pragma unroll
        for (int d = 0; d < 4; d++){
            hb1[d]  = ldin(ob1, l4 + d, F);
            ho20[d] = ldin(ow2, l4 + d, F);
            ho21[d] = ldin(ow2, 32 + l4 + d, F);
        }
        float h[4];
        #pragma unroll
        for (int d = 0; d < 4; d++) h[d] = hb1[d];
        for (int kb = 0; kb < 16; kb++){
            u32x4 fv = *(const u32x4*)&fr[w][g][kb*4];
            #pragma unroll
            for (int j = 0; j < 4; j++){
                u32x4 wv4 = *(const u32x4*)&w1p[(kb*4+j)*32 + l4];
                #pragma unroll
                for (int d = 0; d < 4; d++) h[d] = fdot2u(fv[j], wv4[d], h[d]);
            }
        }
        float s = 0.f, q = 0.f;
        #pragma unroll
        for (int d = 0; d < 4; d++){ s += h[d]; q += h[d]*h[d]; }
        #pragma unroll
        for (int m = 1; m < 8; m <<= 1){ s += __shfl_xor(s, m); q += __shfl_xor(q, m); }
        float mm = s*(1.f/32.f), vv = q*(1.f/32.f) - mm*mm;
        float rs = rsqrtf(fmaxf(vv, 0.f) + LN_EPS);
        float p0 = 0.f, p1 = 0.f;
        #pragma unroll
        for (int d = 0; d < 4; d++){
            float hv = lrelu((h[d] - mm)*rs);
            p0 = fmaf(hv, ho20[d], p0);
            p1 = fmaf(hv, ho21[d], p1);
        }
        #pragma unroll
        for (int m = 1; m < 8; m <<= 1){ p0 += __shfl_xor(p0, m); p1 += __shfl_xor(p1, m); }
        if ((lane & 7) == 0){
            float bo0 = ldin(ob2, 0, F), bo1 = ldin(ob2, 1, F);
            int n = base + g;
            float v0 = ftanh(p0 + bo0), v1 = ftanh(p1 + bo1);
            size_t i0 = (size_t)(n*2)*T_STEPS + t, i1 = (size_t)(n*2+1)*T_STEPS + t;
            if (F){ ((float*)outp)[i0] = v0; ((float*)outp)[i1] = v1; }
            else  { ((u16*)outp)[i0] = f2bf(v0); ((u16*)outp)[i1] = f2bf(v1); }
        }
    }
}

extern "C" void kernel_launch(void* const* d_in, const int* in_sizes, int n_in,
                              void* d_out, int out_size, void* d_ws, size_t ws_size,
                              hipStream_t stream)
{
    const void* cond = d_in[0];
    const void* z    = d_in[1];
    const void* cw1  = d_in[2];
    const void* cb1  = d_in[3];
    const void* cw2  = d_in[4];
    const void* cb2  = d_in[5];
    const void* cbw1 = d_in[6];
    const void* cbb1 = d_in[7];
    const void* cbw2 = d_in[8];
    const void* cbb2 = d_in[9];
    const void* iw1  = d_in[10];
    const void* ib1  = d_in[11];
    const void* iw2  = d_in[12];
    const void* ib2  = d_in[13];
    const void* wih  = d_in[14];
    const void* whh  = d_in[15];
    const void* bih  = d_in[16];
    const void* bhh  = d_in[17];
    const void* wihb = d_in[18];
    const void* whhb = d_in[19];
    const void* bihb = d_in[20];
    const void* bhhb = d_in[21];
    const void* sw   = d_in[22];
    const void* sb   = d_in[23];
    const void* mw   = d_in[24];
    const void* mb   = d_in[25];
    const void* ow1  = d_in[26];
    const void* ob1  = d_in[27];
    const void* ow2  = d_in[28];
    const void* ob2  = d_in[29];
    const void* probe = whh;   // dtype-detection probe buffer

    char* ws = (char*)d_ws;
    size_t off = 0;
    f16* disp  = (f16*)(ws + off); off += (size_t)2*NAG*128*2;          //  2 MB
    f16* semb  = (f16*)(ws + off); off += (size_t)T_STEPS*NAG*64*2;     // 15.7 MB
    f16* hencF = (f16*)(ws + off); off += (size_t)T_STEPS*NAG*128*2;    // 31.5 MB
    f16* hencB = (f16*)(ws + off); off += (size_t)T_STEPS*NAG*128*2;    // 31.5 MB

    k_cond<<<dim3(NAG/8,2), 256, 0, stream>>>(cond, cw1,cb1,cw2,cb2, cbw1,cbb1,cbw2,cbb2, probe, disp);
    k_emb<<<3840, 256, 0, stream>>>(z, iw1,ib1,iw2,ib2, probe, semb);
    k_gru_mfma<<<dim3(NAG/32,2), 384, 0, stream>>>(semb, disp, wih,whh,bih,bhh, wihb,whhb,bihb,bhhb, probe, hencF, hencB);
    k_post<<<3840, 256, 0, stream>>>(hencF, hencB, sw,sb, mw,mb, ow1,ob1,ow2,ob2, probe, d_out);
}